// Round 1
// baseline (2892.644 us; speedup 1.0000x reference)
//
#include <hip/hip_runtime.h>
#include <math.h>

#define BB 64
#define CC 122
#define TT 500
#define NCOUT 64
#define DD 128
#define HHEADS 8
#define FFDIM 256
#define NLAYER 2
#define EPS 1e-5f
#define SEQ (BB*CC)   // 7808

// ---------------- workspace float offsets ----------------
#define WS_W2T     0u            // 20480  (conv2_w transposed [ci][k][co])
#define WS_S1      20480u        // 64
#define WS_SH1     20544u        // 64
#define WS_S2      20608u        // 64
#define WS_SH2     20672u        // 64
#define WS_QKVWT   20736u        // 2*128*384 = 98304  ([l][k][e])
#define WS_OUTWT   119040u       // 2*128*128 = 32768
#define WS_FF1WT   151808u       // 2*128*256 = 65536
#define WS_FF2WT   217344u       // 2*256*128 = 65536
#define WS_TOK     282880u       // 7808*128 = 999424
#define WS_QKV     1282304u      // 7808*384 = 2998272
#define WS_CTX     4280576u      // 999424
#define WS_FFH     5280000u      // 7808*256 = 1998848
#define WS_TMP     7278848u      // 999424  (end = 8278272 floats = 33.1 MB)

__device__ __forceinline__ float gelu_erf(float x) {
    return 0.5f * x * (1.0f + erff(x * 0.70710678118654752f));
}

// ---------------- prep: fold BN, transpose weights ----------------
__global__ void prep_kernel(const float* __restrict__ conv1_b,
                            const float* __restrict__ bn1_g, const float* __restrict__ bn1_b,
                            const float* __restrict__ bn1_m, const float* __restrict__ bn1_v,
                            const float* __restrict__ conv2_w, const float* __restrict__ conv2_b,
                            const float* __restrict__ bn2_g, const float* __restrict__ bn2_b,
                            const float* __restrict__ bn2_m, const float* __restrict__ bn2_v,
                            const float* __restrict__ qkv_w, const float* __restrict__ out_w,
                            const float* __restrict__ ff1_w, const float* __restrict__ ff2_w,
                            float* __restrict__ ws) {
    int idx = blockIdx.x * blockDim.x + threadIdx.x;
    if (idx < 20480) {
        int co = idx & 63; int rest = idx >> 6; int k = rest % 5; int ci = rest / 5;
        ws[WS_W2T + (ci*5 + k)*64 + co] = conv2_w[(co*64 + ci)*5 + k];
    } else if (idx < 20544) {
        int i = idx - 20480;
        float s = bn1_g[i] * rsqrtf(bn1_v[i] + EPS);
        ws[WS_S1 + i] = s;
        ws[WS_SH1 + i] = (conv1_b[i] - bn1_m[i]) * s + bn1_b[i];
    } else if (idx < 20608) {
        int i = idx - 20544;
        float s = bn2_g[i] * rsqrtf(bn2_v[i] + EPS);
        ws[WS_S2 + i] = s;
        ws[WS_SH2 + i] = (conv2_b[i] - bn2_m[i]) * s + bn2_b[i];
    } else if (idx < 118912) {
        int r = idx - 20608; int l = r / 49152; r %= 49152;
        int e = r % 384; int k = r / 384;
        ws[WS_QKVWT + l*49152 + k*384 + e] = qkv_w[l*49152 + e*128 + k];
    } else if (idx < 151680) {
        int r = idx - 118912; int l = r / 16384; r %= 16384;
        int e = r % 128; int k = r / 128;
        ws[WS_OUTWT + l*16384 + k*128 + e] = out_w[l*16384 + e*128 + k];
    } else if (idx < 217216) {
        int r = idx - 151680; int l = r / 32768; r %= 32768;
        int e = r % 256; int k = r / 256;
        ws[WS_FF1WT + l*32768 + k*256 + e] = ff1_w[l*32768 + e*128 + k];
    } else if (idx < 282752) {
        int r = idx - 217216; int l = r / 32768; r %= 32768;
        int e = r % 128; int k = r / 128;
        ws[WS_FF2WT + l*32768 + k*128 + e] = ff2_w[l*32768 + e*256 + k];
    }
}

// ---------------- fused conv1+bn+gelu+pool + conv2+bn+gelu+mean + proj ----------------
// one block per sequence (b,c); h1[64][250] lives in LDS
__global__ __launch_bounds__(256) void conv_kernel(const float* __restrict__ x,
            const float* __restrict__ conv1_w,
            const float* __restrict__ proj_w, const float* __restrict__ proj_b,
            const float* __restrict__ elec,
            const float* __restrict__ wsr, float* __restrict__ tok) {
    __shared__ float h1[NCOUT*250];     // 64000 B
    __shared__ float part[4*64];        // 1024 B
    __shared__ float mean_l[64];        // 256 B
    int n = blockIdx.x;
    int c = n % CC;
    int tid = threadIdx.x;
    int co = tid & 63, tq = tid >> 6;
    const float* xg = x + (size_t)n * TT;

    // ---- phase 1: conv1 (k=9, pad 4) + BN + GELU + maxpool(2) ----
    float w1r[9];
#pragma unroll
    for (int k = 0; k < 9; k++) w1r[k] = conv1_w[co*9 + k];
    float s1 = wsr[WS_S1 + co], sh1 = wsr[WS_SH1 + co];
    for (int tp = tq; tp < 250; tp += 4) {
        int t0 = 2*tp;
        float xw[10];
        if (tp >= 2 && tp <= 247) {
#pragma unroll
            for (int u = 0; u < 10; u++) xw[u] = xg[t0 - 4 + u];
        } else {
#pragma unroll
            for (int u = 0; u < 10; u++) {
                int ii = t0 - 4 + u;
                xw[u] = (ii >= 0 && ii < TT) ? xg[ii] : 0.0f;
            }
        }
        float a = 0.f, bsum = 0.f;
#pragma unroll
        for (int k = 0; k < 9; k++) { a = fmaf(xw[k], w1r[k], a); bsum = fmaf(xw[k+1], w1r[k], bsum); }
        float g0 = gelu_erf(fmaf(a, s1, sh1));
        float g1 = gelu_erf(fmaf(bsum, s1, sh1));
        h1[co*250 + tp] = fmaxf(g0, g1);
    }
    __syncthreads();

    // ---- phase 2: conv2 (k=5, pad 2) + BN + GELU + mean over t ----
    float s2 = wsr[WS_S2 + co], sh2 = wsr[WS_SH2 + co];
    const float* w2t = wsr + WS_W2T;
    float tacc = 0.f;
    for (int j = 0; j < 8; j++) {
        int base = j*32 + tq*8;          // 0,8,...,248 across (j,tq)
        float acc[8];
#pragma unroll
        for (int u = 0; u < 8; u++) acc[u] = 0.f;
        bool edge = (base < 2) || (base > 240);
        for (int ci = 0; ci < 64; ci++) {
            const float* h1c = h1 + ci*250;
            float hw[12];
            if (!edge) {
#pragma unroll
                for (int u = 0; u < 12; u++) hw[u] = h1c[base - 2 + u];
            } else {
#pragma unroll
                for (int u = 0; u < 12; u++) {
                    int q = base - 2 + u;
                    hw[u] = (q >= 0 && q < 250) ? h1c[q] : 0.0f;
                }
            }
            float w5[5];
#pragma unroll
            for (int k = 0; k < 5; k++) w5[k] = w2t[(ci*5 + k)*64 + co];
#pragma unroll
            for (int u = 0; u < 8; u++) {
                float s = acc[u];
                s = fmaf(hw[u+0], w5[0], s);
                s = fmaf(hw[u+1], w5[1], s);
                s = fmaf(hw[u+2], w5[2], s);
                s = fmaf(hw[u+3], w5[3], s);
                s = fmaf(hw[u+4], w5[4], s);
                acc[u] = s;
            }
        }
#pragma unroll
        for (int u = 0; u < 8; u++) {
            int t = base + u;
            if (t < 250) tacc += gelu_erf(fmaf(acc[u], s2, sh2));
        }
    }
    part[tq*64 + co] = tacc;
    __syncthreads();
    if (tid < 64) {
        mean_l[tid] = (part[tid] + part[64+tid] + part[128+tid] + part[192+tid]) * (1.0f/250.0f);
    }
    __syncthreads();

    // ---- phase 3: projection + elec_emb -> tok ----
    if (tid < DD) {
        int d = tid;
        float a = proj_b[d] + elec[c*DD + d];
#pragma unroll 8
        for (int o = 0; o < 64; o++) a = fmaf(mean_l[o], proj_w[d*64 + o], a);
        tok[(size_t)n * DD + d] = a;
    }
}

// ---------------- generic fp32 GEMM: out[m][n] = A[m,:]·Wt[:,n] + bias[n] (opt gelu) ----
__global__ __launch_bounds__(256) void gemm_kernel(const float* __restrict__ A,
        const float* __restrict__ Wt, const float* __restrict__ bias,
        float* __restrict__ out, int N, int K, int gelu_flag) {
    __shared__ __align__(16) float Ash[16*256];
    int m0 = blockIdx.x * 16;
    int tid = threadIdx.x;
    for (int idx = tid; idx < 16*K; idx += 256) Ash[idx] = A[(size_t)m0*K + idx];
    __syncthreads();
    for (int n = tid; n < N; n += 256) {
        float acc[16];
#pragma unroll
        for (int m = 0; m < 16; m++) acc[m] = 0.f;
        for (int k = 0; k < K; k += 4) {
            float w0 = Wt[(k+0)*N + n];
            float w1 = Wt[(k+1)*N + n];
            float w2 = Wt[(k+2)*N + n];
            float w3 = Wt[(k+3)*N + n];
#pragma unroll
            for (int m = 0; m < 16; m++) {
                const float4 a4 = *(const float4*)&Ash[m*K + k];
                acc[m] = fmaf(a4.x, w0, fmaf(a4.y, w1, fmaf(a4.z, w2, fmaf(a4.w, w3, acc[m]))));
            }
        }
        float bn = bias[n];
#pragma unroll
        for (int m = 0; m < 16; m++) {
            float v = acc[m] + bn;
            if (gelu_flag) v = gelu_erf(v);
            out[(size_t)(m0 + m)*N + n] = v;
        }
    }
}

// ---------------- attention: one block per (b, h) ----------------
__global__ __launch_bounds__(128) void attn_kernel(const float* __restrict__ qkv,
                                                   float* __restrict__ ctx) {
    __shared__ float qs[CC*16], ks[CC*16], vs[CC*16];
    int b = blockIdx.x >> 3, h = blockIdx.x & 7;
    int tid = threadIdx.x;
    const float* basep = qkv + (size_t)b*CC*384;
    for (int idx = tid; idx < CC*16; idx += 128) {
        int s = idx >> 4, d = idx & 15;
        qs[idx] = basep[s*384 +        h*16 + d];
        ks[idx] = basep[s*384 + 128 + h*16 + d];
        vs[idx] = basep[s*384 + 256 + h*16 + d];
    }
    __syncthreads();
    int i = tid;
    if (i < CC) {
        float q[16];
#pragma unroll
        for (int d = 0; d < 16; d++) q[d] = qs[i*16+d];
        float mx = -1e30f;
        for (int j = 0; j < CC; j++) {
            float s = 0.f;
#pragma unroll
            for (int d = 0; d < 16; d++) s = fmaf(q[d], ks[j*16+d], s);
            mx = fmaxf(mx, s * 0.25f);
        }
        float sum = 0.f;
        float acc[16];
#pragma unroll
        for (int d = 0; d < 16; d++) acc[d] = 0.f;
        for (int j = 0; j < CC; j++) {
            float s = 0.f;
#pragma unroll
            for (int d = 0; d < 16; d++) s = fmaf(q[d], ks[j*16+d], s);
            float e = expf(s * 0.25f - mx);
            sum += e;
#pragma unroll
            for (int d = 0; d < 16; d++) acc[d] = fmaf(e, vs[j*16+d], acc[d]);
        }
        float r = 1.0f / sum;
        float* op = ctx + ((size_t)b*CC + i)*DD + h*16;
#pragma unroll
        for (int d = 0; d < 16; d++) op[d] = acc[d] * r;
    }
}

// ---------------- fused residual add + LayerNorm (rowwise, D=128) ----------------
__global__ __launch_bounds__(128) void ln_add_kernel(float* __restrict__ tok,
        const float* __restrict__ add,
        const float* __restrict__ g, const float* __restrict__ bt) {
    __shared__ float red[2];
    int row = blockIdx.x, tid = threadIdx.x;
    size_t off = (size_t)row*DD + tid;
    float v = tok[off] + add[off];
    float s = v;
#pragma unroll
    for (int o = 32; o > 0; o >>= 1) s += __shfl_down(s, o, 64);
    if ((tid & 63) == 0) red[tid >> 6] = s;
    __syncthreads();
    float mu = (red[0] + red[1]) * (1.0f/128.0f);
    __syncthreads();
    float d = v - mu;
    float s2 = d * d;
#pragma unroll
    for (int o = 32; o > 0; o >>= 1) s2 += __shfl_down(s2, o, 64);
    if ((tid & 63) == 0) red[tid >> 6] = s2;
    __syncthreads();
    float var = (red[0] + red[1]) * (1.0f/128.0f);
    tok[off] = d * rsqrtf(var + EPS) * g[tid] + bt[tid];
}

// ---------------- final: mean over C + subject head ----------------
__global__ __launch_bounds__(128) void final_kernel(const float* __restrict__ tok,
        const int* __restrict__ sid,
        const float* __restrict__ hw, const float* __restrict__ hb,
        float* __restrict__ outp) {
    __shared__ float pool[DD];
    int b = blockIdx.x, tid = threadIdx.x;
    float s = 0.f;
    for (int c2 = 0; c2 < CC; c2++) s += tok[((size_t)b*CC + c2)*DD + tid];
    pool[tid] = s * (1.0f/(float)CC);
    __syncthreads();
    if (tid < 4) {
        int sb = sid[b];
        const float* w = hw + ((size_t)sb*4 + tid)*DD;
        float a = hb[sb*4 + tid];
#pragma unroll 8
        for (int d = 0; d < DD; d++) a = fmaf(pool[d], w[d], a);
        outp[b*4 + tid] = a;
    }
}

extern "C" void kernel_launch(void* const* d_in, const int* in_sizes, int n_in,
                              void* d_out, int out_size, void* d_ws, size_t ws_size,
                              hipStream_t stream) {
    const float* x       = (const float*)d_in[0];
    const int*   sid     = (const int*)  d_in[1];
    const float* conv1_w = (const float*)d_in[2];
    const float* conv1_b = (const float*)d_in[3];
    const float* bn1_g   = (const float*)d_in[4];
    const float* bn1_b   = (const float*)d_in[5];
    const float* bn1_m   = (const float*)d_in[6];
    const float* bn1_v   = (const float*)d_in[7];
    const float* conv2_w = (const float*)d_in[8];
    const float* conv2_b = (const float*)d_in[9];
    const float* bn2_g   = (const float*)d_in[10];
    const float* bn2_b   = (const float*)d_in[11];
    const float* bn2_m   = (const float*)d_in[12];
    const float* bn2_v   = (const float*)d_in[13];
    const float* proj_w  = (const float*)d_in[14];
    const float* proj_b  = (const float*)d_in[15];
    const float* elec    = (const float*)d_in[16];
    const float* qkv_w   = (const float*)d_in[17];
    const float* qkv_b   = (const float*)d_in[18];
    const float* out_w   = (const float*)d_in[19];
    const float* out_b   = (const float*)d_in[20];
    const float* ln1_g   = (const float*)d_in[21];
    const float* ln1_b   = (const float*)d_in[22];
    const float* ff1_w   = (const float*)d_in[23];
    const float* ff1_b   = (const float*)d_in[24];
    const float* ff2_w   = (const float*)d_in[25];
    const float* ff2_b   = (const float*)d_in[26];
    const float* ln2_g   = (const float*)d_in[27];
    const float* ln2_b   = (const float*)d_in[28];
    const float* heads_w = (const float*)d_in[29];
    const float* heads_b = (const float*)d_in[30];
    float* ws = (float*)d_ws;

    prep_kernel<<<(282752 + 255)/256, 256, 0, stream>>>(
        conv1_b, bn1_g, bn1_b, bn1_m, bn1_v,
        conv2_w, conv2_b, bn2_g, bn2_b, bn2_m, bn2_v,
        qkv_w, out_w, ff1_w, ff2_w, ws);

    conv_kernel<<<SEQ, 256, 0, stream>>>(x, conv1_w, proj_w, proj_b, elec, ws, ws + WS_TOK);

    for (int l = 0; l < NLAYER; l++) {
        gemm_kernel<<<SEQ/16, 256, 0, stream>>>(ws + WS_TOK, ws + WS_QKVWT + l*49152,
                                                qkv_b + l*384, ws + WS_QKV, 384, 128, 0);
        attn_kernel<<<BB*HHEADS, 128, 0, stream>>>(ws + WS_QKV, ws + WS_CTX);
        gemm_kernel<<<SEQ/16, 256, 0, stream>>>(ws + WS_CTX, ws + WS_OUTWT + l*16384,
                                                out_b + l*128, ws + WS_TMP, 128, 128, 0);
        ln_add_kernel<<<SEQ, 128, 0, stream>>>(ws + WS_TOK, ws + WS_TMP, ln1_g + l*128, ln1_b + l*128);
        gemm_kernel<<<SEQ/16, 256, 0, stream>>>(ws + WS_TOK, ws + WS_FF1WT + l*32768,
                                                ff1_b + l*256, ws + WS_FFH, 256, 128, 1);
        gemm_kernel<<<SEQ/16, 256, 0, stream>>>(ws + WS_FFH, ws + WS_FF2WT + l*32768,
                                                ff2_b + l*128, ws + WS_TMP, 128, 256, 0);
        ln_add_kernel<<<SEQ, 128, 0, stream>>>(ws + WS_TOK, ws + WS_TMP, ln2_g + l*128, ln2_b + l*128);
    }

    final_kernel<<<BB, 128, 0, stream>>>(ws + WS_TOK, sid, heads_w, heads_b, (float*)d_out);
}

// Round 2
// 1024.643 us; speedup vs baseline: 2.8231x; 2.8231x over previous
//
#include <hip/hip_runtime.h>
#include <math.h>

#define BB 64
#define CC 122
#define TT 500
#define NCOUT 64
#define DD 128
#define HHEADS 8
#define FFDIM 256
#define NLAYER 2
#define EPS 1e-5f
#define SEQ (BB*CC)   // 7808

// ---------------- workspace float offsets ----------------
#define WS_W2T     0u            // 20480 floats reserved; holds 20480 ushort bf16 w2t [kk][co][ci]
#define WS_S1      20480u        // 64
#define WS_SH1     20544u        // 64
#define WS_S2      20608u        // 64
#define WS_SH2     20672u        // 64
#define WS_QKVWT   20736u        // 2*128*384 = 98304  ([l][k][e])
#define WS_OUTWT   119040u       // 2*128*128 = 32768
#define WS_FF1WT   151808u       // 2*128*256 = 65536
#define WS_FF2WT   217344u       // 2*256*128 = 65536
#define WS_TOK     282880u       // 7808*128 = 999424
#define WS_QKV     1282304u      // 7808*384 = 2998272
#define WS_CTX     4280576u      // 999424
#define WS_FFH     5280000u      // 7808*256 = 1998848
#define WS_TMP     7278848u      // 999424  (end = 8278272 floats = 33.1 MB)

typedef __attribute__((ext_vector_type(8))) short bf16x8;
typedef __attribute__((ext_vector_type(4))) float f32x4;

__device__ __forceinline__ float gelu_erf(float x) {
    return 0.5f * x * (1.0f + erff(x * 0.70710678118654752f));
}

__device__ __forceinline__ unsigned short f2bf(float f) {
    unsigned int u = __float_as_uint(f);
    unsigned int r = u + 0x7FFFu + ((u >> 16) & 1u);
    return (unsigned short)(r >> 16);
}

// ---------------- prep: fold BN, transpose weights, bf16-ify conv2 w ----------------
__global__ void prep_kernel(const float* __restrict__ conv1_b,
                            const float* __restrict__ bn1_g, const float* __restrict__ bn1_b,
                            const float* __restrict__ bn1_m, const float* __restrict__ bn1_v,
                            const float* __restrict__ conv2_w, const float* __restrict__ conv2_b,
                            const float* __restrict__ bn2_g, const float* __restrict__ bn2_b,
                            const float* __restrict__ bn2_m, const float* __restrict__ bn2_v,
                            const float* __restrict__ qkv_w, const float* __restrict__ out_w,
                            const float* __restrict__ ff1_w, const float* __restrict__ ff2_w,
                            float* __restrict__ ws) {
    int idx = blockIdx.x * blockDim.x + threadIdx.x;
    if (idx < 20480) {
        // bf16 w2t[kk][co][ci] <- conv2_w[co][ci][kk]
        int ci = idx & 63; int co = (idx >> 6) & 63; int kk = idx >> 12;
        unsigned short* wt = (unsigned short*)(ws + WS_W2T);
        wt[idx] = f2bf(conv2_w[(co*64 + ci)*5 + kk]);
    } else if (idx < 20544) {
        int i = idx - 20480;
        float s = bn1_g[i] * rsqrtf(bn1_v[i] + EPS);
        ws[WS_S1 + i] = s;
        ws[WS_SH1 + i] = (conv1_b[i] - bn1_m[i]) * s + bn1_b[i];
    } else if (idx < 20608) {
        int i = idx - 20544;
        float s = bn2_g[i] * rsqrtf(bn2_v[i] + EPS);
        ws[WS_S2 + i] = s;
        ws[WS_SH2 + i] = (conv2_b[i] - bn2_m[i]) * s + bn2_b[i];
    } else if (idx < 118912) {
        int r = idx - 20608; int l = r / 49152; r %= 49152;
        int e = r % 384; int k = r / 384;
        ws[WS_QKVWT + l*49152 + k*384 + e] = qkv_w[l*49152 + e*128 + k];
    } else if (idx < 151680) {
        int r = idx - 118912; int l = r / 16384; r %= 16384;
        int e = r % 128; int k = r / 128;
        ws[WS_OUTWT + l*16384 + k*128 + e] = out_w[l*16384 + e*128 + k];
    } else if (idx < 217216) {
        int r = idx - 151680; int l = r / 32768; r %= 32768;
        int e = r % 256; int k = r / 256;
        ws[WS_FF1WT + l*32768 + k*256 + e] = ff1_w[l*32768 + e*128 + k];
    } else if (idx < 282752) {
        int r = idx - 217216; int l = r / 32768; r %= 32768;
        int e = r % 128; int k = r / 128;
        ws[WS_FF2WT + l*32768 + k*128 + e] = ff2_w[l*32768 + e*256 + k];
    }
}

// ---------------- fused conv1(+bn+gelu+pool) [VALU] + conv2(+bn+gelu+mean) [MFMA] + proj ----
// one block per sequence (b,c). h1T (pooled conv1 out, transposed, bf16) lives in LDS:
// rows r = t+2 for t in [-2, 261]; valid t 0..249; chunk-XOR-swizzled for bank-free b128 reads.
__global__ __launch_bounds__(256, 4) void conv_kernel(const float* __restrict__ x,
            const float* __restrict__ conv1_w,
            const float* __restrict__ proj_w, const float* __restrict__ proj_b,
            const float* __restrict__ elec,
            const float* __restrict__ wsr, float* __restrict__ tok) {
    __shared__ __align__(16) unsigned short h1s[264*64];  // 33792 B
    __shared__ float part[4*64];                          // 1024 B
    __shared__ float mean_l[64];
    int n = blockIdx.x;
    int c = n % CC;
    int tid = threadIdx.x;
    int co = tid & 63, tq = tid >> 6;
    const float* xg = x + (size_t)n * TT;

    // zero pad rows r in {0,1} u {252..265} region (only 0..259 ever read)
    for (int idx = tid; idx < 14*64; idx += 256) {
        int rr = idx >> 6;
        int r = (rr < 2) ? rr : (rr - 2 + 252);
        h1s[r*64 + (idx & 63)] = 0;
    }

    // ---- phase 1: conv1 (k=9, pad 4) + BN + GELU + maxpool(2) -> h1T bf16 ----
    float w1r[9];
#pragma unroll
    for (int k = 0; k < 9; k++) w1r[k] = conv1_w[co*9 + k];
    float s1 = wsr[WS_S1 + co], sh1 = wsr[WS_SH1 + co];
    for (int tp = tq; tp < 250; tp += 4) {
        int t0 = 2*tp;
        float xw[10];
        if (tp >= 2 && tp <= 247) {
#pragma unroll
            for (int u = 0; u < 10; u++) xw[u] = xg[t0 - 4 + u];
        } else {
#pragma unroll
            for (int u = 0; u < 10; u++) {
                int ii = t0 - 4 + u;
                xw[u] = (ii >= 0 && ii < TT) ? xg[ii] : 0.0f;
            }
        }
        float a = 0.f, bsum = 0.f;
#pragma unroll
        for (int k = 0; k < 9; k++) { a = fmaf(xw[k], w1r[k], a); bsum = fmaf(xw[k+1], w1r[k], bsum); }
        float g0 = gelu_erf(fmaf(a, s1, sh1));
        float g1 = gelu_erf(fmaf(bsum, s1, sh1));
        int r = tp + 2;
        int cp = (co >> 3) ^ (r & 7);
        h1s[r*64 + cp*8 + (co & 7)] = f2bf(fmaxf(g0, g1));
    }
    __syncthreads();

    // ---- phase 2: conv2 as 5 shifted GEMMs via mfma_f32_16x16x32_bf16 ----
    // wave w owns M-tiles {4w..4w+3} (t) x all 4 N-tiles (co)
    const unsigned short* wt = (const unsigned short*)(wsr + WS_W2T);
    int lane = tid & 63;
    int w = tid >> 6;
    int ln15 = lane & 15, lg = lane >> 4;
    f32x4 acc[4][4];
#pragma unroll
    for (int mi = 0; mi < 4; mi++)
#pragma unroll
        for (int nt = 0; nt < 4; nt++) acc[mi][nt] = (f32x4){0.f, 0.f, 0.f, 0.f};

    const unsigned short* wbase = wt + ln15*64 + lg*8;  // + kk*4096 + nt*1024 + s*32
#pragma unroll
    for (int kk = 0; kk < 5; kk++) {
#pragma unroll
        for (int s = 0; s < 2; s++) {
            bf16x8 bf[4];
#pragma unroll
            for (int nt = 0; nt < 4; nt++)
                bf[nt] = *(const bf16x8*)(wbase + kk*4096 + nt*1024 + s*32);
#pragma unroll
            for (int mi = 0; mi < 4; mi++) {
                int r = (w*4 + mi)*16 + ln15 + kk;      // A row (t + kk), already includes +2 pad shift
                int cp = (s*4 + lg) ^ (r & 7);
                bf16x8 af = *(const bf16x8*)&h1s[r*64 + cp*8];
#pragma unroll
                for (int nt = 0; nt < 4; nt++)
                    acc[mi][nt] = __builtin_amdgcn_mfma_f32_16x16x32_bf16(af, bf[nt], acc[mi][nt], 0, 0, 0);
            }
        }
    }

    // ---- epilogue: BN + GELU + mean over t (mask t<250), reduce across lanes/waves ----
#pragma unroll
    for (int nt = 0; nt < 4; nt++) {
        int co2 = nt*16 + ln15;
        float sc = wsr[WS_S2 + co2], sh = wsr[WS_SH2 + co2];
        float p = 0.f;
#pragma unroll
        for (int mi = 0; mi < 4; mi++) {
            int tbase = (w*4 + mi)*16 + lg*4;
#pragma unroll
            for (int i = 0; i < 4; i++) {
                if (tbase + i < 250)
                    p += gelu_erf(fmaf(acc[mi][nt][i], sc, sh));
            }
        }
        p += __shfl_down(p, 32, 64);
        p += __shfl_down(p, 16, 64);
        if (lane < 16) part[w*64 + co2] = p;
    }
    __syncthreads();
    if (tid < 64) {
        mean_l[tid] = (part[tid] + part[64+tid] + part[128+tid] + part[192+tid]) * (1.0f/250.0f);
    }
    __syncthreads();

    // ---- phase 3: projection + elec_emb -> tok ----
    if (tid < DD) {
        int d = tid;
        float a = proj_b[d] + elec[c*DD + d];
#pragma unroll 8
        for (int o = 0; o < 64; o++) a = fmaf(mean_l[o], proj_w[d*64 + o], a);
        tok[(size_t)n * DD + d] = a;
    }
}

// ---------------- generic fp32 GEMM: out[m][n] = A[m,:]·Wt[:,n] + bias[n] (opt gelu) ----
__global__ __launch_bounds__(256) void gemm_kernel(const float* __restrict__ A,
        const float* __restrict__ Wt, const float* __restrict__ bias,
        float* __restrict__ out, int N, int K, int gelu_flag) {
    __shared__ __align__(16) float Ash[16*256];
    int m0 = blockIdx.x * 16;
    int tid = threadIdx.x;
    for (int idx = tid; idx < 16*K; idx += 256) Ash[idx] = A[(size_t)m0*K + idx];
    __syncthreads();
    for (int n = tid; n < N; n += 256) {
        float acc[16];
#pragma unroll
        for (int m = 0; m < 16; m++) acc[m] = 0.f;
        for (int k = 0; k < K; k += 4) {
            float w0 = Wt[(k+0)*N + n];
            float w1 = Wt[(k+1)*N + n];
            float w2 = Wt[(k+2)*N + n];
            float w3 = Wt[(k+3)*N + n];
#pragma unroll
            for (int m = 0; m < 16; m++) {
                const float4 a4 = *(const float4*)&Ash[m*K + k];
                acc[m] = fmaf(a4.x, w0, fmaf(a4.y, w1, fmaf(a4.z, w2, fmaf(a4.w, w3, acc[m]))));
            }
        }
        float bn = bias[n];
#pragma unroll
        for (int m = 0; m < 16; m++) {
            float v = acc[m] + bn;
            if (gelu_flag) v = gelu_erf(v);
            out[(size_t)(m0 + m)*N + n] = v;
        }
    }
}

// ---------------- attention: one block per (b, h) ----------------
__global__ __launch_bounds__(128) void attn_kernel(const float* __restrict__ qkv,
                                                   float* __restrict__ ctx) {
    __shared__ float qs[CC*16], ks[CC*16], vs[CC*16];
    int b = blockIdx.x >> 3, h = blockIdx.x & 7;
    int tid = threadIdx.x;
    const float* basep = qkv + (size_t)b*CC*384;
    for (int idx = tid; idx < CC*16; idx += 128) {
        int s = idx >> 4, d = idx & 15;
        qs[idx] = basep[s*384 +        h*16 + d];
        ks[idx] = basep[s*384 + 128 + h*16 + d];
        vs[idx] = basep[s*384 + 256 + h*16 + d];
    }
    __syncthreads();
    int i = tid;
    if (i < CC) {
        float q[16];
#pragma unroll
        for (int d = 0; d < 16; d++) q[d] = qs[i*16+d];
        float mx = -1e30f;
        for (int j = 0; j < CC; j++) {
            float s = 0.f;
#pragma unroll
            for (int d = 0; d < 16; d++) s = fmaf(q[d], ks[j*16+d], s);
            mx = fmaxf(mx, s * 0.25f);
        }
        float sum = 0.f;
        float acc[16];
#pragma unroll
        for (int d = 0; d < 16; d++) acc[d] = 0.f;
        for (int j = 0; j < CC; j++) {
            float s = 0.f;
#pragma unroll
            for (int d = 0; d < 16; d++) s = fmaf(q[d], ks[j*16+d], s);
            float e = expf(s * 0.25f - mx);
            sum += e;
#pragma unroll
            for (int d = 0; d < 16; d++) acc[d] = fmaf(e, vs[j*16+d], acc[d]);
        }
        float r = 1.0f / sum;
        float* op = ctx + ((size_t)b*CC + i)*DD + h*16;
#pragma unroll
        for (int d = 0; d < 16; d++) op[d] = acc[d] * r;
    }
}

// ---------------- fused residual add + LayerNorm (rowwise, D=128) ----------------
__global__ __launch_bounds__(128) void ln_add_kernel(float* __restrict__ tok,
        const float* __restrict__ add,
        const float* __restrict__ g, const float* __restrict__ bt) {
    __shared__ float red[2];
    int row = blockIdx.x, tid = threadIdx.x;
    size_t off = (size_t)row*DD + tid;
    float v = tok[off] + add[off];
    float s = v;
#pragma unroll
    for (int o = 32; o > 0; o >>= 1) s += __shfl_down(s, o, 64);
    if ((tid & 63) == 0) red[tid >> 6] = s;
    __syncthreads();
    float mu = (red[0] + red[1]) * (1.0f/128.0f);
    __syncthreads();
    float d = v - mu;
    float s2 = d * d;
#pragma unroll
    for (int o = 32; o > 0; o >>= 1) s2 += __shfl_down(s2, o, 64);
    if ((tid & 63) == 0) red[tid >> 6] = s2;
    __syncthreads();
    float var = (red[0] + red[1]) * (1.0f/128.0f);
    tok[off] = d * rsqrtf(var + EPS) * g[tid] + bt[tid];
}

// ---------------- final: mean over C + subject head ----------------
__global__ __launch_bounds__(128) void final_kernel(const float* __restrict__ tok,
        const int* __restrict__ sid,
        const float* __restrict__ hw, const float* __restrict__ hb,
        float* __restrict__ outp) {
    __shared__ float pool[DD];
    int b = blockIdx.x, tid = threadIdx.x;
    float s = 0.f;
    for (int c2 = 0; c2 < CC; c2++) s += tok[((size_t)b*CC + c2)*DD + tid];
    pool[tid] = s * (1.0f/(float)CC);
    __syncthreads();
    if (tid < 4) {
        int sb = sid[b];
        const float* w = hw + ((size_t)sb*4 + tid)*DD;
        float a = hb[sb*4 + tid];
#pragma unroll 8
        for (int d = 0; d < DD; d++) a = fmaf(pool[d], w[d], a);
        outp[b*4 + tid] = a;
    }
}

extern "C" void kernel_launch(void* const* d_in, const int* in_sizes, int n_in,
                              void* d_out, int out_size, void* d_ws, size_t ws_size,
                              hipStream_t stream) {
    const float* x       = (const float*)d_in[0];
    const int*   sid     = (const int*)  d_in[1];
    const float* conv1_w = (const float*)d_in[2];
    const float* conv1_b = (const float*)d_in[3];
    const float* bn1_g   = (const float*)d_in[4];
    const float* bn1_b   = (const float*)d_in[5];
    const float* bn1_m   = (const float*)d_in[6];
    const float* bn1_v   = (const float*)d_in[7];
    const float* conv2_w = (const float*)d_in[8];
    const float* conv2_b = (const float*)d_in[9];
    const float* bn2_g   = (const float*)d_in[10];
    const float* bn2_b   = (const float*)d_in[11];
    const float* bn2_m   = (const float*)d_in[12];
    const float* bn2_v   = (const float*)d_in[13];
    const float* proj_w  = (const float*)d_in[14];
    const float* proj_b  = (const float*)d_in[15];
    const float* elec    = (const float*)d_in[16];
    const float* qkv_w   = (const float*)d_in[17];
    const float* qkv_b   = (const float*)d_in[18];
    const float* out_w   = (const float*)d_in[19];
    const float* out_b   = (const float*)d_in[20];
    const float* ln1_g   = (const float*)d_in[21];
    const float* ln1_b   = (const float*)d_in[22];
    const float* ff1_w   = (const float*)d_in[23];
    const float* ff1_b   = (const float*)d_in[24];
    const float* ff2_w   = (const float*)d_in[25];
    const float* ff2_b   = (const float*)d_in[26];
    const float* ln2_g   = (const float*)d_in[27];
    const float* ln2_b   = (const float*)d_in[28];
    const float* heads_w = (const float*)d_in[29];
    const float* heads_b = (const float*)d_in[30];
    float* ws = (float*)d_ws;

    prep_kernel<<<(282752 + 255)/256, 256, 0, stream>>>(
        conv1_b, bn1_g, bn1_b, bn1_m, bn1_v,
        conv2_w, conv2_b, bn2_g, bn2_b, bn2_m, bn2_v,
        qkv_w, out_w, ff1_w, ff2_w, ws);

    conv_kernel<<<SEQ, 256, 0, stream>>>(x, conv1_w, proj_w, proj_b, elec, ws, ws + WS_TOK);

    for (int l = 0; l < NLAYER; l++) {
        gemm_kernel<<<SEQ/16, 256, 0, stream>>>(ws + WS_TOK, ws + WS_QKVWT + l*49152,
                                                qkv_b + l*384, ws + WS_QKV, 384, 128, 0);
        attn_kernel<<<BB*HHEADS, 128, 0, stream>>>(ws + WS_QKV, ws + WS_CTX);
        gemm_kernel<<<SEQ/16, 256, 0, stream>>>(ws + WS_CTX, ws + WS_OUTWT + l*16384,
                                                out_b + l*128, ws + WS_TMP, 128, 128, 0);
        ln_add_kernel<<<SEQ, 128, 0, stream>>>(ws + WS_TOK, ws + WS_TMP, ln1_g + l*128, ln1_b + l*128);
        gemm_kernel<<<SEQ/16, 256, 0, stream>>>(ws + WS_TOK, ws + WS_FF1WT + l*32768,
                                                ff1_b + l*256, ws + WS_FFH, 256, 128, 1);
        gemm_kernel<<<SEQ/16, 256, 0, stream>>>(ws + WS_FFH, ws + WS_FF2WT + l*32768,
                                                ff2_b + l*128, ws + WS_TMP, 128, 256, 0);
        ln_add_kernel<<<SEQ, 128, 0, stream>>>(ws + WS_TOK, ws + WS_TMP, ln2_g + l*128, ln2_b + l*128);
    }

    final_kernel<<<BB, 128, 0, stream>>>(ws + WS_TOK, sid, heads_w, heads_b, (float*)d_out);
}

// Round 3
// 669.544 us; speedup vs baseline: 4.3203x; 1.5304x over previous
//
#include <hip/hip_runtime.h>
#include <math.h>

#define BB 64
#define CC 122
#define TT 500
#define NCOUT 64
#define DD 128
#define HHEADS 8
#define FFDIM 256
#define NLAYER 2
#define EPS 1e-5f
#define SEQ (BB*CC)   // 7808

// ---------------- workspace float offsets ----------------
#define WS_W2T     0u            // 10240 floats reserved (20480 ushort bf16 w2t [kk][co][ci])
#define WS_S1      20480u        // 64
#define WS_SH1     20544u        // 64
#define WS_S2      20608u        // 64
#define WS_SH2     20672u        // 64
#define WS_WBF     20736u        // 262144 ushorts (=131072 floats): bf16 qkv/out/ff1/ff2 weights
#define WS_TOK     151808u       // 7808*128 = 999424 floats
#define WS_QKV     1151232u      // 7808*384 = 2998272 floats
#define WS_CTX     4149504u      // 999424 floats
#define WS_FFH     5148928u      // 7808*256 ushorts = 999424 floats (bf16 ff hidden)
// end = 6148352 floats = 24.6 MB

// WBF internal ushort offsets
#define WB_QKV  0u        // l*49152 + e*128 + k          (2*384*128)
#define WB_OUT  98304u    // l*16384 + e*128 + k          (2*128*128)
#define WB_FF1  131072u   // l*32768 + e*128 + k          (2*256*128)
#define WB_FF2  196608u   // l*32768 + e*256 + k          (2*128*256)

typedef __attribute__((ext_vector_type(8))) short bf16x8;
typedef __attribute__((ext_vector_type(4))) float f32x4;

__device__ __forceinline__ unsigned short f2bf(float f) {
    unsigned int u = __float_as_uint(f);
    unsigned int r = u + 0x7FFFu + ((u >> 16) & 1u);
    return (unsigned short)(r >> 16);
}

// branch-free erf-GELU, Abramowitz-Stegun 7.1.26 (max abs err ~1.5e-7)
__device__ __forceinline__ float gelu_fast(float x) {
    float z = fabsf(x) * 0.70710678118654752f;
    float t = __builtin_amdgcn_rcpf(fmaf(0.3275911f, z, 1.0f));
    float p = fmaf(fmaf(fmaf(fmaf(1.061405429f, t, -1.453152027f), t,
                             1.421413741f), t, -0.284496736f), t, 0.254829592f);
    float e = __expf(-z * z);
    float erf_abs = fmaf(-p * t, e, 1.0f);
    float erf_x = copysignf(erf_abs, x);
    return 0.5f * x * (1.0f + erf_x);
}

// ---------------- prep: fold BN, bf16-ify weights ----------------
__global__ void prep_kernel(const float* __restrict__ conv1_b,
                            const float* __restrict__ bn1_g, const float* __restrict__ bn1_b,
                            const float* __restrict__ bn1_m, const float* __restrict__ bn1_v,
                            const float* __restrict__ conv2_w, const float* __restrict__ conv2_b,
                            const float* __restrict__ bn2_g, const float* __restrict__ bn2_b,
                            const float* __restrict__ bn2_m, const float* __restrict__ bn2_v,
                            const float* __restrict__ qkv_w, const float* __restrict__ out_w,
                            const float* __restrict__ ff1_w, const float* __restrict__ ff2_w,
                            float* __restrict__ ws) {
    int idx = blockIdx.x * blockDim.x + threadIdx.x;
    if (idx < 20480) {
        // bf16 w2t[kk][co][ci] <- conv2_w[co][ci][kk]
        int ci = idx & 63; int co = (idx >> 6) & 63; int kk = idx >> 12;
        unsigned short* wt = (unsigned short*)(ws + WS_W2T);
        wt[idx] = f2bf(conv2_w[(co*64 + ci)*5 + kk]);
    } else if (idx < 20544) {
        int i = idx - 20480;
        float s = bn1_g[i] * rsqrtf(bn1_v[i] + EPS);
        ws[WS_S1 + i] = s;
        ws[WS_SH1 + i] = (conv1_b[i] - bn1_m[i]) * s + bn1_b[i];
    } else if (idx < 20608) {
        int i = idx - 20544;
        float s = bn2_g[i] * rsqrtf(bn2_v[i] + EPS);
        ws[WS_S2 + i] = s;
        ws[WS_SH2 + i] = (conv2_b[i] - bn2_m[i]) * s + bn2_b[i];
    } else if (idx < 282752) {
        int r = idx - 20608;
        unsigned short* wbf = (unsigned short*)(ws + WS_WBF);
        float v;
        if (r < 98304)       v = qkv_w[r];
        else if (r < 131072) v = out_w[r - 98304];
        else if (r < 196608) v = ff1_w[r - 131072];
        else                 v = ff2_w[r - 196608];
        wbf[r] = f2bf(v);
    }
}

// ---------------- fused conv1(+bn+gelu+pool) [VALU] + conv2(+bn+gelu+mean) [MFMA] + proj ----
__global__ __launch_bounds__(256, 4) void conv_kernel(const float* __restrict__ x,
            const float* __restrict__ conv1_w,
            const float* __restrict__ proj_w, const float* __restrict__ proj_b,
            const float* __restrict__ elec,
            const float* __restrict__ wsr, float* __restrict__ tok) {
    __shared__ __align__(16) unsigned short h1s[264*64];  // 33792 B
    __shared__ float part[4*64];
    __shared__ float mean_l[64];
    int n = blockIdx.x;
    int c = n % CC;
    int tid = threadIdx.x;
    int co = tid & 63, tq = tid >> 6;
    const float* xg = x + (size_t)n * TT;

    for (int idx = tid; idx < 14*64; idx += 256) {
        int rr = idx >> 6;
        int r = (rr < 2) ? rr : (rr - 2 + 252);
        h1s[r*64 + (idx & 63)] = 0;
    }

    // ---- phase 1: conv1 (k=9, pad 4) + BN + GELU + maxpool(2) -> h1T bf16 ----
    float w1r[9];
#pragma unroll
    for (int k = 0; k < 9; k++) w1r[k] = conv1_w[co*9 + k];
    float s1 = wsr[WS_S1 + co], sh1 = wsr[WS_SH1 + co];
    for (int tp = tq; tp < 250; tp += 4) {
        int t0 = 2*tp;
        float xw[10];
        if (tp >= 2 && tp <= 247) {
#pragma unroll
            for (int u = 0; u < 10; u++) xw[u] = xg[t0 - 4 + u];
        } else {
#pragma unroll
            for (int u = 0; u < 10; u++) {
                int ii = t0 - 4 + u;
                xw[u] = (ii >= 0 && ii < TT) ? xg[ii] : 0.0f;
            }
        }
        float a = 0.f, bsum = 0.f;
#pragma unroll
        for (int k = 0; k < 9; k++) { a = fmaf(xw[k], w1r[k], a); bsum = fmaf(xw[k+1], w1r[k], bsum); }
        float g0 = gelu_fast(fmaf(a, s1, sh1));
        float g1 = gelu_fast(fmaf(bsum, s1, sh1));
        int r = tp + 2;
        int cp = (co >> 3) ^ (r & 7);
        h1s[r*64 + cp*8 + (co & 7)] = f2bf(fmaxf(g0, g1));
    }
    __syncthreads();

    // ---- phase 2: conv2 as 5 shifted GEMMs via mfma_f32_16x16x32_bf16 ----
    const unsigned short* wt = (const unsigned short*)(wsr + WS_W2T);
    int lane = tid & 63;
    int w = tid >> 6;
    int ln15 = lane & 15, lg = lane >> 4;
    f32x4 acc[4][4];
#pragma unroll
    for (int mi = 0; mi < 4; mi++)
#pragma unroll
        for (int nt = 0; nt < 4; nt++) acc[mi][nt] = (f32x4){0.f, 0.f, 0.f, 0.f};

    const unsigned short* wbase = wt + ln15*64 + lg*8;
#pragma unroll
    for (int kk = 0; kk < 5; kk++) {
#pragma unroll
        for (int s = 0; s < 2; s++) {
            bf16x8 bfv[4];
#pragma unroll
            for (int nt = 0; nt < 4; nt++)
                bfv[nt] = *(const bf16x8*)(wbase + kk*4096 + nt*1024 + s*32);
#pragma unroll
            for (int mi = 0; mi < 4; mi++) {
                int r = (w*4 + mi)*16 + ln15 + kk;
                int cp = (s*4 + lg) ^ (r & 7);
                bf16x8 af = *(const bf16x8*)&h1s[r*64 + cp*8];
#pragma unroll
                for (int nt = 0; nt < 4; nt++)
                    acc[mi][nt] = __builtin_amdgcn_mfma_f32_16x16x32_bf16(af, bfv[nt], acc[mi][nt], 0, 0, 0);
            }
        }
    }

    // ---- epilogue: BN + GELU + mean over t ----
#pragma unroll
    for (int nt = 0; nt < 4; nt++) {
        int co2 = nt*16 + ln15;
        float sc = wsr[WS_S2 + co2], sh = wsr[WS_SH2 + co2];
        float p = 0.f;
#pragma unroll
        for (int mi = 0; mi < 4; mi++) {
            int tbase = (w*4 + mi)*16 + lg*4;
#pragma unroll
            for (int i = 0; i < 4; i++) {
                if (tbase + i < 250)
                    p += gelu_fast(fmaf(acc[mi][nt][i], sc, sh));
            }
        }
        p += __shfl_down(p, 32, 64);
        p += __shfl_down(p, 16, 64);
        if (lane < 16) part[w*64 + co2] = p;
    }
    __syncthreads();
    if (tid < 64) {
        mean_l[tid] = (part[tid] + part[64+tid] + part[128+tid] + part[192+tid]) * (1.0f/250.0f);
    }
    __syncthreads();

    if (tid < DD) {
        int d = tid;
        float a = proj_b[d] + elec[c*DD + d];
#pragma unroll 8
        for (int o = 0; o < 64; o++) a = fmaf(mean_l[o], proj_w[d*64 + o], a);
        tok[(size_t)n * DD + d] = a;
    }
}

// ---------------- bf16 MFMA GEMM, M-tile 32, N-tile 128 per blockIdx.y ----
// C[m][n] = sum_k A[m][k] * B[n][k] + bias[n]; optional gelu / bf16 out / fused add+LN
template<int K, int ABF16, int GELUF, int OBF16, int LNF>
__global__ __launch_bounds__(256) void mfma_gemm(const void* __restrict__ Aptr,
        const unsigned short* __restrict__ Bbf,
        const float* __restrict__ bias,
        void* __restrict__ Cptr, int ldC,
        float* __restrict__ tokres,
        const float* __restrict__ lng, const float* __restrict__ lnb) {
    const int tid = threadIdx.x;
    const int m0 = blockIdx.x * 32;
    const int n0 = blockIdx.y * 128;
    __shared__ __align__(16) unsigned short As[32*K];
    __shared__ float Cs[LNF ? 32*129 : 1];

    // stage A (32 x K) into LDS as bf16, 16B-chunk XOR swizzle
    if (!ABF16) {
        const float* A = (const float*)Aptr + (size_t)m0 * K;
        for (int i = tid; i < 8*K; i += 256) {
            int m = i / (K/4); int kq = (i - m*(K/4))*4;
            float4 v = *(const float4*)(A + m*K + kq);
            int cp = (kq >> 3) ^ (m & 15);
            short4 s4 = make_short4((short)f2bf(v.x), (short)f2bf(v.y),
                                    (short)f2bf(v.z), (short)f2bf(v.w));
            *(short4*)&As[m*K + cp*8 + (kq & 7)] = s4;
        }
    } else {
        const unsigned short* A = (const unsigned short*)Aptr + (size_t)m0 * K;
        for (int i = tid; i < 8*K; i += 256) {
            int m = i / (K/4); int kq = (i - m*(K/4))*4;
            short4 v = *(const short4*)(A + m*K + kq);
            int cp = (kq >> 3) ^ (m & 15);
            *(short4*)&As[m*K + cp*8 + (kq & 7)] = v;
        }
    }
    __syncthreads();

    const int lane = tid & 63, w = tid >> 6;
    const int ln15 = lane & 15, lg = lane >> 4;
    f32x4 acc[2][2];
#pragma unroll
    for (int mi = 0; mi < 2; mi++)
#pragma unroll
        for (int ni = 0; ni < 2; ni++) acc[mi][ni] = (f32x4){0.f, 0.f, 0.f, 0.f};

    const unsigned short* Bb = Bbf + (size_t)n0 * K;
#pragma unroll
    for (int kt = 0; kt < K/32; kt++) {
        bf16x8 af[2], bfv[2];
#pragma unroll
        for (int mi = 0; mi < 2; mi++) {
            int m = mi*16 + ln15;
            int cp = (kt*4 + lg) ^ (m & 15);
            af[mi] = *(const bf16x8*)&As[m*K + cp*8];
        }
#pragma unroll
        for (int ni = 0; ni < 2; ni++) {
            int nn = (w*2 + ni)*16 + ln15;
            bfv[ni] = *(const bf16x8*)&Bb[(size_t)nn*K + kt*32 + lg*8];
        }
#pragma unroll
        for (int mi = 0; mi < 2; mi++)
#pragma unroll
            for (int ni = 0; ni < 2; ni++)
                acc[mi][ni] = __builtin_amdgcn_mfma_f32_16x16x32_bf16(af[mi], bfv[ni], acc[mi][ni], 0, 0, 0);
    }

    // epilogue
#pragma unroll
    for (int mi = 0; mi < 2; mi++)
#pragma unroll
        for (int ni = 0; ni < 2; ni++) {
            int nloc = (w*2 + ni)*16 + ln15;
            int nn = n0 + nloc;
            float bn = bias[nn];
#pragma unroll
            for (int i = 0; i < 4; i++) {
                int ml = mi*16 + lg*4 + i;
                float v = acc[mi][ni][i] + bn;
                if (GELUF) v = gelu_fast(v);
                if (LNF) {
                    Cs[ml*129 + nloc] = v + tokres[(size_t)(m0 + ml)*128 + nloc];
                } else if (OBF16) {
                    ((unsigned short*)Cptr)[(size_t)(m0 + ml)*ldC + nn] = f2bf(v);
                } else {
                    ((float*)Cptr)[(size_t)(m0 + ml)*ldC + nn] = v;
                }
            }
        }

    if (LNF) {
        __syncthreads();
        int r = tid >> 3, sub = tid & 7;
        float s1 = 0.f, s2 = 0.f;
#pragma unroll
        for (int j = 0; j < 16; j++) {
            float vv = Cs[r*129 + sub*16 + j];
            s1 += vv; s2 += vv*vv;
        }
        s1 += __shfl_down(s1, 4, 64); s2 += __shfl_down(s2, 4, 64);
        s1 += __shfl_down(s1, 2, 64); s2 += __shfl_down(s2, 2, 64);
        s1 += __shfl_down(s1, 1, 64); s2 += __shfl_down(s2, 1, 64);
        int lb = lane & 56;
        s1 = __shfl(s1, lb, 64); s2 = __shfl(s2, lb, 64);
        float mu = s1 * (1.0f/128.0f);
        float var = s2 * (1.0f/128.0f) - mu*mu;
        float rstd = rsqrtf(var + EPS);
#pragma unroll
        for (int j = 0; j < 16; j++) {
            int nloc = sub*16 + j;
            float vv = (Cs[r*129 + nloc] - mu) * rstd * lng[nloc] + lnb[nloc];
            tokres[(size_t)(m0 + r)*128 + nloc] = vv;
        }
    }
}

// ---------------- attention: one block per (b, h) ----------------
__global__ __launch_bounds__(128) void attn_kernel(const float* __restrict__ qkv,
                                                   float* __restrict__ ctx) {
    __shared__ float qs[CC*16], ks[CC*16], vs[CC*16];
    int b = blockIdx.x >> 3, h = blockIdx.x & 7;
    int tid = threadIdx.x;
    const float* basep = qkv + (size_t)b*CC*384;
    for (int idx = tid; idx < CC*16; idx += 128) {
        int s = idx >> 4, d = idx & 15;
        qs[idx] = basep[s*384 +        h*16 + d];
        ks[idx] = basep[s*384 + 128 + h*16 + d];
        vs[idx] = basep[s*384 + 256 + h*16 + d];
    }
    __syncthreads();
    int i = tid;
    if (i < CC) {
        float q[16];
#pragma unroll
        for (int d = 0; d < 16; d++) q[d] = qs[i*16+d];
        float mx = -1e30f;
        for (int j = 0; j < CC; j++) {
            float s = 0.f;
#pragma unroll
            for (int d = 0; d < 16; d++) s = fmaf(q[d], ks[j*16+d], s);
            mx = fmaxf(mx, s * 0.25f);
        }
        float sum = 0.f;
        float acc[16];
#pragma unroll
        for (int d = 0; d < 16; d++) acc[d] = 0.f;
        for (int j = 0; j < CC; j++) {
            float s = 0.f;
#pragma unroll
            for (int d = 0; d < 16; d++) s = fmaf(q[d], ks[j*16+d], s);
            float e = __expf(s * 0.25f - mx);
            sum += e;
#pragma unroll
            for (int d = 0; d < 16; d++) acc[d] = fmaf(e, vs[j*16+d], acc[d]);
        }
        float r = __builtin_amdgcn_rcpf(sum);
        float* op = ctx + ((size_t)b*CC + i)*DD + h*16;
#pragma unroll
        for (int d = 0; d < 16; d++) op[d] = acc[d] * r;
    }
}

// ---------------- final: mean over C + subject head ----------------
__global__ __launch_bounds__(128) void final_kernel(const float* __restrict__ tok,
        const int* __restrict__ sid,
        const float* __restrict__ hw, const float* __restrict__ hb,
        float* __restrict__ outp) {
    __shared__ float pool[DD];
    int b = blockIdx.x, tid = threadIdx.x;
    float s = 0.f;
    for (int c2 = 0; c2 < CC; c2++) s += tok[((size_t)b*CC + c2)*DD + tid];
    pool[tid] = s * (1.0f/(float)CC);
    __syncthreads();
    if (tid < 4) {
        int sb = sid[b];
        const float* w = hw + ((size_t)sb*4 + tid)*DD;
        float a = hb[sb*4 + tid];
#pragma unroll 8
        for (int d = 0; d < DD; d++) a = fmaf(pool[d], w[d], a);
        outp[b*4 + tid] = a;
    }
}

extern "C" void kernel_launch(void* const* d_in, const int* in_sizes, int n_in,
                              void* d_out, int out_size, void* d_ws, size_t ws_size,
                              hipStream_t stream) {
    const float* x       = (const float*)d_in[0];
    const int*   sid     = (const int*)  d_in[1];
    const float* conv1_w = (const float*)d_in[2];
    const float* conv1_b = (const float*)d_in[3];
    const float* bn1_g   = (const float*)d_in[4];
    const float* bn1_b   = (const float*)d_in[5];
    const float* bn1_m   = (const float*)d_in[6];
    const float* bn1_v   = (const float*)d_in[7];
    const float* conv2_w = (const float*)d_in[8];
    const float* conv2_b = (const float*)d_in[9];
    const float* bn2_g   = (const float*)d_in[10];
    const float* bn2_b   = (const float*)d_in[11];
    const float* bn2_m   = (const float*)d_in[12];
    const float* bn2_v   = (const float*)d_in[13];
    const float* proj_w  = (const float*)d_in[14];
    const float* proj_b  = (const float*)d_in[15];
    const float* elec    = (const float*)d_in[16];
    const float* qkv_w   = (const float*)d_in[17];
    const float* qkv_b   = (const float*)d_in[18];
    const float* out_w   = (const float*)d_in[19];
    const float* out_b   = (const float*)d_in[20];
    const float* ln1_g   = (const float*)d_in[21];
    const float* ln1_b   = (const float*)d_in[22];
    const float* ff1_w   = (const float*)d_in[23];
    const float* ff1_b   = (const float*)d_in[24];
    const float* ff2_w   = (const float*)d_in[25];
    const float* ff2_b   = (const float*)d_in[26];
    const float* ln2_g   = (const float*)d_in[27];
    const float* ln2_b   = (const float*)d_in[28];
    const float* heads_w = (const float*)d_in[29];
    const float* heads_b = (const float*)d_in[30];
    float* ws = (float*)d_ws;
    const unsigned short* wbf = (const unsigned short*)(ws + WS_WBF);

    prep_kernel<<<(282752 + 255)/256, 256, 0, stream>>>(
        conv1_b, bn1_g, bn1_b, bn1_m, bn1_v,
        conv2_w, conv2_b, bn2_g, bn2_b, bn2_m, bn2_v,
        qkv_w, out_w, ff1_w, ff2_w, ws);

    conv_kernel<<<SEQ, 256, 0, stream>>>(x, conv1_w, proj_w, proj_b, elec, ws, ws + WS_TOK);

    for (int l = 0; l < NLAYER; l++) {
        // qkv = tok @ qkv_w^T + qkv_b      [7808 x 384]
        mfma_gemm<128,0,0,0,0><<<dim3(244,3), 256, 0, stream>>>(
            ws + WS_TOK, wbf + WB_QKV + l*49152, qkv_b + l*384,
            ws + WS_QKV, 384, nullptr, nullptr, nullptr);
        attn_kernel<<<BB*HHEADS, 128, 0, stream>>>(ws + WS_QKV, ws + WS_CTX);
        // tok = LN(tok + ctx @ out_w^T + out_b)
        mfma_gemm<128,0,0,0,1><<<dim3(244,1), 256, 0, stream>>>(
            ws + WS_CTX, wbf + WB_OUT + l*16384, out_b + l*128,
            nullptr, 128, ws + WS_TOK, ln1_g + l*128, ln1_b + l*128);
        // ffh = gelu(tok @ ff1^T + b)  -> bf16 [7808 x 256]
        mfma_gemm<128,0,1,1,0><<<dim3(244,2), 256, 0, stream>>>(
            ws + WS_TOK, wbf + WB_FF1 + l*32768, ff1_b + l*256,
            (void*)(ws + WS_FFH), 256, nullptr, nullptr, nullptr);
        // tok = LN(tok + ffh @ ff2^T + b)
        mfma_gemm<256,1,0,0,1><<<dim3(244,1), 256, 0, stream>>>(
            ws + WS_FFH, wbf + WB_FF2 + l*32768, ff2_b + l*128,
            nullptr, 128, ws + WS_TOK, ln2_g + l*128, ln2_b + l*128);
    }

    final_kernel<<<BB, 128, 0, stream>>>(ws + WS_TOK, sid, heads_w, heads_b, (float*)d_out);
}

// Round 4
// 567.456 us; speedup vs baseline: 5.0976x; 1.1799x over previous
//
#include <hip/hip_runtime.h>
#include <math.h>

#define BB 64
#define CC 122
#define TT 500
#define NCOUT 64
#define DD 128
#define HHEADS 8
#define FFDIM 256
#define NLAYER 2
#define EPS 1e-5f
#define SEQ (BB*CC)   // 7808

// ---------------- workspace float offsets ----------------
#define WS_W2T     0u            // 10240 floats reserved (20480 ushort bf16 w2t [kk][co][ci])
#define WS_S1      20480u        // 64
#define WS_SH1     20544u        // 64
#define WS_S2      20608u        // 64
#define WS_SH2     20672u        // 64
#define WS_WBF     20736u        // 262144 ushorts (=131072 floats): bf16 qkv/out/ff1/ff2 weights
#define WS_TOK     151808u       // 7808*128 = 999424 floats
#define WS_QKV     1151232u      // 7808*384 = 2998272 floats
#define WS_CTX     4149504u      // 999424 floats
#define WS_FFH     5148928u      // (unused now; kept for layout stability)
#define WS_GTAB    6148352u      // 2048 floats: 1024 x (gelu, slope) pairs over [-8,8]
// end = 6150400 floats = 24.6 MB

// WBF internal ushort offsets
#define WB_QKV  0u        // l*49152 + e*128 + k          (2*384*128)
#define WB_OUT  98304u    // l*16384 + e*128 + k          (2*128*128)
#define WB_FF1  131072u   // l*32768 + e*128 + k          (2*256*128)
#define WB_FF2  196608u   // l*32768 + e*256 + k          (2*128*256)

typedef __attribute__((ext_vector_type(8))) short bf16x8;
typedef __attribute__((ext_vector_type(4))) float f32x4;

__device__ __forceinline__ unsigned short f2bf(float f) {
    unsigned int u = __float_as_uint(f);
    unsigned int r = u + 0x7FFFu + ((u >> 16) & 1u);
    return (unsigned short)(r >> 16);
}

// branch-free erf-GELU, Abramowitz-Stegun 7.1.26 (max abs err ~1.5e-7) — used in ff only
__device__ __forceinline__ float gelu_fast(float x) {
    float z = fabsf(x) * 0.70710678118654752f;
    float t = __builtin_amdgcn_rcpf(fmaf(0.3275911f, z, 1.0f));
    float p = fmaf(fmaf(fmaf(fmaf(1.061405429f, t, -1.453152027f), t,
                             1.421413741f), t, -0.284496736f), t, 0.254829592f);
    float e = __expf(-z * z);
    float erf_abs = fmaf(-p * t, e, 1.0f);
    float erf_x = copysignf(erf_abs, x);
    return 0.5f * x * (1.0f + erf_x);
}

// table GELU: 1024 (value,slope) pairs over [-8,8], linear interp, err ~1e-5
__device__ __forceinline__ float gelu_tab(float x, const float* __restrict__ gt) {
    float p = fmaf(x, 64.0f, 512.0f);
    p = fminf(fmaxf(p, 0.0f), 1023.999f);
    float fl = floorf(p);
    int i = (int)fl;
    float fr = p - fl;
    float2 gd = *(const float2*)&gt[2*i];
    float v = fmaf(fr, gd.y, gd.x);
    v = (x > 8.0f) ? x : v;
    v = (x < -8.0f) ? 0.0f : v;
    return v;
}

// ---------------- prep: fold BN, bf16-ify weights, build gelu table ----------------
__global__ void prep_kernel(const float* __restrict__ conv1_b,
                            const float* __restrict__ bn1_g, const float* __restrict__ bn1_b,
                            const float* __restrict__ bn1_m, const float* __restrict__ bn1_v,
                            const float* __restrict__ conv2_w, const float* __restrict__ conv2_b,
                            const float* __restrict__ bn2_g, const float* __restrict__ bn2_b,
                            const float* __restrict__ bn2_m, const float* __restrict__ bn2_v,
                            const float* __restrict__ qkv_w, const float* __restrict__ out_w,
                            const float* __restrict__ ff1_w, const float* __restrict__ ff2_w,
                            float* __restrict__ ws) {
    int idx = blockIdx.x * blockDim.x + threadIdx.x;
    if (idx < 20480) {
        int ci = idx & 63; int co = (idx >> 6) & 63; int kk = idx >> 12;
        unsigned short* wt = (unsigned short*)(ws + WS_W2T);
        wt[idx] = f2bf(conv2_w[(co*64 + ci)*5 + kk]);
    } else if (idx < 20544) {
        int i = idx - 20480;
        float s = bn1_g[i] * rsqrtf(bn1_v[i] + EPS);
        ws[WS_S1 + i] = s;
        ws[WS_SH1 + i] = (conv1_b[i] - bn1_m[i]) * s + bn1_b[i];
    } else if (idx < 20608) {
        int i = idx - 20544;
        float s = bn2_g[i] * rsqrtf(bn2_v[i] + EPS);
        ws[WS_S2 + i] = s;
        ws[WS_SH2 + i] = (conv2_b[i] - bn2_m[i]) * s + bn2_b[i];
    } else if (idx < 282752) {
        int r = idx - 20608;
        unsigned short* wbf = (unsigned short*)(ws + WS_WBF);
        float v;
        if (r < 98304)       v = qkv_w[r];
        else if (r < 131072) v = out_w[r - 98304];
        else if (r < 196608) v = ff1_w[r - 131072];
        else                 v = ff2_w[r - 196608];
        wbf[r] = f2bf(v);
    } else if (idx < 283776) {
        int i = idx - 282752;
        float x0 = (i - 512) * 0.015625f;
        float x1 = x0 + 0.015625f;
        float g0 = 0.5f*x0*(1.0f + erff(x0*0.70710678118654752f));
        float g1 = 0.5f*x1*(1.0f + erff(x1*0.70710678118654752f));
        ws[WS_GTAB + 2*i]     = g0;
        ws[WS_GTAB + 2*i + 1] = g1 - g0;
    }
}

// ---------------- fused conv1(+bn+gelu+pool) + conv2(+bn+gelu+mean) [MFMA] + proj ----
__global__ __launch_bounds__(256, 4) void conv_kernel(const float* __restrict__ x,
            const float* __restrict__ conv1_w,
            const float* __restrict__ proj_w, const float* __restrict__ proj_b,
            const float* __restrict__ elec,
            const float* __restrict__ wsr, float* __restrict__ tok) {
    __shared__ __align__(16) unsigned short h1s[264*64];  // 33792 B
    __shared__ __align__(16) float xls[576];              // zero-padded x row
    __shared__ __align__(16) float gtab[2048];            // gelu table
    __shared__ float part[4*64];
    __shared__ float mean_l[64];
    int n = blockIdx.x;
    int c = n % CC;
    int tid = threadIdx.x;
    int co = tid & 63, tq = tid >> 6;
    const float* xg = x + (size_t)n * TT;

    // stage: zero-pad xls edges, load x row, copy gelu table, zero h1s pad rows
    for (int i = tid; i < 76; i += 256) {
        int a = (i < 8) ? i : (500 + i);
        xls[a] = 0.0f;
    }
    if (tid < 125) {
        float4 v = *(const float4*)(xg + tid*4);
        *(float4*)&xls[8 + tid*4] = v;
    }
    {
        const float4* gsrc = (const float4*)(wsr + WS_GTAB);
        float4* gdst = (float4*)gtab;
        for (int i = tid; i < 512; i += 256) gdst[i] = gsrc[i];
    }
    for (int idx = tid; idx < 14*64; idx += 256) {
        int rr = idx >> 6;
        int r = (rr < 2) ? rr : (rr - 2 + 252);
        h1s[r*64 + (idx & 63)] = 0;
    }
    __syncthreads();

    // ---- phase 1: conv1 (k=9, pad 4) + BN + GELU + maxpool(2) -> h1T bf16 ----
    float w1r[9];
#pragma unroll
    for (int k = 0; k < 9; k++) w1r[k] = conv1_w[co*9 + k];
    float s1 = wsr[WS_S1 + co], sh1 = wsr[WS_SH1 + co];
    for (int tp = tq; tp < 250; tp += 4) {
        const float* xw = &xls[2*tp + 4];   // = x[2tp-4 ..], halo zero-padded
        float a = 0.f, bsum = 0.f;
#pragma unroll
        for (int k = 0; k < 9; k++) { a = fmaf(xw[k], w1r[k], a); bsum = fmaf(xw[k+1], w1r[k], bsum); }
        float g0 = gelu_tab(fmaf(a, s1, sh1), gtab);
        float g1 = gelu_tab(fmaf(bsum, s1, sh1), gtab);
        int r = tp + 2;
        int cp = (co >> 3) ^ (r & 7);
        h1s[r*64 + cp*8 + (co & 7)] = f2bf(fmaxf(g0, g1));
    }
    __syncthreads();

    // ---- phase 2: conv2 as 5 shifted GEMMs via mfma_f32_16x16x32_bf16 ----
    const unsigned short* wt = (const unsigned short*)(wsr + WS_W2T);
    int lane = tid & 63;
    int w = tid >> 6;
    int ln15 = lane & 15, lg = lane >> 4;
    f32x4 acc[4][4];
#pragma unroll
    for (int mi = 0; mi < 4; mi++)
#pragma unroll
        for (int nt = 0; nt < 4; nt++) acc[mi][nt] = (f32x4){0.f, 0.f, 0.f, 0.f};

    const unsigned short* wbase = wt + ln15*64 + lg*8;
#pragma unroll
    for (int kk = 0; kk < 5; kk++) {
#pragma unroll
        for (int s = 0; s < 2; s++) {
            bf16x8 bfv[4];
#pragma unroll
            for (int nt = 0; nt < 4; nt++)
                bfv[nt] = *(const bf16x8*)(wbase + kk*4096 + nt*1024 + s*32);
#pragma unroll
            for (int mi = 0; mi < 4; mi++) {
                int r = (w*4 + mi)*16 + ln15 + kk;
                int cp = (s*4 + lg) ^ (r & 7);
                bf16x8 af = *(const bf16x8*)&h1s[r*64 + cp*8];
#pragma unroll
                for (int nt = 0; nt < 4; nt++)
                    acc[mi][nt] = __builtin_amdgcn_mfma_f32_16x16x32_bf16(af, bfv[nt], acc[mi][nt], 0, 0, 0);
            }
        }
    }

    // ---- epilogue: BN + GELU + mean over t ----
#pragma unroll
    for (int nt = 0; nt < 4; nt++) {
        int co2 = nt*16 + ln15;
        float sc = wsr[WS_S2 + co2], sh = wsr[WS_SH2 + co2];
        float p = 0.f;
#pragma unroll
        for (int mi = 0; mi < 4; mi++) {
            int tbase = (w*4 + mi)*16 + lg*4;
#pragma unroll
            for (int i = 0; i < 4; i++) {
                if (tbase + i < 250)
                    p += gelu_tab(fmaf(acc[mi][nt][i], sc, sh), gtab);
            }
        }
        p += __shfl_down(p, 32, 64);
        p += __shfl_down(p, 16, 64);
        if (lane < 16) part[w*64 + co2] = p;
    }
    __syncthreads();
    if (tid < 64) {
        mean_l[tid] = (part[tid] + part[64+tid] + part[128+tid] + part[192+tid]) * (1.0f/250.0f);
    }
    __syncthreads();

    if (tid < DD) {
        int d = tid;
        float a = proj_b[d] + elec[c*DD + d];
#pragma unroll 8
        for (int o = 0; o < 64; o++) a = fmaf(mean_l[o], proj_w[d*64 + o], a);
        tok[(size_t)n * DD + d] = a;
    }
}

// ---------------- bf16 MFMA GEMM, M-tile 32, N-tile 128 per blockIdx.y ----
template<int K, int GELUF, int LNF>
__global__ __launch_bounds__(256) void mfma_gemm(const float* __restrict__ Aptr,
        const unsigned short* __restrict__ Bbf,
        const float* __restrict__ bias,
        float* __restrict__ Cptr, int ldC,
        float* __restrict__ tokres,
        const float* __restrict__ lng, const float* __restrict__ lnb) {
    const int tid = threadIdx.x;
    const int m0 = blockIdx.x * 32;
    const int n0 = blockIdx.y * 128;
    __shared__ __align__(16) unsigned short As[32*K];
    __shared__ float Cs[LNF ? 32*129 : 1];

    const float* A = Aptr + (size_t)m0 * K;
    for (int i = tid; i < 8*K; i += 256) {
        int m = i / (K/4); int kq = (i - m*(K/4))*4;
        float4 v = *(const float4*)(A + m*K + kq);
        int cp = (kq >> 3) ^ (m & 15);
        short4 s4 = make_short4((short)f2bf(v.x), (short)f2bf(v.y),
                                (short)f2bf(v.z), (short)f2bf(v.w));
        *(short4*)&As[m*K + cp*8 + (kq & 7)] = s4;
    }
    __syncthreads();

    const int lane = tid & 63, w = tid >> 6;
    const int ln15 = lane & 15, lg = lane >> 4;
    f32x4 acc[2][2];
#pragma unroll
    for (int mi = 0; mi < 2; mi++)
#pragma unroll
        for (int ni = 0; ni < 2; ni++) acc[mi][ni] = (f32x4){0.f, 0.f, 0.f, 0.f};

    const unsigned short* Bb = Bbf + (size_t)n0 * K;
#pragma unroll
    for (int kt = 0; kt < K/32; kt++) {
        bf16x8 af[2], bfv[2];
#pragma unroll
        for (int mi = 0; mi < 2; mi++) {
            int m = mi*16 + ln15;
            int cp = (kt*4 + lg) ^ (m & 15);
            af[mi] = *(const bf16x8*)&As[m*K + cp*8];
        }
#pragma unroll
        for (int ni = 0; ni < 2; ni++) {
            int nn = (w*2 + ni)*16 + ln15;
            bfv[ni] = *(const bf16x8*)&Bb[(size_t)nn*K + kt*32 + lg*8];
        }
#pragma unroll
        for (int mi = 0; mi < 2; mi++)
#pragma unroll
            for (int ni = 0; ni < 2; ni++)
                acc[mi][ni] = __builtin_amdgcn_mfma_f32_16x16x32_bf16(af[mi], bfv[ni], acc[mi][ni], 0, 0, 0);
    }

#pragma unroll
    for (int mi = 0; mi < 2; mi++)
#pragma unroll
        for (int ni = 0; ni < 2; ni++) {
            int nloc = (w*2 + ni)*16 + ln15;
            int nn = n0 + nloc;
            float bn = bias[nn];
#pragma unroll
            for (int i = 0; i < 4; i++) {
                int ml = mi*16 + lg*4 + i;
                float v = acc[mi][ni][i] + bn;
                if (GELUF) v = gelu_fast(v);
                if (LNF) {
                    Cs[ml*129 + nloc] = v + tokres[(size_t)(m0 + ml)*128 + nloc];
                } else {
                    Cptr[(size_t)(m0 + ml)*ldC + nn] = v;
                }
            }
        }

    if (LNF) {
        __syncthreads();
        int r = tid >> 3, sub = tid & 7;
        float s1 = 0.f, s2 = 0.f;
#pragma unroll
        for (int j = 0; j < 16; j++) {
            float vv = Cs[r*129 + sub*16 + j];
            s1 += vv; s2 += vv*vv;
        }
        s1 += __shfl_down(s1, 4, 64); s2 += __shfl_down(s2, 4, 64);
        s1 += __shfl_down(s1, 2, 64); s2 += __shfl_down(s2, 2, 64);
        s1 += __shfl_down(s1, 1, 64); s2 += __shfl_down(s2, 1, 64);
        int lb = lane & 56;
        s1 = __shfl(s1, lb, 64); s2 = __shfl(s2, lb, 64);
        float mu = s1 * (1.0f/128.0f);
        float var = s2 * (1.0f/128.0f) - mu*mu;
        float rstd = rsqrtf(var + EPS);
#pragma unroll
        for (int j = 0; j < 16; j++) {
            int nloc = sub*16 + j;
            float vv = (Cs[r*129 + nloc] - mu) * rstd * lng[nloc] + lnb[nloc];
            tokres[(size_t)(m0 + r)*128 + nloc] = vv;
        }
    }
}

// ---------------- fused FF block: H=gelu(tok@ff1^T+b1); tok=LN(tok + H@ff2^T+b2) ----
__global__ __launch_bounds__(256) void ff_fused(const float* __restrict__ tok,
        const unsigned short* __restrict__ B1, const float* __restrict__ b1,
        const unsigned short* __restrict__ B2, const float* __restrict__ b2,
        float* __restrict__ tokres,
        const float* __restrict__ lng, const float* __restrict__ lnb) {
    const int tid = threadIdx.x;
    const int m0 = blockIdx.x * 32;
    __shared__ __align__(16) unsigned short As[32*128];   // 8 KB
    __shared__ __align__(16) unsigned short Hs[32*256];   // 16 KB
    __shared__ float Cs[32*129];                          // 16.5 KB

    const float* A = tok + (size_t)m0 * 128;
    for (int i = tid; i < 8*128; i += 256) {
        int m = i >> 5; int kq = (i & 31) * 4;
        float4 v = *(const float4*)(A + m*128 + kq);
        int cp = (kq >> 3) ^ (m & 15);
        short4 s4 = make_short4((short)f2bf(v.x), (short)f2bf(v.y),
                                (short)f2bf(v.z), (short)f2bf(v.w));
        *(short4*)&As[m*128 + cp*8 + (kq & 7)] = s4;
    }
    __syncthreads();

    const int lane = tid & 63, w = tid >> 6;
    const int ln15 = lane & 15, lg = lane >> 4;

    // ---- ff1: M=32, N=256 (wave w owns cols w*64..w*64+63), K=128 ----
    f32x4 acc1[2][4];
#pragma unroll
    for (int mi = 0; mi < 2; mi++)
#pragma unroll
        for (int ni = 0; ni < 4; ni++) acc1[mi][ni] = (f32x4){0.f, 0.f, 0.f, 0.f};
#pragma unroll
    for (int kt = 0; kt < 4; kt++) {
        bf16x8 af[2];
#pragma unroll
        for (int mi = 0; mi < 2; mi++) {
            int m = mi*16 + ln15;
            int cp = (kt*4 + lg) ^ (m & 15);
            af[mi] = *(const bf16x8*)&As[m*128 + cp*8];
        }
#pragma unroll
        for (int ni = 0; ni < 4; ni++) {
            int nn = w*64 + ni*16 + ln15;
            bf16x8 bfv = *(const bf16x8*)&B1[(size_t)nn*128 + kt*32 + lg*8];
#pragma unroll
            for (int mi = 0; mi < 2; mi++)
                acc1[mi][ni] = __builtin_amdgcn_mfma_f32_16x16x32_bf16(af[mi], bfv, acc1[mi][ni], 0, 0, 0);
        }
    }
    // bias + gelu -> Hs (bf16, swizzled as A-layout for ff2)
#pragma unroll
    for (int ni = 0; ni < 4; ni++) {
        int nn = w*64 + ni*16 + ln15;
        float bb = b1[nn];
#pragma unroll
        for (int mi = 0; mi < 2; mi++)
#pragma unroll
            for (int i = 0; i < 4; i++) {
                int m = mi*16 + lg*4 + i;
                float v = gelu_fast(acc1[mi][ni][i] + bb);
                int cp = ((nn >> 3) ^ (m & 15));
                Hs[m*256 + cp*8 + (nn & 7)] = f2bf(v);
            }
    }
    __syncthreads();

    // ---- ff2: M=32, N=128, K=256 ----
    f32x4 acc2[2][2];
#pragma unroll
    for (int mi = 0; mi < 2; mi++)
#pragma unroll
        for (int ni = 0; ni < 2; ni++) acc2[mi][ni] = (f32x4){0.f, 0.f, 0.f, 0.f};
#pragma unroll
    for (int kt = 0; kt < 8; kt++) {
        bf16x8 af[2];
#pragma unroll
        for (int mi = 0; mi < 2; mi++) {
            int m = mi*16 + ln15;
            int cp = (kt*4 + lg) ^ (m & 15);
            af[mi] = *(const bf16x8*)&Hs[m*256 + cp*8];
        }
#pragma unroll
        for (int ni = 0; ni < 2; ni++) {
            int nn = (w*2 + ni)*16 + ln15;
            bf16x8 bfv = *(const bf16x8*)&B2[(size_t)nn*256 + kt*32 + lg*8];
#pragma unroll
            for (int mi = 0; mi < 2; mi++)
                acc2[mi][ni] = __builtin_amdgcn_mfma_f32_16x16x32_bf16(af[mi], bfv, acc2[mi][ni], 0, 0, 0);
        }
    }
    // bias + residual -> Cs
#pragma unroll
    for (int mi = 0; mi < 2; mi++)
#pragma unroll
        for (int ni = 0; ni < 2; ni++) {
            int nloc = (w*2 + ni)*16 + ln15;
            float bb = b2[nloc];
#pragma unroll
            for (int i = 0; i < 4; i++) {
                int ml = mi*16 + lg*4 + i;
                Cs[ml*129 + nloc] = acc2[mi][ni][i] + bb + tokres[(size_t)(m0 + ml)*128 + nloc];
            }
        }
    __syncthreads();

    // rowwise LN
    int r = tid >> 3, sub = tid & 7;
    float s1 = 0.f, s2 = 0.f;
#pragma unroll
    for (int j = 0; j < 16; j++) {
        float vv = Cs[r*129 + sub*16 + j];
        s1 += vv; s2 += vv*vv;
    }
    s1 += __shfl_down(s1, 4, 64); s2 += __shfl_down(s2, 4, 64);
    s1 += __shfl_down(s1, 2, 64); s2 += __shfl_down(s2, 2, 64);
    s1 += __shfl_down(s1, 1, 64); s2 += __shfl_down(s2, 1, 64);
    int lb = lane & 56;
    s1 = __shfl(s1, lb, 64); s2 = __shfl(s2, lb, 64);
    float mu = s1 * (1.0f/128.0f);
    float var = s2 * (1.0f/128.0f) - mu*mu;
    float rstd = rsqrtf(var + EPS);
#pragma unroll
    for (int j = 0; j < 16; j++) {
        int nloc = sub*16 + j;
        float vv = (Cs[r*129 + nloc] - mu) * rstd * lng[nloc] + lnb[nloc];
        tokres[(size_t)(m0 + r)*128 + nloc] = vv;
    }
}

// ---------------- attention: one block per (b, h) ----------------
__global__ __launch_bounds__(128) void attn_kernel(const float* __restrict__ qkv,
                                                   float* __restrict__ ctx) {
    __shared__ float qs[CC*16], ks[CC*16], vs[CC*16];
    int b = blockIdx.x >> 3, h = blockIdx.x & 7;
    int tid = threadIdx.x;
    const float* basep = qkv + (size_t)b*CC*384;
    for (int idx = tid; idx < CC*16; idx += 128) {
        int s = idx >> 4, d = idx & 15;
        qs[idx] = basep[s*384 +        h*16 + d];
        ks[idx] = basep[s*384 + 128 + h*16 + d];
        vs[idx] = basep[s*384 + 256 + h*16 + d];
    }
    __syncthreads();
    int i = tid;
    if (i < CC) {
        float q[16];
#pragma unroll
        for (int d = 0; d < 16; d++) q[d] = qs[i*16+d];
        float mx = -1e30f;
        for (int j = 0; j < CC; j++) {
            float s = 0.f;
#pragma unroll
            for (int d = 0; d < 16; d++) s = fmaf(q[d], ks[j*16+d], s);
            mx = fmaxf(mx, s * 0.25f);
        }
        float sum = 0.f;
        float acc[16];
#pragma unroll
        for (int d = 0; d < 16; d++) acc[d] = 0.f;
        for (int j = 0; j < CC; j++) {
            float s = 0.f;
#pragma unroll
            for (int d = 0; d < 16; d++) s = fmaf(q[d], ks[j*16+d], s);
            float e = __expf(s * 0.25f - mx);
            sum += e;
#pragma unroll
            for (int d = 0; d < 16; d++) acc[d] = fmaf(e, vs[j*16+d], acc[d]);
        }
        float r = __builtin_amdgcn_rcpf(sum);
        float* op = ctx + ((size_t)b*CC + i)*DD + h*16;
#pragma unroll
        for (int d = 0; d < 16; d++) op[d] = acc[d] * r;
    }
}

// ---------------- final: mean over C + subject head ----------------
__global__ __launch_bounds__(128) void final_kernel(const float* __restrict__ tok,
        const int* __restrict__ sid,
        const float* __restrict__ hw, const float* __restrict__ hb,
        float* __restrict__ outp) {
    __shared__ float pool[DD];
    int b = blockIdx.x, tid = threadIdx.x;
    float s = 0.f;
    for (int c2 = 0; c2 < CC; c2++) s += tok[((size_t)b*CC + c2)*DD + tid];
    pool[tid] = s * (1.0f/(float)CC);
    __syncthreads();
    if (tid < 4) {
        int sb = sid[b];
        const float* w = hw + ((size_t)sb*4 + tid)*DD;
        float a = hb[sb*4 + tid];
#pragma unroll 8
        for (int d = 0; d < DD; d++) a = fmaf(pool[d], w[d], a);
        outp[b*4 + tid] = a;
    }
}

extern "C" void kernel_launch(void* const* d_in, const int* in_sizes, int n_in,
                              void* d_out, int out_size, void* d_ws, size_t ws_size,
                              hipStream_t stream) {
    const float* x       = (const float*)d_in[0];
    const int*   sid     = (const int*)  d_in[1];
    const float* conv1_w = (const float*)d_in[2];
    const float* conv1_b = (const float*)d_in[3];
    const float* bn1_g   = (const float*)d_in[4];
    const float* bn1_b   = (const float*)d_in[5];
    const float* bn1_m   = (const float*)d_in[6];
    const float* bn1_v   = (const float*)d_in[7];
    const float* conv2_w = (const float*)d_in[8];
    const float* conv2_b = (const float*)d_in[9];
    const float* bn2_g   = (const float*)d_in[10];
    const float* bn2_b   = (const float*)d_in[11];
    const float* bn2_m   = (const float*)d_in[12];
    const float* bn2_v   = (const float*)d_in[13];
    const float* proj_w  = (const float*)d_in[14];
    const float* proj_b  = (const float*)d_in[15];
    const float* elec    = (const float*)d_in[16];
    const float* qkv_w   = (const float*)d_in[17];
    const float* qkv_b   = (const float*)d_in[18];
    const float* out_w   = (const float*)d_in[19];
    const float* out_b   = (const float*)d_in[20];
    const float* ln1_g   = (const float*)d_in[21];
    const float* ln1_b   = (const float*)d_in[22];
    const float* ff1_w   = (const float*)d_in[23];
    const float* ff1_b   = (const float*)d_in[24];
    const float* ff2_w   = (const float*)d_in[25];
    const float* ff2_b   = (const float*)d_in[26];
    const float* ln2_g   = (const float*)d_in[27];
    const float* ln2_b   = (const float*)d_in[28];
    const float* heads_w = (const float*)d_in[29];
    const float* heads_b = (const float*)d_in[30];
    float* ws = (float*)d_ws;
    const unsigned short* wbf = (const unsigned short*)(ws + WS_WBF);

    prep_kernel<<<(283776 + 255)/256, 256, 0, stream>>>(
        conv1_b, bn1_g, bn1_b, bn1_m, bn1_v,
        conv2_w, conv2_b, bn2_g, bn2_b, bn2_m, bn2_v,
        qkv_w, out_w, ff1_w, ff2_w, ws);

    conv_kernel<<<SEQ, 256, 0, stream>>>(x, conv1_w, proj_w, proj_b, elec, ws, ws + WS_TOK);

    for (int l = 0; l < NLAYER; l++) {
        // qkv = tok @ qkv_w^T + qkv_b      [7808 x 384]
        mfma_gemm<128,0,0><<<dim3(244,3), 256, 0, stream>>>(
            ws + WS_TOK, wbf + WB_QKV + l*49152, qkv_b + l*384,
            ws + WS_QKV, 384, nullptr, nullptr, nullptr);
        attn_kernel<<<BB*HHEADS, 128, 0, stream>>>(ws + WS_QKV, ws + WS_CTX);
        // tok = LN(tok + ctx @ out_w^T + out_b)
        mfma_gemm<128,0,1><<<dim3(244,1), 256, 0, stream>>>(
            ws + WS_CTX, wbf + WB_OUT + l*16384, out_b + l*128,
            nullptr, 128, ws + WS_TOK, ln1_g + l*128, ln1_b + l*128);
        // tok = LN(tok + gelu(tok@ff1^T+b1)@ff2^T + b2)  — fused
        ff_fused<<<244, 256, 0, stream>>>(
            ws + WS_TOK, wbf + WB_FF1 + l*32768, ff1_b + l*256,
            wbf + WB_FF2 + l*32768, ff2_b + l*128,
            ws + WS_TOK, ln2_g + l*128, ln2_b + l*128);
    }

    final_kernel<<<BB, 128, 0, stream>>>(ws + WS_TOK, sid, heads_w, heads_b, (float*)d_out);
}

// Round 5
// 485.950 us; speedup vs baseline: 5.9526x; 1.1677x over previous
//
#include <hip/hip_runtime.h>
#include <math.h>

#define BB 64
#define CC 122
#define TT 500
#define NCOUT 64
#define DD 128
#define HHEADS 8
#define FFDIM 256
#define NLAYER 2
#define EPS 1e-5f
#define SEQ (BB*CC)   // 7808

// ---------------- workspace float offsets ----------------
#define WS_W2T     0u            // 20480 ushort bf16 w2t [kk][co][ci]
#define WS_S1      20480u        // 64
#define WS_SH1     20544u        // 64
#define WS_S2      20608u        // 64
#define WS_SH2     20672u        // 64
#define WS_WBF     20736u        // 262144 ushorts: bf16 qkv/out/ff1/ff2 weights
#define WS_TOK     151808u       // 7808*128 floats
#define WS_QKV     1151232u      // 7808*384 floats
#define WS_CTX     4149504u      // 999424 floats
#define WS_GTAB    6148352u      // 1024 floats: 512 x (gelu, delta) pairs over [-8,8]
#define WS_W1S     6149376u      // 1024 floats = 2048 ushorts: bf16 w1s[co][k=32], BN-scale folded
// end = 6150400 floats = 24.6 MB

// WBF internal ushort offsets
#define WB_QKV  0u        // l*49152 + e*128 + k
#define WB_OUT  98304u    // l*16384 + e*128 + k
#define WB_FF1  131072u   // l*32768 + e*128 + k
#define WB_FF2  196608u   // l*32768 + e*256 + k

typedef __attribute__((ext_vector_type(8))) short bf16x8;
typedef __attribute__((ext_vector_type(4))) float f32x4;

__device__ __forceinline__ unsigned short f2bf(float f) {
    unsigned int u = __float_as_uint(f);
    unsigned int r = u + 0x7FFFu + ((u >> 16) & 1u);
    return (unsigned short)(r >> 16);
}

// branch-free erf-GELU (A&S 7.1.26) — used only in ff1 epilogue (2M calls)
__device__ __forceinline__ float gelu_fast(float x) {
    float z = fabsf(x) * 0.70710678118654752f;
    float t = __builtin_amdgcn_rcpf(fmaf(0.3275911f, z, 1.0f));
    float p = fmaf(fmaf(fmaf(fmaf(1.061405429f, t, -1.453152027f), t,
                             1.421413741f), t, -0.284496736f), t, 0.254829592f);
    float e = __expf(-z * z);
    float erf_abs = fmaf(-p * t, e, 1.0f);
    float erf_x = copysignf(erf_abs, x);
    return 0.5f * x * (1.0f + erf_x);
}

// table GELU: 512 (value,delta) pairs over [-8,8]; inputs provably within ±6 here
__device__ __forceinline__ float gelu_tab(float x, const float* __restrict__ gt) {
    float p = fmaf(x, 32.0f, 256.0f);
    p = fminf(fmaxf(p, 0.0f), 511.999f);
    int i = (int)p;
    float fr = p - (float)i;
    float2 gd = *(const float2*)&gt[2*i];
    return fmaf(fr, gd.y, gd.x);
}

// ---------------- prep: fold BN, bf16-ify weights, build tables ----------------
__global__ void prep_kernel(const float* __restrict__ conv1_w, const float* __restrict__ conv1_b,
                            const float* __restrict__ bn1_g, const float* __restrict__ bn1_b,
                            const float* __restrict__ bn1_m, const float* __restrict__ bn1_v,
                            const float* __restrict__ conv2_w, const float* __restrict__ conv2_b,
                            const float* __restrict__ bn2_g, const float* __restrict__ bn2_b,
                            const float* __restrict__ bn2_m, const float* __restrict__ bn2_v,
                            const float* __restrict__ qkv_w, const float* __restrict__ out_w,
                            const float* __restrict__ ff1_w, const float* __restrict__ ff2_w,
                            float* __restrict__ ws) {
    int idx = blockIdx.x * blockDim.x + threadIdx.x;
    if (idx < 20480) {
        int ci = idx & 63; int co = (idx >> 6) & 63; int kk = idx >> 12;
        unsigned short* wt = (unsigned short*)(ws + WS_W2T);
        wt[idx] = f2bf(conv2_w[(co*64 + ci)*5 + kk]);
    } else if (idx < 20544) {
        int i = idx - 20480;
        float s = bn1_g[i] * rsqrtf(bn1_v[i] + EPS);
        ws[WS_S1 + i] = s;
        ws[WS_SH1 + i] = (conv1_b[i] - bn1_m[i]) * s + bn1_b[i];
    } else if (idx < 20608) {
        int i = idx - 20544;
        float s = bn2_g[i] * rsqrtf(bn2_v[i] + EPS);
        ws[WS_S2 + i] = s;
        ws[WS_SH2 + i] = (conv2_b[i] - bn2_m[i]) * s + bn2_b[i];
    } else if (idx < 282752) {
        int r = idx - 20608;
        unsigned short* wbf = (unsigned short*)(ws + WS_WBF);
        float v;
        if (r < 98304)       v = qkv_w[r];
        else if (r < 131072) v = out_w[r - 98304];
        else if (r < 196608) v = ff1_w[r - 131072];
        else                 v = ff2_w[r - 196608];
        wbf[r] = f2bf(v);
    } else if (idx < 283264) {
        int i = idx - 282752;
        float x0 = (i - 256) * 0.03125f;
        float x1 = x0 + 0.03125f;
        float g0 = 0.5f*x0*(1.0f + erff(x0*0.70710678118654752f));
        float g1 = 0.5f*x1*(1.0f + erff(x1*0.70710678118654752f));
        ws[WS_GTAB + 2*i]     = g0;
        ws[WS_GTAB + 2*i + 1] = g1 - g0;
    } else if (idx < 285312) {
        int i = idx - 283264;            // co*32 + k
        int co = i >> 5, k = i & 31;
        unsigned short* w1s = (unsigned short*)(ws + WS_W1S);
        float s = bn1_g[co] * rsqrtf(bn1_v[co] + EPS);
        w1s[i] = (k < 9) ? f2bf(conv1_w[co*9 + k] * s) : (unsigned short)0;
    }
}

// ---------------- fused conv1 [MFMA] + pool + conv2 [MFMA] + mean + proj ----------------
__global__ __launch_bounds__(256, 4) void conv_kernel(const float* __restrict__ x,
            const float* __restrict__ proj_w, const float* __restrict__ proj_b,
            const float* __restrict__ elec,
            const float* __restrict__ wsr, float* __restrict__ tok) {
    __shared__ __align__(16) unsigned short h1s[264*64];  // 33792 B
    __shared__ __align__(16) unsigned short xbf[544];     // 1088 B (x bf16, halo-padded)
    __shared__ __align__(16) float gtab[1024];            // 4096 B
    __shared__ float part[256];                           // 1024 B
    __shared__ float mean_l[64];                          // 256 B
    int n = blockIdx.x;
    int c = n % CC;
    int tid = threadIdx.x;
    const float* xg = x + (size_t)n * TT;

    // stage: xbf[i] = bf16(x[i-4]) for i in [4,504), zeros elsewhere; gelu table; h1s pad rows
    for (int i = tid; i < 544; i += 256) {
        unsigned short v = 0;
        if (i >= 4 && i < 504) v = f2bf(xg[i-4]);
        xbf[i] = v;
    }
    {
        const float4* gsrc = (const float4*)(wsr + WS_GTAB);
        float4* gdst = (float4*)gtab;
        if (tid < 256) gdst[tid] = gsrc[tid];
    }
    for (int idx = tid; idx < 14*64; idx += 256) {
        int rr = idx >> 6;
        int r = (rr < 2) ? rr : (rr - 2 + 252);
        h1s[r*64 + (idx & 63)] = 0;
    }
    __syncthreads();

    int lane = tid & 63;
    int w = tid >> 6;
    int ln15 = lane & 15, lg = lane >> 4;

    // ---- phase 1: conv1 (k=9, pad 4, BN-folded) via MFMA im2col + GELU + maxpool(2) ----
    {
        const unsigned short* w1s = (const unsigned short*)(wsr + WS_W1S);
        bf16x8 b1f[4];
        float sh1v[4];
#pragma unroll
        for (int nt = 0; nt < 4; nt++) {
            int co = nt*16 + ln15;
            b1f[nt] = *(const bf16x8*)&w1s[co*32 + lg*8];
            sh1v[nt] = wsr[WS_SH1 + co];
        }
        bool km[8];
#pragma unroll
        for (int j = 0; j < 8; j++) km[j] = (lg*8 + j) < 9;

        for (int mi = 0; mi < 8; mi++) {
            int mt = w*8 + mi;
            int t = mt*16 + ln15;
            short e[8];
#pragma unroll
            for (int j = 0; j < 8; j++) {
                unsigned short vv = xbf[t + lg*8 + j];
                e[j] = km[j] ? (short)vv : (short)0;
            }
            bf16x8 af = {e[0],e[1],e[2],e[3],e[4],e[5],e[6],e[7]};
#pragma unroll
            for (int nt = 0; nt < 4; nt++) {
                f32x4 cacc = __builtin_amdgcn_mfma_f32_16x16x32_bf16(af, b1f[nt],
                                (f32x4){0.f,0.f,0.f,0.f}, 0, 0, 0);
                // c[i] = conv1 at t' = mt*16 + lg*4 + i, channel co = nt*16+ln15
                float g0 = gelu_tab(cacc[0] + sh1v[nt], gtab);
                float g1 = gelu_tab(cacc[1] + sh1v[nt], gtab);
                float g2 = gelu_tab(cacc[2] + sh1v[nt], gtab);
                float g3 = gelu_tab(cacc[3] + sh1v[nt], gtab);
                int tpA = mt*8 + lg*2;          // even; tpA<250 => tpA+1<250 too
                if (tpA < 250) {
                    int co = nt*16 + ln15;
                    int r = tpA + 2;
                    int cp = (co >> 3) ^ (r & 7);
                    h1s[r*64 + cp*8 + (co & 7)] = f2bf(fmaxf(g0, g1));
                    int r2 = r + 1;
                    int cp2 = (co >> 3) ^ (r2 & 7);
                    h1s[r2*64 + cp2*8 + (co & 7)] = f2bf(fmaxf(g2, g3));
                }
            }
        }
    }
    __syncthreads();

    // ---- phase 2: conv2 as 5 shifted GEMMs via mfma_f32_16x16x32_bf16 ----
    const unsigned short* wt = (const unsigned short*)(wsr + WS_W2T);
    f32x4 acc[4][4];
#pragma unroll
    for (int mi = 0; mi < 4; mi++)
#pragma unroll
        for (int nt = 0; nt < 4; nt++) acc[mi][nt] = (f32x4){0.f, 0.f, 0.f, 0.f};

    const unsigned short* wbase = wt + ln15*64 + lg*8;
#pragma unroll
    for (int kk = 0; kk < 5; kk++) {
#pragma unroll
        for (int s = 0; s < 2; s++) {
            bf16x8 bfv[4];
#pragma unroll
            for (int nt = 0; nt < 4; nt++)
                bfv[nt] = *(const bf16x8*)(wbase + kk*4096 + nt*1024 + s*32);
#pragma unroll
            for (int mi = 0; mi < 4; mi++) {
                int r = (w*4 + mi)*16 + ln15 + kk;
                int cp = (s*4 + lg) ^ (r & 7);
                bf16x8 af = *(const bf16x8*)&h1s[r*64 + cp*8];
#pragma unroll
                for (int nt = 0; nt < 4; nt++)
                    acc[mi][nt] = __builtin_amdgcn_mfma_f32_16x16x32_bf16(af, bfv[nt], acc[mi][nt], 0, 0, 0);
            }
        }
    }

    // ---- epilogue: BN + GELU + mean over t ----
#pragma unroll
    for (int nt = 0; nt < 4; nt++) {
        int co2 = nt*16 + ln15;
        float sc = wsr[WS_S2 + co2], sh = wsr[WS_SH2 + co2];
        float p = 0.f;
#pragma unroll
        for (int mi = 0; mi < 4; mi++) {
            int tbase = (w*4 + mi)*16 + lg*4;
#pragma unroll
            for (int i = 0; i < 4; i++) {
                if (tbase + i < 250)
                    p += gelu_tab(fmaf(acc[mi][nt][i], sc, sh), gtab);
            }
        }
        p += __shfl_down(p, 32, 64);
        p += __shfl_down(p, 16, 64);
        if (lane < 16) part[w*64 + co2] = p;
    }
    __syncthreads();
    if (tid < 64) {
        mean_l[tid] = (part[tid] + part[64+tid] + part[128+tid] + part[192+tid]) * (1.0f/250.0f);
    }
    __syncthreads();

    if (tid < DD) {
        int d = tid;
        float a = proj_b[d] + elec[c*DD + d];
#pragma unroll 8
        for (int o = 0; o < 64; o++) a = fmaf(mean_l[o], proj_w[d*64 + o], a);
        tok[(size_t)n * DD + d] = a;
    }
}

// ---------------- bf16 MFMA GEMM (qkv): M-tile 32, N-tile 128 per blockIdx.y ----
template<int K>
__global__ __launch_bounds__(256) void mfma_gemm(const float* __restrict__ Aptr,
        const unsigned short* __restrict__ Bbf,
        const float* __restrict__ bias,
        float* __restrict__ Cptr, int ldC) {
    const int tid = threadIdx.x;
    const int m0 = blockIdx.x * 32;
    const int n0 = blockIdx.y * 128;
    __shared__ __align__(16) unsigned short As[32*K];

    const float* A = Aptr + (size_t)m0 * K;
    for (int i = tid; i < 8*K; i += 256) {
        int m = i / (K/4); int kq = (i - m*(K/4))*4;
        float4 v = *(const float4*)(A + m*K + kq);
        int cp = (kq >> 3) ^ (m & 15);
        short4 s4 = make_short4((short)f2bf(v.x), (short)f2bf(v.y),
                                (short)f2bf(v.z), (short)f2bf(v.w));
        *(short4*)&As[m*K + cp*8 + (kq & 7)] = s4;
    }
    __syncthreads();

    const int lane = tid & 63, w = tid >> 6;
    const int ln15 = lane & 15, lg = lane >> 4;
    f32x4 acc[2][2];
#pragma unroll
    for (int mi = 0; mi < 2; mi++)
#pragma unroll
        for (int ni = 0; ni < 2; ni++) acc[mi][ni] = (f32x4){0.f, 0.f, 0.f, 0.f};

    const unsigned short* Bb = Bbf + (size_t)n0 * K;
#pragma unroll
    for (int kt = 0; kt < K/32; kt++) {
        bf16x8 af[2], bfv[2];
#pragma unroll
        for (int mi = 0; mi < 2; mi++) {
            int m = mi*16 + ln15;
            int cp = (kt*4 + lg) ^ (m & 15);
            af[mi] = *(const bf16x8*)&As[m*K + cp*8];
        }
#pragma unroll
        for (int ni = 0; ni < 2; ni++) {
            int nn = (w*2 + ni)*16 + ln15;
            bfv[ni] = *(const bf16x8*)&Bb[(size_t)nn*K + kt*32 + lg*8];
        }
#pragma unroll
        for (int mi = 0; mi < 2; mi++)
#pragma unroll
            for (int ni = 0; ni < 2; ni++)
                acc[mi][ni] = __builtin_amdgcn_mfma_f32_16x16x32_bf16(af[mi], bfv[ni], acc[mi][ni], 0, 0, 0);
    }

#pragma unroll
    for (int mi = 0; mi < 2; mi++)
#pragma unroll
        for (int ni = 0; ni < 2; ni++) {
            int nloc = (w*2 + ni)*16 + ln15;
            int nn = n0 + nloc;
            float bn = bias[nn];
#pragma unroll
            for (int i = 0; i < 4; i++) {
                int ml = mi*16 + lg*4 + i;
                Cptr[(size_t)(m0 + ml)*ldC + nn] = acc[mi][ni][i] + bn;
            }
        }
}

// ---------------- fused layer tail: tok=LN1(tok+ctx@outW+b); tok=LN2(tok+ff(tok)) ----
__global__ __launch_bounds__(256) void layer_tail(const float* __restrict__ ctx,
        const unsigned short* __restrict__ outW, const float* __restrict__ outb,
        float* __restrict__ tok,
        const float* __restrict__ ln1g, const float* __restrict__ ln1b,
        const unsigned short* __restrict__ B1, const float* __restrict__ b1,
        const unsigned short* __restrict__ B2, const float* __restrict__ b2,
        const float* __restrict__ ln2g, const float* __restrict__ ln2b) {
    const int tid = threadIdx.x;
    const int m0 = blockIdx.x * 32;
    __shared__ __align__(16) unsigned short As[32*128];   // 8 KB  (ctx, then LN1 out)
    __shared__ __align__(16) unsigned short Hs[32*256];   // 16 KB
    __shared__ float Cs[32*129];                          // 16.5 KB

    // stage ctx -> As (bf16 swizzled)
    const float* A = ctx + (size_t)m0 * 128;
    for (int i = tid; i < 1024; i += 256) {
        int m = i >> 5; int kq = (i & 31) * 4;
        float4 v = *(const float4*)(A + m*128 + kq);
        int cp = (kq >> 3) ^ (m & 15);
        short4 s4 = make_short4((short)f2bf(v.x), (short)f2bf(v.y),
                                (short)f2bf(v.z), (short)f2bf(v.w));
        *(short4*)&As[m*128 + cp*8 + (kq & 7)] = s4;
    }
    __syncthreads();

    const int lane = tid & 63, w = tid >> 6;
    const int ln15 = lane & 15, lg = lane >> 4;

    // ---- out-proj: M=32, N=128, K=128 ----
    {
        f32x4 acc[2][2];
#pragma unroll
        for (int mi = 0; mi < 2; mi++)
#pragma unroll
            for (int ni = 0; ni < 2; ni++) acc[mi][ni] = (f32x4){0.f, 0.f, 0.f, 0.f};
#pragma unroll
        for (int kt = 0; kt < 4; kt++) {
            bf16x8 af[2], bfv[2];
#pragma unroll
            for (int mi = 0; mi < 2; mi++) {
                int m = mi*16 + ln15;
                int cp = (kt*4 + lg) ^ (m & 15);
                af[mi] = *(const bf16x8*)&As[m*128 + cp*8];
            }
#pragma unroll
            for (int ni = 0; ni < 2; ni++) {
                int nn = (w*2 + ni)*16 + ln15;
                bfv[ni] = *(const bf16x8*)&outW[(size_t)nn*128 + kt*32 + lg*8];
            }
#pragma unroll
            for (int mi = 0; mi < 2; mi++)
#pragma unroll
                for (int ni = 0; ni < 2; ni++)
                    acc[mi][ni] = __builtin_amdgcn_mfma_f32_16x16x32_bf16(af[mi], bfv[ni], acc[mi][ni], 0, 0, 0);
        }
#pragma unroll
        for (int mi = 0; mi < 2; mi++)
#pragma unroll
            for (int ni = 0; ni < 2; ni++) {
                int nloc = (w*2 + ni)*16 + ln15;
                float bb = outb[nloc];
#pragma unroll
                for (int i = 0; i < 4; i++) {
                    int ml = mi*16 + lg*4 + i;
                    Cs[ml*129 + nloc] = acc[mi][ni][i] + bb + tok[(size_t)(m0 + ml)*128 + nloc];
                }
            }
    }
    __syncthreads();

    // ---- LN1: Cs -> normalized (Cs, f32) + As (bf16 swizzled) ----
    {
        int r = tid >> 3, sub = tid & 7;
        float s1 = 0.f, s2 = 0.f;
#pragma unroll
        for (int j = 0; j < 16; j++) {
            float vv = Cs[r*129 + sub*16 + j];
            s1 += vv; s2 += vv*vv;
        }
        s1 += __shfl_down(s1, 4, 64); s2 += __shfl_down(s2, 4, 64);
        s1 += __shfl_down(s1, 2, 64); s2 += __shfl_down(s2, 2, 64);
        s1 += __shfl_down(s1, 1, 64); s2 += __shfl_down(s2, 1, 64);
        int lb = lane & 56;
        s1 = __shfl(s1, lb, 64); s2 = __shfl(s2, lb, 64);
        float mu = s1 * (1.0f/128.0f);
        float var = s2 * (1.0f/128.0f) - mu*mu;
        float rstd = rsqrtf(var + EPS);
#pragma unroll
        for (int j = 0; j < 16; j++) {
            int nloc = sub*16 + j;
            float vv = (Cs[r*129 + nloc] - mu) * rstd * ln1g[nloc] + ln1b[nloc];
            Cs[r*129 + nloc] = vv;
            int cp = (nloc >> 3) ^ (r & 15);
            As[r*128 + cp*8 + (nloc & 7)] = f2bf(vv);
        }
    }
    __syncthreads();

    // ---- ff1: M=32, N=256, K=128 -> gelu -> Hs ----
    {
        f32x4 acc1[2][4];
#pragma unroll
        for (int mi = 0; mi < 2; mi++)
#pragma unroll
            for (int ni = 0; ni < 4; ni++) acc1[mi][ni] = (f32x4){0.f, 0.f, 0.f, 0.f};
#pragma unroll
        for (int kt = 0; kt < 4; kt++) {
            bf16x8 af[2];
#pragma unroll
            for (int mi = 0; mi < 2; mi++) {
                int m = mi*16 + ln15;
                int cp = (kt*4 + lg) ^ (m & 15);
                af[mi] = *(const bf16x8*)&As[m*128 + cp*8];
            }
#pragma unroll
            for (int ni = 0; ni < 4; ni++) {
                int nn = w*64 + ni*16 + ln15;
                bf16x8 bfv = *(const bf16x8*)&B1[(size_t)nn*128 + kt*32 + lg*8];
#pragma unroll
                for (int mi = 0; mi < 2; mi++)
                    acc1[mi][ni] = __builtin_amdgcn_mfma_f32_16x16x32_bf16(af[mi], bfv, acc1[mi][ni], 0, 0, 0);
            }
        }
#pragma unroll
        for (int ni = 0; ni < 4; ni++) {
            int nn = w*64 + ni*16 + ln15;
            float bb = b1[nn];
#pragma unroll
            for (int mi = 0; mi < 2; mi++)
#pragma unroll
                for (int i = 0; i < 4; i++) {
                    int m = mi*16 + lg*4 + i;
                    float v = gelu_fast(acc1[mi][ni][i] + bb);
                    int cp = ((nn >> 3) ^ (m & 15));
                    Hs[m*256 + cp*8 + (nn & 7)] = f2bf(v);
                }
        }
    }
    __syncthreads();

    // ---- ff2: M=32, N=128, K=256; + residual (Cs) ----
    {
        f32x4 acc2[2][2];
#pragma unroll
        for (int mi = 0; mi < 2; mi++)
#pragma unroll
            for (int ni = 0; ni < 2; ni++) acc2[mi][ni] = (f32x4){0.f, 0.f, 0.f, 0.f};
#pragma unroll
        for (int kt = 0; kt < 8; kt++) {
            bf16x8 af[2];
#pragma unroll
            for (int mi = 0; mi < 2; mi++) {
                int m = mi*16 + ln15;
                int cp = (kt*4 + lg) ^ (m & 15);
                af[mi] = *(const bf16x8*)&Hs[m*256 + cp*8];
            }
#pragma unroll
            for (int ni = 0; ni < 2; ni++) {
                int nn = (w*2 + ni)*16 + ln15;
                bf16x8 bfv = *(const bf16x8*)&B2[(size_t)nn*256 + kt*32 + lg*8];
#pragma unroll
                for (int mi = 0; mi < 2; mi++)
                    acc2[mi][ni] = __builtin_amdgcn_mfma_f32_16x16x32_bf16(af[mi], bfv, acc2[mi][ni], 0, 0, 0);
            }
        }
        __syncthreads();   // everyone done reading Cs(LN1) before overwrite? owners overwrite own elems only — but reads in this loop were from Hs; Cs reads happen below by same owner. Barrier keeps Hs stable; harmless.
#pragma unroll
        for (int mi = 0; mi < 2; mi++)
#pragma unroll
            for (int ni = 0; ni < 2; ni++) {
                int nloc = (w*2 + ni)*16 + ln15;
                float bb = b2[nloc];
#pragma unroll
                for (int i = 0; i < 4; i++) {
                    int ml = mi*16 + lg*4 + i;
                    Cs[ml*129 + nloc] = acc2[mi][ni][i] + bb + Cs[ml*129 + nloc];
                }
            }
    }
    __syncthreads();

    // ---- LN2 -> tok (global) ----
    {
        int r = tid >> 3, sub = tid & 7;
        float s1 = 0.f, s2 = 0.f;
#pragma unroll
        for (int j = 0; j < 16; j++) {
            float vv = Cs[r*129 + sub*16 + j];
            s1 += vv; s2 += vv*vv;
        }
        s1 += __shfl_down(s1, 4, 64); s2 += __shfl_down(s2, 4, 64);
        s1 += __shfl_down(s1, 2, 64); s2 += __shfl_down(s2, 2, 64);
        s1 += __shfl_down(s1, 1, 64); s2 += __shfl_down(s2, 1, 64);
        int lb = lane & 56;
        s1 = __shfl(s1, lb, 64); s2 = __shfl(s2, lb, 64);
        float mu = s1 * (1.0f/128.0f);
        float var = s2 * (1.0f/128.0f) - mu*mu;
        float rstd = rsqrtf(var + EPS);
#pragma unroll
        for (int j = 0; j < 16; j++) {
            int nloc = sub*16 + j;
            float vv = (Cs[r*129 + nloc] - mu) * rstd * ln2g[nloc] + ln2b[nloc];
            tok[(size_t)(m0 + r)*128 + nloc] = vv;
        }
    }
}

// ---------------- attention: one block per (b, h) ----------------
__global__ __launch_bounds__(128) void attn_kernel(const float* __restrict__ qkv,
                                                   float* __restrict__ ctx) {
    __shared__ float qs[CC*16], ks[CC*16], vs[CC*16];
    int b = blockIdx.x >> 3, h = blockIdx.x & 7;
    int tid = threadIdx.x;
    const float* basep = qkv + (size_t)b*CC*384;
    for (int idx = tid; idx < CC*16; idx += 128) {
        int s = idx >> 4, d = idx & 15;
        qs[idx] = basep[s*384 +        h*16 + d];
        ks[idx] = basep[s*384 + 128 + h*16 + d];
        vs[idx] = basep[s*384 + 256 + h*16 + d];
    }
    __syncthreads();
    int i = tid;
    if (i < CC) {
        float q[16];
#pragma unroll
        for (int d = 0; d < 16; d++) q[d] = qs[i*16+d];
        float mx = -1e30f;
        for (int j = 0; j < CC; j++) {
            float s = 0.f;
#pragma unroll
            for (int d = 0; d < 16; d++) s = fmaf(q[d], ks[j*16+d], s);
            mx = fmaxf(mx, s * 0.25f);
        }
        float sum = 0.f;
        float acc[16];
#pragma unroll
        for (int d = 0; d < 16; d++) acc[d] = 0.f;
        for (int j = 0; j < CC; j++) {
            float s = 0.f;
#pragma unroll
            for (int d = 0; d < 16; d++) s = fmaf(q[d], ks[j*16+d], s);
            float e = __expf(s * 0.25f - mx);
            sum += e;
#pragma unroll
            for (int d = 0; d < 16; d++) acc[d] = fmaf(e, vs[j*16+d], acc[d]);
        }
        float r = __builtin_amdgcn_rcpf(sum);
        float* op = ctx + ((size_t)b*CC + i)*DD + h*16;
#pragma unroll
        for (int d = 0; d < 16; d++) op[d] = acc[d] * r;
    }
}

// ---------------- final: mean over C + subject head ----------------
__global__ __launch_bounds__(128) void final_kernel(const float* __restrict__ tok,
        const int* __restrict__ sid,
        const float* __restrict__ hw, const float* __restrict__ hb,
        float* __restrict__ outp) {
    __shared__ float pool[DD];
    int b = blockIdx.x, tid = threadIdx.x;
    float s = 0.f;
    for (int c2 = 0; c2 < CC; c2++) s += tok[((size_t)b*CC + c2)*DD + tid];
    pool[tid] = s * (1.0f/(float)CC);
    __syncthreads();
    if (tid < 4) {
        int sb = sid[b];
        const float* w = hw + ((size_t)sb*4 + tid)*DD;
        float a = hb[sb*4 + tid];
#pragma unroll 8
        for (int d = 0; d < DD; d++) a = fmaf(pool[d], w[d], a);
        outp[b*4 + tid] = a;
    }
}

extern "C" void kernel_launch(void* const* d_in, const int* in_sizes, int n_in,
                              void* d_out, int out_size, void* d_ws, size_t ws_size,
                              hipStream_t stream) {
    const float* x       = (const float*)d_in[0];
    const int*   sid     = (const int*)  d_in[1];
    const float* conv1_w = (const float*)d_in[2];
    const float* conv1_b = (const float*)d_in[3];
    const float* bn1_g   = (const float*)d_in[4];
    const float* bn1_b   = (const float*)d_in[5];
    const float* bn1_m   = (const float*)d_in[6];
    const float* bn1_v   = (const float*)d_in[7];
    const float* conv2_w = (const float*)d_in[8];
    const float* conv2_b = (const float*)d_in[9];
    const float* bn2_g   = (const float*)d_in[10];
    const float* bn2_b   = (const float*)d_in[11];
    const float* bn2_m   = (const float*)d_in[12];
    const float* bn2_v   = (const float*)d_in[13];
    const float* proj_w  = (const float*)d_in[14];
    const float* proj_b  = (const float*)d_in[15];
    const float* elec    = (const float*)d_in[16];
    const float* qkv_w   = (const float*)d_in[17];
    const float* qkv_b   = (const float*)d_in[18];
    const float* out_w   = (const float*)d_in[19];
    const float* out_b   = (const float*)d_in[20];
    const float* ln1_g   = (const float*)d_in[21];
    const float* ln1_b   = (const float*)d_in[22];
    const float* ff1_w   = (const float*)d_in[23];
    const float* ff1_b   = (const float*)d_in[24];
    const float* ff2_w   = (const float*)d_in[25];
    const float* ff2_b   = (const float*)d_in[26];
    const float* ln2_g   = (const float*)d_in[27];
    const float* ln2_b   = (const float*)d_in[28];
    const float* heads_w = (const float*)d_in[29];
    const float* heads_b = (const float*)d_in[30];
    float* ws = (float*)d_ws;
    const unsigned short* wbf = (const unsigned short*)(ws + WS_WBF);

    prep_kernel<<<(285312 + 255)/256, 256, 0, stream>>>(
        conv1_w, conv1_b, bn1_g, bn1_b, bn1_m, bn1_v,
        conv2_w, conv2_b, bn2_g, bn2_b, bn2_m, bn2_v,
        qkv_w, out_w, ff1_w, ff2_w, ws);

    conv_kernel<<<SEQ, 256, 0, stream>>>(x, proj_w, proj_b, elec, ws, ws + WS_TOK);

    for (int l = 0; l < NLAYER; l++) {
        mfma_gemm<128><<<dim3(244,3), 256, 0, stream>>>(
            ws + WS_TOK, wbf + WB_QKV + l*49152, qkv_b + l*384,
            ws + WS_QKV, 384);
        attn_kernel<<<BB*HHEADS, 128, 0, stream>>>(ws + WS_QKV, ws + WS_CTX);
        layer_tail<<<244, 256, 0, stream>>>(
            ws + WS_CTX, wbf + WB_OUT + l*16384, out_b + l*128,
            ws + WS_TOK, ln1_g + l*128, ln1_b + l*128,
            wbf + WB_FF1 + l*32768, ff1_b + l*256,
            wbf + WB_FF2 + l*32768, ff2_b + l*128,
            ln2_g + l*128, ln2_b + l*128);
    }

    final_kernel<<<BB, 128, 0, stream>>>(ws + WS_TOK, sid, heads_w, heads_b, (float*)d_out);
}

// Round 6
// 434.514 us; speedup vs baseline: 6.6572x; 1.1184x over previous
//
#include <hip/hip_runtime.h>
#include <math.h>

#define BB 64
#define CC 122
#define TT 500
#define NCOUT 64
#define DD 128
#define HHEADS 8
#define FFDIM 256
#define NLAYER 2
#define EPS 1e-5f
#define SEQ (BB*CC)   // 7808

// ---------------- workspace float offsets ----------------
#define WS_W2T     0u            // 20480 ushort bf16 w2t [kk][co][ci] (20480 floats reserved)
#define WS_S1      20480u
#define WS_SH1     20544u
#define WS_S2      20608u
#define WS_SH2     20672u
#define WS_WBF     20736u        // 262144 ushorts: bf16 qkv/out/ff1/ff2 weights
#define WS_TOK     151808u       // 7808*128 floats
#define WS_QKVB    1151232u      // 7808*256 ushorts (bf16 q,k) = 999424 floats
#define WS_VTB     2150656u      // 64*128*128 ushorts (bf16 v^T, [b][dh][j]) = 524288 floats
#define WS_GTAB    2674944u      // 1024 floats: 512 x (gelu, delta) pairs over [-8,8]
#define WS_W1S     2675968u      // 1024 floats = 2048 ushorts: bf16 w1s[co][k=32], BN-folded
// end = 2676992 floats = 10.7 MB

// WBF internal ushort offsets
#define WB_QKV  0u        // l*49152 + e*128 + k
#define WB_OUT  98304u    // l*16384 + e*128 + k
#define WB_FF1  131072u   // l*32768 + e*128 + k
#define WB_FF2  196608u   // l*32768 + e*256 + k

typedef __attribute__((ext_vector_type(8))) short bf16x8;
typedef __attribute__((ext_vector_type(4))) float f32x4;

__device__ __forceinline__ unsigned short f2bf(float f) {
    unsigned int u = __float_as_uint(f);
    unsigned int r = u + 0x7FFFu + ((u >> 16) & 1u);
    return (unsigned short)(r >> 16);
}

// branch-free erf-GELU (A&S 7.1.26)
__device__ __forceinline__ float gelu_fast(float x) {
    float z = fabsf(x) * 0.70710678118654752f;
    float t = __builtin_amdgcn_rcpf(fmaf(0.3275911f, z, 1.0f));
    float p = fmaf(fmaf(fmaf(fmaf(1.061405429f, t, -1.453152027f), t,
                             1.421413741f), t, -0.284496736f), t, 0.254829592f);
    float e = __expf(-z * z);
    float erf_abs = fmaf(-p * t, e, 1.0f);
    float erf_x = copysignf(erf_abs, x);
    return 0.5f * x * (1.0f + erf_x);
}

// table GELU: 512 (value,delta) pairs over [-8,8]
__device__ __forceinline__ float gelu_tab(float x, const float* __restrict__ gt) {
    float p = fmaf(x, 32.0f, 256.0f);
    p = fminf(fmaxf(p, 0.0f), 511.999f);
    int i = (int)p;
    float fr = p - (float)i;
    float2 gd = *(const float2*)&gt[2*i];
    return fmaf(fr, gd.y, gd.x);
}

// ---------------- prep: fold BN, bf16-ify weights, build tables ----------------
__global__ void prep_kernel(const float* __restrict__ conv1_w, const float* __restrict__ conv1_b,
                            const float* __restrict__ bn1_g, const float* __restrict__ bn1_b,
                            const float* __restrict__ bn1_m, const float* __restrict__ bn1_v,
                            const float* __restrict__ conv2_w, const float* __restrict__ conv2_b,
                            const float* __restrict__ bn2_g, const float* __restrict__ bn2_b,
                            const float* __restrict__ bn2_m, const float* __restrict__ bn2_v,
                            const float* __restrict__ qkv_w, const float* __restrict__ out_w,
                            const float* __restrict__ ff1_w, const float* __restrict__ ff2_w,
                            float* __restrict__ ws) {
    int idx = blockIdx.x * blockDim.x + threadIdx.x;
    if (idx < 20480) {
        int ci = idx & 63; int co = (idx >> 6) & 63; int kk = idx >> 12;
        unsigned short* wt = (unsigned short*)(ws + WS_W2T);
        wt[idx] = f2bf(conv2_w[(co*64 + ci)*5 + kk]);
    } else if (idx < 20544) {
        int i = idx - 20480;
        float s = bn1_g[i] * rsqrtf(bn1_v[i] + EPS);
        ws[WS_S1 + i] = s;
        ws[WS_SH1 + i] = (conv1_b[i] - bn1_m[i]) * s + bn1_b[i];
    } else if (idx < 20608) {
        int i = idx - 20544;
        float s = bn2_g[i] * rsqrtf(bn2_v[i] + EPS);
        ws[WS_S2 + i] = s;
        ws[WS_SH2 + i] = (conv2_b[i] - bn2_m[i]) * s + bn2_b[i];
    } else if (idx < 282752) {
        int r = idx - 20608;
        unsigned short* wbf = (unsigned short*)(ws + WS_WBF);
        float v;
        if (r < 98304)       v = qkv_w[r];
        else if (r < 131072) v = out_w[r - 98304];
        else if (r < 196608) v = ff1_w[r - 131072];
        else                 v = ff2_w[r - 196608];
        wbf[r] = f2bf(v);
    } else if (idx < 283264) {
        int i = idx - 282752;
        float x0 = (i - 256) * 0.03125f;
        float x1 = x0 + 0.03125f;
        float g0 = 0.5f*x0*(1.0f + erff(x0*0.70710678118654752f));
        float g1 = 0.5f*x1*(1.0f + erff(x1*0.70710678118654752f));
        ws[WS_GTAB + 2*i]     = g0;
        ws[WS_GTAB + 2*i + 1] = g1 - g0;
    } else if (idx < 285312) {
        int i = idx - 283264;            // co*32 + k
        int co = i >> 5, k = i & 31;
        unsigned short* w1s = (unsigned short*)(ws + WS_W1S);
        float s = bn1_g[co] * rsqrtf(bn1_v[co] + EPS);
        w1s[i] = (k < 9) ? f2bf(conv1_w[co*9 + k] * s) : (unsigned short)0;
    }
}

// ---------------- fused conv1 [MFMA] + pool + conv2 [MFMA] + mean + proj ----------------
__global__ __launch_bounds__(256, 4) void conv_kernel(const float* __restrict__ x,
            const float* __restrict__ proj_w, const float* __restrict__ proj_b,
            const float* __restrict__ elec,
            const float* __restrict__ wsr, float* __restrict__ tok) {
    __shared__ __align__(16) unsigned short h1s[264*64];  // 33792 B
    __shared__ __align__(16) unsigned short xbf[544];     // 1088 B
    __shared__ __align__(16) float gtab[1024];            // 4096 B
    __shared__ float part[256];
    __shared__ float mean_l[64];
    int n = blockIdx.x;
    int c = n % CC;
    int tid = threadIdx.x;
    const float* xg = x + (size_t)n * TT;

    for (int i = tid; i < 544; i += 256) {
        unsigned short v = 0;
        if (i >= 4 && i < 504) v = f2bf(xg[i-4]);
        xbf[i] = v;
    }
    {
        const float4* gsrc = (const float4*)(wsr + WS_GTAB);
        float4* gdst = (float4*)gtab;
        if (tid < 256) gdst[tid] = gsrc[tid];
    }
    for (int idx = tid; idx < 14*64; idx += 256) {
        int rr = idx >> 6;
        int r = (rr < 2) ? rr : (rr - 2 + 252);
        h1s[r*64 + (idx & 63)] = 0;
    }
    __syncthreads();

    int lane = tid & 63;
    int w = tid >> 6;
    int ln15 = lane & 15, lg = lane >> 4;

    // ---- phase 1: conv1 via MFMA im2col (w1s zero-padded k>=9 kills masked taps) ----
    {
        const unsigned short* w1s = (const unsigned short*)(wsr + WS_W1S);
        bf16x8 b1f[4];
        float sh1v[4];
#pragma unroll
        for (int nt = 0; nt < 4; nt++) {
            int co = nt*16 + ln15;
            b1f[nt] = *(const bf16x8*)&w1s[co*32 + lg*8];
            sh1v[nt] = wsr[WS_SH1 + co];
        }
        for (int mi = 0; mi < 8; mi++) {
            int mt = w*8 + mi;
            int t = mt*16 + ln15;
            short e[8];
#pragma unroll
            for (int j = 0; j < 8; j++) e[j] = (short)xbf[t + lg*8 + j];
            bf16x8 af = {e[0],e[1],e[2],e[3],e[4],e[5],e[6],e[7]};
#pragma unroll
            for (int nt = 0; nt < 4; nt++) {
                f32x4 cacc = __builtin_amdgcn_mfma_f32_16x16x32_bf16(af, b1f[nt],
                                (f32x4){0.f,0.f,0.f,0.f}, 0, 0, 0);
                float g0 = gelu_tab(cacc[0] + sh1v[nt], gtab);
                float g1 = gelu_tab(cacc[1] + sh1v[nt], gtab);
                float g2 = gelu_tab(cacc[2] + sh1v[nt], gtab);
                float g3 = gelu_tab(cacc[3] + sh1v[nt], gtab);
                int tpA = mt*8 + lg*2;
                if (tpA < 250) {
                    int co = nt*16 + ln15;
                    int r = tpA + 2;
                    int cp = (co >> 3) ^ (r & 7);
                    h1s[r*64 + cp*8 + (co & 7)] = f2bf(fmaxf(g0, g1));
                    int r2 = r + 1;
                    int cp2 = (co >> 3) ^ (r2 & 7);
                    h1s[r2*64 + cp2*8 + (co & 7)] = f2bf(fmaxf(g2, g3));
                }
            }
        }
    }
    __syncthreads();

    // ---- phase 2: conv2 as 5 shifted GEMMs ----
    const unsigned short* wt = (const unsigned short*)(wsr + WS_W2T);
    f32x4 acc[4][4];
#pragma unroll
    for (int mi = 0; mi < 4; mi++)
#pragma unroll
        for (int nt = 0; nt < 4; nt++) acc[mi][nt] = (f32x4){0.f, 0.f, 0.f, 0.f};

    const unsigned short* wbase = wt + ln15*64 + lg*8;
#pragma unroll
    for (int kk = 0; kk < 5; kk++) {
#pragma unroll
        for (int s = 0; s < 2; s++) {
            bf16x8 bfv[4];
#pragma unroll
            for (int nt = 0; nt < 4; nt++)
                bfv[nt] = *(const bf16x8*)(wbase + kk*4096 + nt*1024 + s*32);
#pragma unroll
            for (int mi = 0; mi < 4; mi++) {
                int r = (w*4 + mi)*16 + ln15 + kk;
                int cp = (s*4 + lg) ^ (r & 7);
                bf16x8 af = *(const bf16x8*)&h1s[r*64 + cp*8];
#pragma unroll
                for (int nt = 0; nt < 4; nt++)
                    acc[mi][nt] = __builtin_amdgcn_mfma_f32_16x16x32_bf16(af, bfv[nt], acc[mi][nt], 0, 0, 0);
            }
        }
    }

    // ---- epilogue: BN + GELU + mean over t ----
#pragma unroll
    for (int nt = 0; nt < 4; nt++) {
        int co2 = nt*16 + ln15;
        float sc = wsr[WS_S2 + co2], sh = wsr[WS_SH2 + co2];
        float p = 0.f;
#pragma unroll
        for (int mi = 0; mi < 4; mi++) {
            int tbase = (w*4 + mi)*16 + lg*4;
#pragma unroll
            for (int i = 0; i < 4; i++) {
                if (tbase + i < 250)
                    p += gelu_tab(fmaf(acc[mi][nt][i], sc, sh), gtab);
            }
        }
        p += __shfl_down(p, 32, 64);
        p += __shfl_down(p, 16, 64);
        if (lane < 16) part[w*64 + co2] = p;
    }
    __syncthreads();
    if (tid < 64) {
        mean_l[tid] = (part[tid] + part[64+tid] + part[128+tid] + part[192+tid]) * (1.0f/250.0f);
    }
    __syncthreads();

    if (tid < DD) {
        int d = tid;
        float a = proj_b[d] + elec[c*DD + d];
#pragma unroll 8
        for (int o = 0; o < 64; o++) a = fmaf(mean_l[o], proj_w[d*64 + o], a);
        tok[(size_t)n * DD + d] = a;
    }
}

// ---------------- qkv GEMM: tok[f32] @ qkv_w^T + b -> bf16 qkvb (q,k) / vtb (v^T) ----
__global__ __launch_bounds__(256) void qkv_gemm(const float* __restrict__ Aptr,
        const unsigned short* __restrict__ Bbf,   // layer's qkv weights [e][k]
        const float* __restrict__ bias,           // layer's qkv bias [384]
        unsigned short* __restrict__ qkvb,        // [7808][256]
        unsigned short* __restrict__ vtb) {       // [b*128+dh][128]
    const int tid = threadIdx.x;
    const int m0 = blockIdx.x * 32;
    const int y  = blockIdx.y;                    // 0:q 1:k 2:v
    const int n0 = y * 128;
    __shared__ __align__(16) unsigned short As[32*128];

    const float* A = Aptr + (size_t)m0 * 128;
    for (int i = tid; i < 1024; i += 256) {
        int m = i >> 5; int kq = (i & 31)*4;
        float4 v = *(const float4*)(A + m*128 + kq);
        int cp = (kq >> 3) ^ (m & 15);
        short4 s4 = make_short4((short)f2bf(v.x), (short)f2bf(v.y),
                                (short)f2bf(v.z), (short)f2bf(v.w));
        *(short4*)&As[m*128 + cp*8 + (kq & 7)] = s4;
    }
    __syncthreads();

    const int lane = tid & 63, w = tid >> 6;
    const int ln15 = lane & 15, lg = lane >> 4;
    f32x4 acc[2][2];
#pragma unroll
    for (int mi = 0; mi < 2; mi++)
#pragma unroll
        for (int ni = 0; ni < 2; ni++) acc[mi][ni] = (f32x4){0.f, 0.f, 0.f, 0.f};

    const unsigned short* Bb = Bbf + (size_t)n0 * 128;
#pragma unroll
    for (int kt = 0; kt < 4; kt++) {
        bf16x8 af[2], bfv[2];
#pragma unroll
        for (int mi = 0; mi < 2; mi++) {
            int m = mi*16 + ln15;
            int cp = (kt*4 + lg) ^ (m & 15);
            af[mi] = *(const bf16x8*)&As[m*128 + cp*8];
        }
#pragma unroll
        for (int ni = 0; ni < 2; ni++) {
            int nn = (w*2 + ni)*16 + ln15;
            bfv[ni] = *(const bf16x8*)&Bb[(size_t)nn*128 + kt*32 + lg*8];
        }
#pragma unroll
        for (int mi = 0; mi < 2; mi++)
#pragma unroll
            for (int ni = 0; ni < 2; ni++)
                acc[mi][ni] = __builtin_amdgcn_mfma_f32_16x16x32_bf16(af[mi], bfv[ni], acc[mi][ni], 0, 0, 0);
    }

#pragma unroll
    for (int mi = 0; mi < 2; mi++)
#pragma unroll
        for (int ni = 0; ni < 2; ni++) {
            int nloc = (w*2 + ni)*16 + ln15;
            float bb = bias[n0 + nloc];
#pragma unroll
            for (int i = 0; i < 4; i++) {
                int ml = mi*16 + lg*4 + i;
                int nrow = m0 + ml;
                unsigned short us = f2bf(acc[mi][ni][i] + bb);
                if (y < 2) {
                    qkvb[(size_t)nrow*256 + n0 + nloc] = us;
                } else {
                    int bq = nrow / 122;
                    int j  = nrow - bq*122;
                    vtb[((size_t)(bq*128 + nloc))*128 + j] = us;
                }
            }
        }
}

// ---------------- fused attention + out-proj + LN1 + FF + LN2 ----------------
// block = (b, quarter): rows m0l..m0l+31 of batch b; wave w handles heads {w, w+4}
__global__ __launch_bounds__(256) void attn_tail(
        const unsigned short* __restrict__ qkvb,
        const unsigned short* __restrict__ vtb,
        const unsigned short* __restrict__ outW, const float* __restrict__ outb,
        float* __restrict__ tok,
        const float* __restrict__ ln1g, const float* __restrict__ ln1b,
        const unsigned short* __restrict__ B1, const float* __restrict__ b1,
        const unsigned short* __restrict__ B2, const float* __restrict__ b2,
        const float* __restrict__ ln2g, const float* __restrict__ ln2b) {
    __shared__ float Cs[32*129];                              // 16.5 KB
    __shared__ __align__(16) unsigned short Pregion[4*32*128]; // 32 KB (P per wave; later ln1buf+Hs)
    __shared__ __align__(16) unsigned short ctxs[32*128];      // 8 KB

    const int tid = threadIdx.x;
    const int blk = blockIdx.x;
    const int b = blk >> 2, mq = blk & 3;
    const int m0l = mq * 32;
    const int lane = tid & 63, w = tid >> 6;
    const int ln15 = lane & 15, lg = lane >> 4;

    const unsigned short* qb = qkvb + (size_t)b * 122 * 256;
    unsigned short* Pw = Pregion + w * 4096;

    // ================= attention =================
#pragma unroll
    for (int hs = 0; hs < 2; hs++) {
        int h = w + hs*4;
        // Q A-frags (octets k>=16 zeroed)
        bf16x8 af[2];
#pragma unroll
        for (int mi = 0; mi < 2; mi++) {
            int mrow = m0l + mi*16 + ln15;
            int gr = (mrow < 122) ? mrow : 121;
            bf16x8 z = {0,0,0,0,0,0,0,0};
            if (lg < 2) z = *(const bf16x8*)(qb + gr*256 + h*16 + lg*8);
            af[mi] = z;
        }
        // S = Q K^T
        f32x4 S[2][8];
#pragma unroll
        for (int nt = 0; nt < 8; nt++) {
            int j = nt*16 + ln15;
            int gj = (j < 122) ? j : 121;
            bf16x8 bv = {0,0,0,0,0,0,0,0};
            if (lg < 2) bv = *(const bf16x8*)(qb + gj*256 + 128 + h*16 + lg*8);
#pragma unroll
            for (int mi = 0; mi < 2; mi++)
                S[mi][nt] = __builtin_amdgcn_mfma_f32_16x16x32_bf16(af[mi], bv,
                                (f32x4){0.f,0.f,0.f,0.f}, 0, 0, 0);
        }
        // softmax (rows live in 16-lane groups; xor shuffles stay in-group)
        float sm[2][4];
#pragma unroll
        for (int mi = 0; mi < 2; mi++)
#pragma unroll
            for (int i = 0; i < 4; i++) {
                float m_ = -1e30f;
#pragma unroll
                for (int nt = 0; nt < 8; nt++) {
                    float v = S[mi][nt][i] * 0.25f;
                    if (nt == 7 && ln15 >= 10) v = -1e30f;
                    S[mi][nt][i] = v;
                    m_ = fmaxf(m_, v);
                }
                m_ = fmaxf(m_, __shfl_xor(m_, 1, 64));
                m_ = fmaxf(m_, __shfl_xor(m_, 2, 64));
                m_ = fmaxf(m_, __shfl_xor(m_, 4, 64));
                m_ = fmaxf(m_, __shfl_xor(m_, 8, 64));
                float s_ = 0.f;
#pragma unroll
                for (int nt = 0; nt < 8; nt++) {
                    float e = __expf(S[mi][nt][i] - m_);
                    S[mi][nt][i] = e;
                    s_ += e;
                }
                s_ += __shfl_xor(s_, 1, 64);
                s_ += __shfl_xor(s_, 2, 64);
                s_ += __shfl_xor(s_, 4, 64);
                s_ += __shfl_xor(s_, 8, 64);
                sm[mi][i] = s_;
            }
        // P (unnormalized, <=1) -> Pw in A-layout
#pragma unroll
        for (int mi = 0; mi < 2; mi++)
#pragma unroll
            for (int nt = 0; nt < 8; nt++)
#pragma unroll
                for (int i = 0; i < 4; i++) {
                    int rp = mi*16 + lg*4 + i;
                    int j = nt*16 + ln15;
                    int cp = (j >> 3) ^ (rp & 15);
                    Pw[rp*128 + cp*8 + (j & 7)] = f2bf(S[mi][nt][i]);
                }
        // PV
        f32x4 cacc[2] = {(f32x4){0.f,0.f,0.f,0.f}, (f32x4){0.f,0.f,0.f,0.f}};
#pragma unroll
        for (int kt = 0; kt < 4; kt++) {
            bf16x8 bv = *(const bf16x8*)(vtb + ((size_t)(b*128 + h*16 + ln15))*128 + kt*32 + lg*8);
#pragma unroll
            for (int mi = 0; mi < 2; mi++) {
                int m = mi*16 + ln15;
                int cp = (kt*4 + lg) ^ (m & 15);
                bf16x8 ap = *(const bf16x8*)&Pw[m*128 + cp*8];
                cacc[mi] = __builtin_amdgcn_mfma_f32_16x16x32_bf16(ap, bv, cacc[mi], 0, 0, 0);
            }
        }
        // normalize + write ctx (bf16, A-layout)
#pragma unroll
        for (int mi = 0; mi < 2; mi++)
#pragma unroll
            for (int i = 0; i < 4; i++) {
                float inv = __builtin_amdgcn_rcpf(sm[mi][i]);
                int rp = mi*16 + lg*4 + i;
                int ccol = h*16 + ln15;
                int cp = (ccol >> 3) ^ (rp & 15);
                ctxs[rp*128 + cp*8 + (ccol & 7)] = f2bf(cacc[mi][i] * inv);
            }
    }
    __syncthreads();

    // ================= out-proj + residual =================
    {
        f32x4 acc[2][2];
#pragma unroll
        for (int mi = 0; mi < 2; mi++)
#pragma unroll
            for (int ni = 0; ni < 2; ni++) acc[mi][ni] = (f32x4){0.f,0.f,0.f,0.f};
#pragma unroll
        for (int kt = 0; kt < 4; kt++) {
            bf16x8 afm[2], bv[2];
#pragma unroll
            for (int mi = 0; mi < 2; mi++) {
                int m = mi*16 + ln15;
                int cp = (kt*4 + lg) ^ (m & 15);
                afm[mi] = *(const bf16x8*)&ctxs[m*128 + cp*8];
            }
#pragma unroll
            for (int ni = 0; ni < 2; ni++) {
                int nn = (w*2 + ni)*16 + ln15;
                bv[ni] = *(const bf16x8*)&outW[(size_t)nn*128 + kt*32 + lg*8];
            }
#pragma unroll
            for (int mi = 0; mi < 2; mi++)
#pragma unroll
                for (int ni = 0; ni < 2; ni++)
                    acc[mi][ni] = __builtin_amdgcn_mfma_f32_16x16x32_bf16(afm[mi], bv[ni], acc[mi][ni], 0, 0, 0);
        }
#pragma unroll
        for (int mi = 0; mi < 2; mi++)
#pragma unroll
            for (int ni = 0; ni < 2; ni++) {
                int nloc = (w*2 + ni)*16 + ln15;
                float bb = outb[nloc];
#pragma unroll
                for (int i = 0; i < 4; i++) {
                    int ml = mi*16 + lg*4 + i;
                    int mrow = m0l + ml;
                    int grow = b*122 + ((mrow < 122) ? mrow : 121);
                    Cs[ml*129 + nloc] = acc[mi][ni][i] + bb + tok[(size_t)grow*128 + nloc];
                }
            }
    }
    __syncthreads();

    // ================= LN1 -> Cs(f32) + ln1buf(bf16) =================
    unsigned short* ln1buf = Pregion;          // 8 KB
    unsigned short* Hs = Pregion + 4096;       // 16 KB
    {
        int r = tid >> 3, sub = tid & 7;
        float s1 = 0.f, s2 = 0.f;
#pragma unroll
        for (int j = 0; j < 16; j++) {
            float vv = Cs[r*129 + sub*16 + j];
            s1 += vv; s2 += vv*vv;
        }
        s1 += __shfl_down(s1, 4, 64); s2 += __shfl_down(s2, 4, 64);
        s1 += __shfl_down(s1, 2, 64); s2 += __shfl_down(s2, 2, 64);
        s1 += __shfl_down(s1, 1, 64); s2 += __shfl_down(s2, 1, 64);
        int lb = lane & 56;
        s1 = __shfl(s1, lb, 64); s2 = __shfl(s2, lb, 64);
        float mu = s1 * (1.0f/128.0f);
        float var = s2 * (1.0f/128.0f) - mu*mu;
        float rstd = rsqrtf(var + EPS);
#pragma unroll
        for (int j = 0; j < 16; j++) {
            int nloc = sub*16 + j;
            float vv = (Cs[r*129 + nloc] - mu) * rstd * ln1g[nloc] + ln1b[nloc];
            Cs[r*129 + nloc] = vv;
            int cp = (nloc >> 3) ^ (r & 15);
            ln1buf[r*128 + cp*8 + (nloc & 7)] = f2bf(vv);
        }
    }
    __syncthreads();

    // ================= ff1 (gelu) -> Hs =================
    {
        f32x4 acc1[2][4];
#pragma unroll
        for (int mi = 0; mi < 2; mi++)
#pragma unroll
            for (int ni = 0; ni < 4; ni++) acc1[mi][ni] = (f32x4){0.f,0.f,0.f,0.f};
#pragma unroll
        for (int kt = 0; kt < 4; kt++) {
            bf16x8 afm[2];
#pragma unroll
            for (int mi = 0; mi < 2; mi++) {
                int m = mi*16 + ln15;
                int cp = (kt*4 + lg) ^ (m & 15);
                afm[mi] = *(const bf16x8*)&ln1buf[m*128 + cp*8];
            }
#pragma unroll
            for (int ni = 0; ni < 4; ni++) {
                int nn = w*64 + ni*16 + ln15;
                bf16x8 bv = *(const bf16x8*)&B1[(size_t)nn*128 + kt*32 + lg*8];
#pragma unroll
                for (int mi = 0; mi < 2; mi++)
                    acc1[mi][ni] = __builtin_amdgcn_mfma_f32_16x16x32_bf16(afm[mi], bv, acc1[mi][ni], 0, 0, 0);
            }
        }
#pragma unroll
        for (int ni = 0; ni < 4; ni++) {
            int nn = w*64 + ni*16 + ln15;
            float bb = b1[nn];
#pragma unroll
            for (int mi = 0; mi < 2; mi++)
#pragma unroll
                for (int i = 0; i < 4; i++) {
                    int m = mi*16 + lg*4 + i;
                    float v = gelu_fast(acc1[mi][ni][i] + bb);
                    int cp = (nn >> 3) ^ (m & 15);
                    Hs[m*256 + cp*8 + (nn & 7)] = f2bf(v);
                }
        }
    }
    __syncthreads();

    // ================= ff2 + residual (LN1 out) =================
    {
        f32x4 acc2[2][2];
#pragma unroll
        for (int mi = 0; mi < 2; mi++)
#pragma unroll
            for (int ni = 0; ni < 2; ni++) acc2[mi][ni] = (f32x4){0.f,0.f,0.f,0.f};
#pragma unroll
        for (int kt = 0; kt < 8; kt++) {
            bf16x8 afm[2];
#pragma unroll
            for (int mi = 0; mi < 2; mi++) {
                int m = mi*16 + ln15;
                int cp = (kt*4 + lg) ^ (m & 15);
                afm[mi] = *(const bf16x8*)&Hs[m*256 + cp*8];
            }
#pragma unroll
            for (int ni = 0; ni < 2; ni++) {
                int nn = (w*2 + ni)*16 + ln15;
                bf16x8 bv = *(const bf16x8*)&B2[(size_t)nn*256 + kt*32 + lg*8];
#pragma unroll
                for (int mi = 0; mi < 2; mi++)
                    acc2[mi][ni] = __builtin_amdgcn_mfma_f32_16x16x32_bf16(afm[mi], bv, acc2[mi][ni], 0, 0, 0);
            }
        }
#pragma unroll
        for (int mi = 0; mi < 2; mi++)
#pragma unroll
            for (int ni = 0; ni < 2; ni++) {
                int nloc = (w*2 + ni)*16 + ln15;
                float bb = b2[nloc];
#pragma unroll
                for (int i = 0; i < 4; i++) {
                    int ml = mi*16 + lg*4 + i;
                    Cs[ml*129 + nloc] = acc2[mi][ni][i] + bb + Cs[ml*129 + nloc];
                }
            }
    }
    __syncthreads();

    // ================= LN2 -> tok =================
    {
        int r = tid >> 3, sub = tid & 7;
        float s1 = 0.f, s2 = 0.f;
#pragma unroll
        for (int j = 0; j < 16; j++) {
            float vv = Cs[r*129 + sub*16 + j];
            s1 += vv; s2 += vv*vv;
        }
        s1 += __shfl_down(s1, 4, 64); s2 += __shfl_down(s2, 4, 64);
        s1 += __shfl_down(s1, 2, 64); s2 += __shfl_down(s2, 2, 64);
        s1 += __shfl_down(s1, 1, 64); s2 += __shfl_down(s2, 1, 64);
        int lb = lane & 56;
        s1 = __shfl(s1, lb, 64); s2 = __shfl(s2, lb, 64);
        float mu = s1 * (1.0f/128.0f);
        float var = s2 * (1.0f/128.0f) - mu*mu;
        float rstd = rsqrtf(var + EPS);
        if (m0l + r < 122) {
#pragma unroll
            for (int j = 0; j < 16; j++) {
                int nloc = sub*16 + j;
                float vv = (Cs[r*129 + nloc] - mu) * rstd * ln2g[nloc] + ln2b[nloc];
                tok[((size_t)(b*122 + m0l + r))*128 + nloc] = vv;
            }
        }
    }
}

// ---------------- final: mean over C + subject head ----------------
__global__ __launch_bounds__(128) void final_kernel(const float* __restrict__ tok,
        const int* __restrict__ sid,
        const float* __restrict__ hw, const float* __restrict__ hb,
        float* __restrict__ outp) {
    __shared__ float pool[DD];
    int b = blockIdx.x, tid = threadIdx.x;
    float s = 0.f;
    for (int c2 = 0; c2 < CC; c2++) s += tok[((size_t)b*CC + c2)*DD + tid];
    pool[tid] = s * (1.0f/(float)CC);
    __syncthreads();
    if (tid < 4) {
        int sb = sid[b];
        const float* w = hw + ((size_t)sb*4 + tid)*DD;
        float a = hb[sb*4 + tid];
#pragma unroll 8
        for (int d = 0; d < DD; d++) a = fmaf(pool[d], w[d], a);
        outp[b*4 + tid] = a;
    }
}

extern "C" void kernel_launch(void* const* d_in, const int* in_sizes, int n_in,
                              void* d_out, int out_size, void* d_ws, size_t ws_size,
                              hipStream_t stream) {
    const float* x       = (const float*)d_in[0];
    const int*   sid     = (const int*)  d_in[1];
    const float* conv1_w = (const float*)d_in[2];
    const float* conv1_b = (const float*)d_in[3];
    const float* bn1_g   = (const float*)d_in[4];
    const float* bn1_b   = (const float*)d_in[5];
    const float* bn1_m   = (const float*)d_in[6];
    const float* bn1_v   = (const float*)d_in[7];
    const float* conv2_w = (const float*)d_in[8];
    const float* conv2_b = (const float*)d_in[9];
    const float* bn2_g   = (const float*)d_in[10];
    const float* bn2_b   = (const float*)d_in[11];
    const float* bn2_m   = (const float*)d_in[12];
    const float* bn2_v   = (const float*)d_in[13];
    const float* proj_w  = (const float*)d_in[14];
    const float* proj_b  = (const float*)d_in[15];
    const float* elec    = (const float*)d_in[16];
    const float* qkv_w   = (const float*)d_in[17];
    const float* qkv_b   = (const float*)d_in[18];
    const float* out_w   = (const float*)d_in[19];
    const float* out_b   = (const float*)d_in[20];
    const float* ln1_g   = (const float*)d_in[21];
    const float* ln1_b   = (const float*)d_in[22];
    const float* ff1_w   = (const float*)d_in[23];
    const float* ff1_b   = (const float*)d_in[24];
    const float* ff2_w   = (const float*)d_in[25];
    const float* ff2_b   = (const float*)d_in[26];
    const float* ln2_g   = (const float*)d_in[27];
    const float* ln2_b   = (const float*)d_in[28];
    const float* heads_w = (const float*)d_in[29];
    const float* heads_b = (const float*)d_in[30];
    float* ws = (float*)d_ws;
    const unsigned short* wbf = (const unsigned short*)(ws + WS_WBF);
    unsigned short* qkvb = (unsigned short*)(ws + WS_QKVB);
    unsigned short* vtb  = (unsigned short*)(ws + WS_VTB);

    prep_kernel<<<(285312 + 255)/256, 256, 0, stream>>>(
        conv1_w, conv1_b, bn1_g, bn1_b, bn1_m, bn1_v,
        conv2_w, conv2_b, bn2_g, bn2_b, bn2_m, bn2_v,
        qkv_w, out_w, ff1_w, ff2_w, ws);

    conv_kernel<<<SEQ, 256, 0, stream>>>(x, proj_w, proj_b, elec, ws, ws + WS_TOK);

    for (int l = 0; l < NLAYER; l++) {
        qkv_gemm<<<dim3(244,3), 256, 0, stream>>>(
            ws + WS_TOK, wbf + WB_QKV + l*49152, qkv_b + l*384, qkvb, vtb);
        attn_tail<<<BB*4, 256, 0, stream>>>(
            qkvb, vtb,
            wbf + WB_OUT + l*16384, out_b + l*128,
            ws + WS_TOK, ln1_g + l*128, ln1_b + l*128,
            wbf + WB_FF1 + l*32768, ff1_b + l*256,
            wbf + WB_FF2 + l*32768, ff2_b + l*128,
            ln2_g + l*128, ln2_b + l*128);
    }

    final_kernel<<<BB, 128, 0, stream>>>(ws + WS_TOK, sid, heads_w, heads_b, (float*)d_out);
}

// Round 7
// 429.321 us; speedup vs baseline: 6.7377x; 1.0121x over previous
//
#include <hip/hip_runtime.h>
#include <math.h>

#define BB 64
#define CC 122
#define TT 500
#define NCOUT 64
#define DD 128
#define HHEADS 8
#define FFDIM 256
#define NLAYER 2
#define EPS 1e-5f
#define SEQ (BB*CC)   // 7808

// ---------------- workspace float offsets ----------------
#define WS_W2T     0u            // 20480 ushort bf16 w2t [kk][co][ci] (20480 floats reserved)
#define WS_S1      20480u
#define WS_SH1     20544u
#define WS_S2      20608u
#define WS_SH2     20672u
#define WS_WBF     20736u        // 262144 ushorts: bf16 qkv/out/ff1/ff2 weights
#define WS_TOK     151808u       // 7808*128 floats
#define WS_QKVB    1151232u      // 7808*256 ushorts (bf16 q,k) = 999424 floats
#define WS_VTB     2150656u      // 64*128*128 ushorts (bf16 v^T, [b][dh][j]) = 524288 floats
#define WS_GTAB    2674944u      // 1024 floats: 512 x (gelu, delta) pairs over [-8,8]
#define WS_W1S     2675968u      // 1024 floats = 2048 ushorts: bf16 w1s[co][k=32], BN-folded
// end = 2676992 floats = 10.7 MB

// WBF internal ushort offsets
#define WB_QKV  0u        // l*49152 + e*128 + k
#define WB_OUT  98304u    // l*16384 + e*128 + k
#define WB_FF1  131072u   // l*32768 + e*128 + k
#define WB_FF2  196608u   // l*32768 + e*256 + k

typedef __attribute__((ext_vector_type(8))) short bf16x8;
typedef __attribute__((ext_vector_type(4))) float f32x4;

__device__ __forceinline__ unsigned short f2bf(float f) {
    unsigned int u = __float_as_uint(f);
    unsigned int r = u + 0x7FFFu + ((u >> 16) & 1u);
    return (unsigned short)(r >> 16);
}

// branch-free erf-GELU (A&S 7.1.26)
__device__ __forceinline__ float gelu_fast(float x) {
    float z = fabsf(x) * 0.70710678118654752f;
    float t = __builtin_amdgcn_rcpf(fmaf(0.3275911f, z, 1.0f));
    float p = fmaf(fmaf(fmaf(fmaf(1.061405429f, t, -1.453152027f), t,
                             1.421413741f), t, -0.284496736f), t, 0.254829592f);
    float e = __expf(-z * z);
    float erf_abs = fmaf(-p * t, e, 1.0f);
    float erf_x = copysignf(erf_abs, x);
    return 0.5f * x * (1.0f + erf_x);
}

// table GELU: 512 (value,delta) pairs over [-8,8]
__device__ __forceinline__ float gelu_tab(float x, const float* __restrict__ gt) {
    float p = fmaf(x, 32.0f, 256.0f);
    p = fminf(fmaxf(p, 0.0f), 511.999f);
    int i = (int)p;
    float fr = p - (float)i;
    float2 gd = *(const float2*)&gt[2*i];
    return fmaf(fr, gd.y, gd.x);
}

// ---------------- prep: fold BN, bf16-ify weights, build tables ----------------
__global__ void prep_kernel(const float* __restrict__ conv1_w, const float* __restrict__ conv1_b,
                            const float* __restrict__ bn1_g, const float* __restrict__ bn1_b,
                            const float* __restrict__ bn1_m, const float* __restrict__ bn1_v,
                            const float* __restrict__ conv2_w, const float* __restrict__ conv2_b,
                            const float* __restrict__ bn2_g, const float* __restrict__ bn2_b,
                            const float* __restrict__ bn2_m, const float* __restrict__ bn2_v,
                            const float* __restrict__ qkv_w, const float* __restrict__ out_w,
                            const float* __restrict__ ff1_w, const float* __restrict__ ff2_w,
                            float* __restrict__ ws) {
    int idx = blockIdx.x * blockDim.x + threadIdx.x;
    if (idx < 20480) {
        int ci = idx & 63; int co = (idx >> 6) & 63; int kk = idx >> 12;
        unsigned short* wt = (unsigned short*)(ws + WS_W2T);
        wt[idx] = f2bf(conv2_w[(co*64 + ci)*5 + kk]);
    } else if (idx < 20544) {
        int i = idx - 20480;
        float s = bn1_g[i] * rsqrtf(bn1_v[i] + EPS);
        ws[WS_S1 + i] = s;
        ws[WS_SH1 + i] = (conv1_b[i] - bn1_m[i]) * s + bn1_b[i];
    } else if (idx < 20608) {
        int i = idx - 20544;
        float s = bn2_g[i] * rsqrtf(bn2_v[i] + EPS);
        ws[WS_S2 + i] = s;
        ws[WS_SH2 + i] = (conv2_b[i] - bn2_m[i]) * s + bn2_b[i];
    } else if (idx < 282752) {
        int r = idx - 20608;
        unsigned short* wbf = (unsigned short*)(ws + WS_WBF);
        float v;
        if (r < 98304)       v = qkv_w[r];
        else if (r < 131072) v = out_w[r - 98304];
        else if (r < 196608) v = ff1_w[r - 131072];
        else                 v = ff2_w[r - 196608];
        wbf[r] = f2bf(v);
    } else if (idx < 283264) {
        int i = idx - 282752;
        float x0 = (i - 256) * 0.03125f;
        float x1 = x0 + 0.03125f;
        float g0 = 0.5f*x0*(1.0f + erff(x0*0.70710678118654752f));
        float g1 = 0.5f*x1*(1.0f + erff(x1*0.70710678118654752f));
        ws[WS_GTAB + 2*i]     = g0;
        ws[WS_GTAB + 2*i + 1] = g1 - g0;
    } else if (idx < 285312) {
        int i = idx - 283264;            // co*32 + k
        int co = i >> 5, k = i & 31;
        unsigned short* w1s = (unsigned short*)(ws + WS_W1S);
        float s = bn1_g[co] * rsqrtf(bn1_v[co] + EPS);
        w1s[i] = (k < 9) ? f2bf(conv1_w[co*9 + k] * s) : (unsigned short)0;
    }
}

// ---------------- fused conv1 [MFMA] + pool + conv2 [MFMA] + mean + proj ----------------
__global__ __launch_bounds__(256, 4) void conv_kernel(const float* __restrict__ x,
            const float* __restrict__ proj_w, const float* __restrict__ proj_b,
            const float* __restrict__ elec,
            const float* __restrict__ wsr, float* __restrict__ tok) {
    __shared__ __align__(16) unsigned short h1s[264*64];  // 33792 B
    __shared__ __align__(16) unsigned short xbf[544];     // 1088 B
    __shared__ __align__(16) float gtab[1024];            // 4096 B
    __shared__ float part[256];
    __shared__ float mean_l[64];
    int n = blockIdx.x;
    int c = n % CC;
    int tid = threadIdx.x;
    const float* xg = x + (size_t)n * TT;

    for (int i = tid; i < 544; i += 256) {
        unsigned short v = 0;
        if (i >= 4 && i < 504) v = f2bf(xg[i-4]);
        xbf[i] = v;
    }
    {
        const float4* gsrc = (const float4*)(wsr + WS_GTAB);
        float4* gdst = (float4*)gtab;
        if (tid < 256) gdst[tid] = gsrc[tid];
    }
    for (int idx = tid; idx < 14*64; idx += 256) {
        int rr = idx >> 6;
        int r = (rr < 2) ? rr : (rr - 2 + 252);
        h1s[r*64 + (idx & 63)] = 0;
    }
    __syncthreads();

    int lane = tid & 63;
    int w = tid >> 6;
    int ln15 = lane & 15, lg = lane >> 4;

    // ---- phase 1: conv1 via MFMA im2col (w1s zero-padded k>=9 kills masked taps) ----
    {
        const unsigned short* w1s = (const unsigned short*)(wsr + WS_W1S);
        bf16x8 b1f[4];
        float sh1v[4];
#pragma unroll
        for (int nt = 0; nt < 4; nt++) {
            int co = nt*16 + ln15;
            b1f[nt] = *(const bf16x8*)&w1s[co*32 + lg*8];
            sh1v[nt] = wsr[WS_SH1 + co];
        }
        for (int mi = 0; mi < 8; mi++) {
            int mt = w*8 + mi;
            int t = mt*16 + ln15;
            short e[8];
#pragma unroll
            for (int j = 0; j < 8; j++) e[j] = (short)xbf[t + lg*8 + j];
            bf16x8 af = {e[0],e[1],e[2],e[3],e[4],e[5],e[6],e[7]};
#pragma unroll
            for (int nt = 0; nt < 4; nt++) {
                f32x4 cacc = __builtin_amdgcn_mfma_f32_16x16x32_bf16(af, b1f[nt],
                                (f32x4){0.f,0.f,0.f,0.f}, 0, 0, 0);
                float g0 = gelu_tab(cacc[0] + sh1v[nt], gtab);
                float g1 = gelu_tab(cacc[1] + sh1v[nt], gtab);
                float g2 = gelu_tab(cacc[2] + sh1v[nt], gtab);
                float g3 = gelu_tab(cacc[3] + sh1v[nt], gtab);
                int tpA = mt*8 + lg*2;
                if (tpA < 250) {
                    int co = nt*16 + ln15;
                    int r = tpA + 2;
                    int cp = (co >> 3) ^ (r & 7);
                    h1s[r*64 + cp*8 + (co & 7)] = f2bf(fmaxf(g0, g1));
                    int r2 = r + 1;
                    int cp2 = (co >> 3) ^ (r2 & 7);
                    h1s[r2*64 + cp2*8 + (co & 7)] = f2bf(fmaxf(g2, g3));
                }
            }
        }
    }
    __syncthreads();

    // ---- phase 2: conv2 as 5 shifted GEMMs ----
    const unsigned short* wt = (const unsigned short*)(wsr + WS_W2T);
    f32x4 acc[4][4];
#pragma unroll
    for (int mi = 0; mi < 4; mi++)
#pragma unroll
        for (int nt = 0; nt < 4; nt++) acc[mi][nt] = (f32x4){0.f, 0.f, 0.f, 0.f};

    const unsigned short* wbase = wt + ln15*64 + lg*8;
#pragma unroll
    for (int kk = 0; kk < 5; kk++) {
#pragma unroll
        for (int s = 0; s < 2; s++) {
            bf16x8 bfv[4];
#pragma unroll
            for (int nt = 0; nt < 4; nt++)
                bfv[nt] = *(const bf16x8*)(wbase + kk*4096 + nt*1024 + s*32);
#pragma unroll
            for (int mi = 0; mi < 4; mi++) {
                int r = (w*4 + mi)*16 + ln15 + kk;
                int cp = (s*4 + lg) ^ (r & 7);
                bf16x8 af = *(const bf16x8*)&h1s[r*64 + cp*8];
#pragma unroll
                for (int nt = 0; nt < 4; nt++)
                    acc[mi][nt] = __builtin_amdgcn_mfma_f32_16x16x32_bf16(af, bfv[nt], acc[mi][nt], 0, 0, 0);
            }
        }
    }

    // ---- epilogue: BN + GELU + mean over t ----
#pragma unroll
    for (int nt = 0; nt < 4; nt++) {
        int co2 = nt*16 + ln15;
        float sc = wsr[WS_S2 + co2], sh = wsr[WS_SH2 + co2];
        float p = 0.f;
#pragma unroll
        for (int mi = 0; mi < 4; mi++) {
            int tbase = (w*4 + mi)*16 + lg*4;
#pragma unroll
            for (int i = 0; i < 4; i++) {
                if (tbase + i < 250)
                    p += gelu_tab(fmaf(acc[mi][nt][i], sc, sh), gtab);
            }
        }
        p += __shfl_down(p, 32, 64);
        p += __shfl_down(p, 16, 64);
        if (lane < 16) part[w*64 + co2] = p;
    }
    __syncthreads();
    if (tid < 64) {
        mean_l[tid] = (part[tid] + part[64+tid] + part[128+tid] + part[192+tid]) * (1.0f/250.0f);
    }
    __syncthreads();

    if (tid < DD) {
        int d = tid;
        float a = proj_b[d] + elec[c*DD + d];
#pragma unroll 8
        for (int o = 0; o < 64; o++) a = fmaf(mean_l[o], proj_w[d*64 + o], a);
        tok[(size_t)n * DD + d] = a;
    }
}

// ---------------- qkv GEMM: tok[f32] @ qkv_w^T + b -> bf16 qkvb (q,k) / vtb (v^T) ----
__global__ __launch_bounds__(256) void qkv_gemm(const float* __restrict__ Aptr,
        const unsigned short* __restrict__ Bbf,   // layer's qkv weights [e][k]
        const float* __restrict__ bias,           // layer's qkv bias [384]
        unsigned short* __restrict__ qkvb,        // [7808][256]
        unsigned short* __restrict__ vtb) {       // [b*128+dh][128]
    const int tid = threadIdx.x;
    const int m0 = blockIdx.x * 32;
    const int y  = blockIdx.y;                    // 0:q 1:k 2:v
    const int n0 = y * 128;
    __shared__ __align__(16) unsigned short As[32*128];

    const float* A = Aptr + (size_t)m0 * 128;
    for (int i = tid; i < 1024; i += 256) {
        int m = i >> 5; int kq = (i & 31)*4;
        float4 v = *(const float4*)(A + m*128 + kq);
        int cp = (kq >> 3) ^ (m & 15);
        short4 s4 = make_short4((short)f2bf(v.x), (short)f2bf(v.y),
                                (short)f2bf(v.z), (short)f2bf(v.w));
        *(short4*)&As[m*128 + cp*8 + (kq & 7)] = s4;
    }
    __syncthreads();

    const int lane = tid & 63, w = tid >> 6;
    const int ln15 = lane & 15, lg = lane >> 4;
    f32x4 acc[2][2];
#pragma unroll
    for (int mi = 0; mi < 2; mi++)
#pragma unroll
        for (int ni = 0; ni < 2; ni++) acc[mi][ni] = (f32x4){0.f, 0.f, 0.f, 0.f};

    const unsigned short* Bb = Bbf + (size_t)n0 * 128;
#pragma unroll
    for (int kt = 0; kt < 4; kt++) {
        bf16x8 af[2], bfv[2];
#pragma unroll
        for (int mi = 0; mi < 2; mi++) {
            int m = mi*16 + ln15;
            int cp = (kt*4 + lg) ^ (m & 15);
            af[mi] = *(const bf16x8*)&As[m*128 + cp*8];
        }
#pragma unroll
        for (int ni = 0; ni < 2; ni++) {
            int nn = (w*2 + ni)*16 + ln15;
            bfv[ni] = *(const bf16x8*)&Bb[(size_t)nn*128 + kt*32 + lg*8];
        }
#pragma unroll
        for (int mi = 0; mi < 2; mi++)
#pragma unroll
            for (int ni = 0; ni < 2; ni++)
                acc[mi][ni] = __builtin_amdgcn_mfma_f32_16x16x32_bf16(af[mi], bfv[ni], acc[mi][ni], 0, 0, 0);
    }

#pragma unroll
    for (int mi = 0; mi < 2; mi++)
#pragma unroll
        for (int ni = 0; ni < 2; ni++) {
            int nloc = (w*2 + ni)*16 + ln15;
            float bb = bias[n0 + nloc];
#pragma unroll
            for (int i = 0; i < 4; i++) {
                int ml = mi*16 + lg*4 + i;
                int nrow = m0 + ml;
                unsigned short us = f2bf(acc[mi][ni][i] + bb);
                if (y < 2) {
                    qkvb[(size_t)nrow*256 + n0 + nloc] = us;
                } else {
                    int bq = nrow / 122;
                    int j  = nrow - bq*122;
                    vtb[((size_t)(bq*128 + nloc))*128 + j] = us;
                }
            }
        }
}

// ---------------- fused attention + out-proj + LN1 + FF + LN2 (512 thr, head/wave) ----
// block = (b, quarter): rows m0l..m0l+31 of batch b; wave w handles head w
__global__ __launch_bounds__(512) void attn_tail(
        const unsigned short* __restrict__ qkvb,
        const unsigned short* __restrict__ vtb,
        const unsigned short* __restrict__ outW, const float* __restrict__ outb,
        float* __restrict__ tok,
        const float* __restrict__ ln1g, const float* __restrict__ ln1b,
        const unsigned short* __restrict__ B1, const float* __restrict__ b1,
        const unsigned short* __restrict__ B2, const float* __restrict__ b2,
        const float* __restrict__ ln2g, const float* __restrict__ ln2b) {
    __shared__ float Cs[32*129];                               // 16.5 KB
    __shared__ __align__(16) unsigned short Pregion[8*16*128]; // 32 KB (P/wave; later ln1buf+Hs)
    __shared__ __align__(16) unsigned short ctxs[32*128];      // 8 KB

    const int tid = threadIdx.x;
    const int blk = blockIdx.x;
    const int b = blk >> 2, mq = blk & 3;
    const int m0l = mq * 32;
    const int lane = tid & 63, w = tid >> 6;       // w = 0..7 = head
    const int ln15 = lane & 15, lg = lane >> 4;

    const unsigned short* qb = qkvb + (size_t)b * 122 * 256;
    unsigned short* Pw = Pregion + w * 2048;       // 16 rows x 128 cols bf16

    // ================= attention: head h = w, two 16-row chunks =================
    {
        const int h = w;
#pragma unroll
        for (int mt = 0; mt < 2; mt++) {
            // Q A-frag (octets k>=16 zeroed)
            int mrow = m0l + mt*16 + ln15;
            int gr = (mrow < 122) ? mrow : 121;
            bf16x8 af = {0,0,0,0,0,0,0,0};
            if (lg < 2) af = *(const bf16x8*)(qb + gr*256 + h*16 + lg*8);
            // S = Q K^T
            f32x4 S[8];
#pragma unroll
            for (int nt = 0; nt < 8; nt++) {
                int j = nt*16 + ln15;
                int gj = (j < 122) ? j : 121;
                bf16x8 bv = {0,0,0,0,0,0,0,0};
                if (lg < 2) bv = *(const bf16x8*)(qb + gj*256 + 128 + h*16 + lg*8);
                S[nt] = __builtin_amdgcn_mfma_f32_16x16x32_bf16(af, bv,
                            (f32x4){0.f,0.f,0.f,0.f}, 0, 0, 0);
            }
            // softmax (row = lg*4+i; reduce over ln15 within 16-lane group)
            float sm[4];
#pragma unroll
            for (int i = 0; i < 4; i++) {
                float m_ = -1e30f;
#pragma unroll
                for (int nt = 0; nt < 8; nt++) {
                    float v = S[nt][i] * 0.25f;
                    if (nt == 7 && ln15 >= 10) v = -1e30f;
                    S[nt][i] = v;
                    m_ = fmaxf(m_, v);
                }
                m_ = fmaxf(m_, __shfl_xor(m_, 1, 64));
                m_ = fmaxf(m_, __shfl_xor(m_, 2, 64));
                m_ = fmaxf(m_, __shfl_xor(m_, 4, 64));
                m_ = fmaxf(m_, __shfl_xor(m_, 8, 64));
                float s_ = 0.f;
#pragma unroll
                for (int nt = 0; nt < 8; nt++) {
                    float e = __expf(S[nt][i] - m_);
                    S[nt][i] = e;
                    s_ += e;
                }
                s_ += __shfl_xor(s_, 1, 64);
                s_ += __shfl_xor(s_, 2, 64);
                s_ += __shfl_xor(s_, 4, 64);
                s_ += __shfl_xor(s_, 8, 64);
                sm[i] = s_;
            }
            // P (unnormalized) -> Pw (16 rows, A-layout)
#pragma unroll
            for (int nt = 0; nt < 8; nt++)
#pragma unroll
                for (int i = 0; i < 4; i++) {
                    int rp = lg*4 + i;
                    int j = nt*16 + ln15;
                    int cp = (j >> 3) ^ rp;
                    Pw[rp*128 + cp*8 + (j & 7)] = f2bf(S[nt][i]);
                }
            // PV (K=128 over j)
            f32x4 cacc = (f32x4){0.f,0.f,0.f,0.f};
#pragma unroll
            for (int kt = 0; kt < 4; kt++) {
                bf16x8 bv = *(const bf16x8*)(vtb + ((size_t)(b*128 + h*16 + ln15))*128 + kt*32 + lg*8);
                int m = ln15;
                int cp = (kt*4 + lg) ^ m;
                bf16x8 ap = *(const bf16x8*)&Pw[m*128 + cp*8];
                cacc = __builtin_amdgcn_mfma_f32_16x16x32_bf16(ap, bv, cacc, 0, 0, 0);
            }
            // normalize + write ctx (bf16, A-layout)
#pragma unroll
            for (int i = 0; i < 4; i++) {
                float inv = __builtin_amdgcn_rcpf(sm[i]);
                int rp = mt*16 + lg*4 + i;
                int ccol = h*16 + ln15;
                int cp = (ccol >> 3) ^ (rp & 15);
                ctxs[rp*128 + cp*8 + (ccol & 7)] = f2bf(cacc[i] * inv);
            }
        }
    }
    __syncthreads();

    // ================= out-proj + residual: wave w owns cols w*16..w*16+15 =================
    {
        f32x4 acc[2];
#pragma unroll
        for (int mi = 0; mi < 2; mi++) acc[mi] = (f32x4){0.f,0.f,0.f,0.f};
        int nn = w*16 + ln15;
#pragma unroll
        for (int kt = 0; kt < 4; kt++) {
            bf16x8 bv = *(const bf16x8*)&outW[(size_t)nn*128 + kt*32 + lg*8];
#pragma unroll
            for (int mi = 0; mi < 2; mi++) {
                int m = mi*16 + ln15;
                int cp = (kt*4 + lg) ^ (m & 15);
                bf16x8 afm = *(const bf16x8*)&ctxs[m*128 + cp*8];
                acc[mi] = __builtin_amdgcn_mfma_f32_16x16x32_bf16(afm, bv, acc[mi], 0, 0, 0);
            }
        }
        float bb = outb[nn];
#pragma unroll
        for (int mi = 0; mi < 2; mi++)
#pragma unroll
            for (int i = 0; i < 4; i++) {
                int ml = mi*16 + lg*4 + i;
                int mrow = m0l + ml;
                int grow = b*122 + ((mrow < 122) ? mrow : 121);
                Cs[ml*129 + nn] = acc[mi][i] + bb + tok[(size_t)grow*128 + nn];
            }
    }
    __syncthreads();

    // ================= LN1 -> Cs(f32) + ln1buf(bf16) =================
    unsigned short* ln1buf = Pregion;          // 8 KB
    unsigned short* Hs = Pregion + 4096;       // 16 KB
    {
        int r = tid >> 4, sub = tid & 15;      // 32 rows x 16 lanes x 8 cols
        float s1 = 0.f, s2 = 0.f;
#pragma unroll
        for (int j = 0; j < 8; j++) {
            float vv = Cs[r*129 + sub*8 + j];
            s1 += vv; s2 += vv*vv;
        }
        s1 += __shfl_xor(s1, 1, 64); s2 += __shfl_xor(s2, 1, 64);
        s1 += __shfl_xor(s1, 2, 64); s2 += __shfl_xor(s2, 2, 64);
        s1 += __shfl_xor(s1, 4, 64); s2 += __shfl_xor(s2, 4, 64);
        s1 += __shfl_xor(s1, 8, 64); s2 += __shfl_xor(s2, 8, 64);
        float mu = s1 * (1.0f/128.0f);
        float var = s2 * (1.0f/128.0f) - mu*mu;
        float rstd = rsqrtf(var + EPS);
#pragma unroll
        for (int j = 0; j < 8; j++) {
            int nloc = sub*8 + j;
            float vv = (Cs[r*129 + nloc] - mu) * rstd * ln1g[nloc] + ln1b[nloc];
            Cs[r*129 + nloc] = vv;
            int cp = (nloc >> 3) ^ (r & 15);
            ln1buf[r*128 + cp*8 + (nloc & 7)] = f2bf(vv);
        }
    }
    __syncthreads();

    // ================= ff1 (gelu) -> Hs: wave w owns cols w*32..w*32+31 =================
    {
        f32x4 acc1[2][2];
#pragma unroll
        for (int mi = 0; mi < 2; mi++)
#pragma unroll
            for (int ni = 0; ni < 2; ni++) acc1[mi][ni] = (f32x4){0.f,0.f,0.f,0.f};
#pragma unroll
        for (int kt = 0; kt < 4; kt++) {
            bf16x8 afm[2];
#pragma unroll
            for (int mi = 0; mi < 2; mi++) {
                int m = mi*16 + ln15;
                int cp = (kt*4 + lg) ^ (m & 15);
                afm[mi] = *(const bf16x8*)&ln1buf[m*128 + cp*8];
            }
#pragma unroll
            for (int ni = 0; ni < 2; ni++) {
                int nn = (w*2 + ni)*16 + ln15;
                bf16x8 bv = *(const bf16x8*)&B1[(size_t)nn*128 + kt*32 + lg*8];
#pragma unroll
                for (int mi = 0; mi < 2; mi++)
                    acc1[mi][ni] = __builtin_amdgcn_mfma_f32_16x16x32_bf16(afm[mi], bv, acc1[mi][ni], 0, 0, 0);
            }
        }
#pragma unroll
        for (int ni = 0; ni < 2; ni++) {
            int nn = (w*2 + ni)*16 + ln15;
            float bb = b1[nn];
#pragma unroll
            for (int mi = 0; mi < 2; mi++)
#pragma unroll
                for (int i = 0; i < 4; i++) {
                    int m = mi*16 + lg*4 + i;
                    float v = gelu_fast(acc1[mi][ni][i] + bb);
                    int cp = (nn >> 3) ^ (m & 15);
                    Hs[m*256 + cp*8 + (nn & 7)] = f2bf(v);
                }
        }
    }
    __syncthreads();

    // ================= ff2 + residual: wave w owns cols w*16..w*16+15 =================
    {
        f32x4 acc2[2];
#pragma unroll
        for (int mi = 0; mi < 2; mi++) acc2[mi] = (f32x4){0.f,0.f,0.f,0.f};
        int nn = w*16 + ln15;
#pragma unroll
        for (int kt = 0; kt < 8; kt++) {
            bf16x8 bv = *(const bf16x8*)&B2[(size_t)nn*256 + kt*32 + lg*8];
#pragma unroll
            for (int mi = 0; mi < 2; mi++) {
                int m = mi*16 + ln15;
                int cp = (kt*4 + lg) ^ (m & 15);
                bf16x8 afm = *(const bf16x8*)&Hs[m*256 + cp*8];
                acc2[mi] = __builtin_amdgcn_mfma_f32_16x16x32_bf16(afm, bv, acc2[mi], 0, 0, 0);
            }
        }
        float bb = b2[nn];
#pragma unroll
        for (int mi = 0; mi < 2; mi++)
#pragma unroll
            for (int i = 0; i < 4; i++) {
                int ml = mi*16 + lg*4 + i;
                Cs[ml*129 + nn] = acc2[mi][i] + bb + Cs[ml*129 + nn];
            }
    }
    __syncthreads();

    // ================= LN2 -> tok =================
    {
        int r = tid >> 4, sub = tid & 15;
        float s1 = 0.f, s2 = 0.f;
#pragma unroll
        for (int j = 0; j < 8; j++) {
            float vv = Cs[r*129 + sub*8 + j];
            s1 += vv; s2 += vv*vv;
        }
        s1 += __shfl_xor(s1, 1, 64); s2 += __shfl_xor(s2, 1, 64);
        s1 += __shfl_xor(s1, 2, 64); s2 += __shfl_xor(s2, 2, 64);
        s1 += __shfl_xor(s1, 4, 64); s2 += __shfl_xor(s2, 4, 64);
        s1 += __shfl_xor(s1, 8, 64); s2 += __shfl_xor(s2, 8, 64);
        float mu = s1 * (1.0f/128.0f);
        float var = s2 * (1.0f/128.0f) - mu*mu;
        float rstd = rsqrtf(var + EPS);
        if (m0l + r < 122) {
#pragma unroll
            for (int j = 0; j < 8; j++) {
                int nloc = sub*8 + j;
                float vv = (Cs[r*129 + nloc] - mu) * rstd * ln2g[nloc] + ln2b[nloc];
                tok[((size_t)(b*122 + m0l + r))*128 + nloc] = vv;
            }
        }
    }
}

// ---------------- final: mean over C + subject head ----------------
__global__ __launch_bounds__(128) void final_kernel(const float* __restrict__ tok,
        const int* __restrict__ sid,
        const float* __restrict__ hw, const float* __restrict__ hb,
        float* __restrict__ outp) {
    __shared__ float pool[DD];
    int b = blockIdx.x, tid = threadIdx.x;
    float s = 0.f;
    for (int c2 = 0; c2 < CC; c2++) s += tok[((size_t)b*CC + c2)*DD + tid];
    pool[tid] = s * (1.0f/(float)CC);
    __syncthreads();
    if (tid < 4) {
        int sb = sid[b];
        const float* w = hw + ((size_t)sb*4 + tid)*DD;
        float a = hb[sb*4 + tid];
#pragma unroll 8
        for (int d = 0; d < DD; d++) a = fmaf(pool[d], w[d], a);
        outp[b*4 + tid] = a;
    }
}

extern "C" void kernel_launch(void* const* d_in, const int* in_sizes, int n_in,
                              void* d_out, int out_size, void* d_ws, size_t ws_size,
                              hipStream_t stream) {
    const float* x       = (const float*)d_in[0];
    const int*   sid     = (const int*)  d_in[1];
    const float* conv1_w = (const float*)d_in[2];
    const float* conv1_b = (const float*)d_in[3];
    const float* bn1_g   = (const float*)d_in[4];
    const float* bn1_b   = (const float*)d_in[5];
    const float* bn1_m   = (const float*)d_in[6];
    const float* bn1_v   = (const float*)d_in[7];
    const float* conv2_w = (const float*)d_in[8];
    const float* conv2_b = (const float*)d_in[9];
    const float* bn2_g   = (const float*)d_in[10];
    const float* bn2_b   = (const float*)d_in[11];
    const float* bn2_m   = (const float*)d_in[12];
    const float* bn2_v   = (const float*)d_in[13];
    const float* proj_w  = (const float*)d_in[14];
    const float* proj_b  = (const float*)d_in[15];
    const float* elec    = (const float*)d_in[16];
    const float* qkv_w   = (const float*)d_in[17];
    const float* qkv_b   = (const float*)d_in[18];
    const float* out_w   = (const float*)d_in[19];
    const float* out_b   = (const float*)d_in[20];
    const float* ln1_g   = (const float*)d_in[21];
    const float* ln1_b   = (const float*)d_in[22];
    const float* ff1_w   = (const float*)d_in[23];
    const float* ff1_b   = (const float*)d_in[24];
    const float* ff2_w   = (const float*)d_in[25];
    const float* ff2_b   = (const float*)d_in[26];
    const float* ln2_g   = (const float*)d_in[27];
    const float* ln2_b   = (const float*)d_in[28];
    const float* heads_w = (const float*)d_in[29];
    const float* heads_b = (const float*)d_in[30];
    float* ws = (float*)d_ws;
    const unsigned short* wbf = (const unsigned short*)(ws + WS_WBF);
    unsigned short* qkvb = (unsigned short*)(ws + WS_QKVB);
    unsigned short* vtb  = (unsigned short*)(ws + WS_VTB);

    prep_kernel<<<(285312 + 255)/256, 256, 0, stream>>>(
        conv1_w, conv1_b, bn1_g, bn1_b, bn1_m, bn1_v,
        conv2_w, conv2_b, bn2_g, bn2_b, bn2_m, bn2_v,
        qkv_w, out_w, ff1_w, ff2_w, ws);

    conv_kernel<<<SEQ, 256, 0, stream>>>(x, proj_w, proj_b, elec, ws, ws + WS_TOK);

    for (int l = 0; l < NLAYER; l++) {
        qkv_gemm<<<dim3(244,3), 256, 0, stream>>>(
            ws + WS_TOK, wbf + WB_QKV + l*49152, qkv_b + l*384, qkvb, vtb);
        attn_tail<<<BB*4, 512, 0, stream>>>(
            qkvb, vtb,
            wbf + WB_OUT + l*16384, out_b + l*128,
            ws + WS_TOK, ln1_g + l*128, ln1_b + l*128,
            wbf + WB_FF1 + l*32768, ff1_b + l*256,
            wbf + WB_FF2 + l*32768, ff2_b + l*128,
            ln2_g + l*128, ln2_b + l*128);
    }

    final_kernel<<<BB, 128, 0, stream>>>(ws + WS_TOK, sid, heads_w, heads_b, (float*)d_out);
}

// Round 8
// 419.526 us; speedup vs baseline: 6.8950x; 1.0233x over previous
//
#include <hip/hip_runtime.h>
#include <hip/hip_fp16.h>
#include <hip/hip_bf16.h>
#include <math.h>

#define BB 64
#define CC 122
#define TT 500
#define NCOUT 64
#define DD 128
#define HHEADS 8
#define FFDIM 256
#define NLAYER 2
#define EPS 1e-5f
#define SEQ (BB*CC)   // 7808

// ---------------- workspace float offsets ----------------
#define WS_W2T     0u            // 20480 ushort bf16 w2t [kk][co][ci] (20480 floats reserved)
#define WS_S1      20480u
#define WS_SH1     20544u
#define WS_S2      20608u
#define WS_SH2     20672u
#define WS_WBF     20736u        // 262144 ushorts: bf16 qkv/out/ff1/ff2 weights
#define WS_TOK     151808u       // 7808*128 floats
#define WS_QKVB    1151232u      // 7808*256 ushorts (bf16 q,k) = 999424 floats
#define WS_VTB     2150656u      // 64*128*128 ushorts (bf16 v^T, [b][dh][j]) = 524288 floats
#define WS_GTAB    2674944u      // 512 uints: packed f16 (gelu, delta) pairs over [-8,8]
#define WS_W1S     2675968u      // 1024 floats = 2048 ushorts: bf16 w1s[co][k=32], BN-folded
// end = 2676992 floats = 10.7 MB

// WBF internal ushort offsets
#define WB_QKV  0u        // l*49152 + e*128 + k
#define WB_OUT  98304u    // l*16384 + e*128 + k
#define WB_FF1  131072u   // l*32768 + e*128 + k
#define WB_FF2  196608u   // l*32768 + e*256 + k

typedef __attribute__((ext_vector_type(8))) short bf16x8;
typedef __attribute__((ext_vector_type(4))) float f32x4;

__device__ __forceinline__ unsigned short f2bf(float f) {
    unsigned int u = __float_as_uint(f);
    unsigned int r = u + 0x7FFFu + ((u >> 16) & 1u);
    return (unsigned short)(r >> 16);
}

// branch-free erf-GELU (A&S 7.1.26)
__device__ __forceinline__ float gelu_fast(float x) {
    float z = fabsf(x) * 0.70710678118654752f;
    float t = __builtin_amdgcn_rcpf(fmaf(0.3275911f, z, 1.0f));
    float p = fmaf(fmaf(fmaf(fmaf(1.061405429f, t, -1.453152027f), t,
                             1.421413741f), t, -0.284496736f), t, 0.254829592f);
    float e = __expf(-z * z);
    float erf_abs = fmaf(-p * t, e, 1.0f);
    float erf_x = copysignf(erf_abs, x);
    return 0.5f * x * (1.0f + erf_x);
}

// table GELU: 512 packed-f16 (value,delta) pairs over [-8,8]; b32 gather
__device__ __forceinline__ float gelu_tab(float x, const unsigned* __restrict__ gt) {
    float p = fmaf(x, 32.0f, 256.0f);
    p = fminf(fmaxf(p, 0.0f), 511.999f);
    int i = (int)p;
    float fr = p - (float)i;
    unsigned u = gt[i];
    __half2 h2 = *(__half2*)&u;
    float v0 = __half2float(h2.x);
    float d  = __half2float(h2.y);
    return fmaf(fr, d, v0);
}

// ---------------- prep: fold BN, bf16-ify weights, build tables ----------------
__global__ void prep_kernel(const float* __restrict__ conv1_w, const float* __restrict__ conv1_b,
                            const float* __restrict__ bn1_g, const float* __restrict__ bn1_b,
                            const float* __restrict__ bn1_m, const float* __restrict__ bn1_v,
                            const float* __restrict__ conv2_w, const float* __restrict__ conv2_b,
                            const float* __restrict__ bn2_g, const float* __restrict__ bn2_b,
                            const float* __restrict__ bn2_m, const float* __restrict__ bn2_v,
                            const float* __restrict__ qkv_w, const float* __restrict__ out_w,
                            const float* __restrict__ ff1_w, const float* __restrict__ ff2_w,
                            float* __restrict__ ws) {
    int idx = blockIdx.x * blockDim.x + threadIdx.x;
    if (idx < 20480) {
        int ci = idx & 63; int co = (idx >> 6) & 63; int kk = idx >> 12;
        unsigned short* wt = (unsigned short*)(ws + WS_W2T);
        wt[idx] = f2bf(conv2_w[(co*64 + ci)*5 + kk]);
    } else if (idx < 20544) {
        int i = idx - 20480;
        float s = bn1_g[i] * rsqrtf(bn1_v[i] + EPS);
        ws[WS_S1 + i] = s;
        ws[WS_SH1 + i] = (conv1_b[i] - bn1_m[i]) * s + bn1_b[i];
    } else if (idx < 20608) {
        int i = idx - 20544;
        float s = bn2_g[i] * rsqrtf(bn2_v[i] + EPS);
        ws[WS_S2 + i] = s;
        ws[WS_SH2 + i] = (conv2_b[i] - bn2_m[i]) * s + bn2_b[i];
    } else if (idx < 282752) {
        int r = idx - 20608;
        unsigned short* wbf = (unsigned short*)(ws + WS_WBF);
        float v;
        if (r < 98304)       v = qkv_w[r];
        else if (r < 131072) v = out_w[r - 98304];
        else if (r < 196608) v = ff1_w[r - 131072];
        else                 v = ff2_w[r - 196608];
        wbf[r] = f2bf(v);
    } else if (idx < 283264) {
        int i = idx - 282752;
        float x0 = (i - 256) * 0.03125f;
        float x1 = x0 + 0.03125f;
        float g0 = 0.5f*x0*(1.0f + erff(x0*0.70710678118654752f));
        float g1 = 0.5f*x1*(1.0f + erff(x1*0.70710678118654752f));
        __half hv = __float2half_rn(g0);
        __half hd = __float2half_rn(g1 - g0);
        unsigned short uv = *(unsigned short*)&hv;
        unsigned short ud = *(unsigned short*)&hd;
        ((unsigned*)(ws + WS_GTAB))[i] = (unsigned)uv | ((unsigned)ud << 16);
    } else if (idx < 285312) {
        int i = idx - 283264;            // co*32 + k
        int co = i >> 5, k = i & 31;
        unsigned short* w1s = (unsigned short*)(ws + WS_W1S);
        float s = bn1_g[co] * rsqrtf(bn1_v[co] + EPS);
        w1s[i] = (k < 9) ? f2bf(conv1_w[co*9 + k] * s) : (unsigned short)0;
    }
}

// ---------------- fused conv1 [MFMA] + pool + conv2 [MFMA] + mean + proj ----------------
// LDS total ~38.2 KB -> 4 blocks/CU
__global__ __launch_bounds__(256, 4) void conv_kernel(const float* __restrict__ x,
            const float* __restrict__ proj_w, const float* __restrict__ proj_b,
            const float* __restrict__ elec,
            const float* __restrict__ wsr, float* __restrict__ tok) {
    __shared__ __align__(16) unsigned short h1s[264*64];  // 33792 B
    __shared__ __align__(16) unsigned short xbf[544];     // 1088 B
    __shared__ __align__(16) unsigned gtab[512];          // 2048 B (packed f16 pairs)
    __shared__ float part[256];                           // 1024 B
    __shared__ float mean_l[64];                          // 256 B
    int n = blockIdx.x;
    int c = n % CC;
    int tid = threadIdx.x;
    const float* xg = x + (size_t)n * TT;

    for (int i = tid; i < 544; i += 256) {
        unsigned short v = 0;
        if (i >= 4 && i < 504) v = f2bf(xg[i-4]);
        xbf[i] = v;
    }
    if (tid < 128) {
        ((uint4*)gtab)[tid] = ((const uint4*)(wsr + WS_GTAB))[tid];
    }
    for (int idx = tid; idx < 14*64; idx += 256) {
        int rr = idx >> 6;
        int r = (rr < 2) ? rr : (rr - 2 + 252);
        h1s[r*64 + (idx & 63)] = 0;
    }
    __syncthreads();

    int lane = tid & 63;
    int w = tid >> 6;
    int ln15 = lane & 15, lg = lane >> 4;

    // ---- phase 1: conv1 via MFMA im2col (w1s zero-padded k>=9 kills masked taps) ----
    {
        const unsigned short* w1s = (const unsigned short*)(wsr + WS_W1S);
        bf16x8 b1f[4];
        float sh1v[4];
#pragma unroll
        for (int nt = 0; nt < 4; nt++) {
            int co = nt*16 + ln15;
            b1f[nt] = *(const bf16x8*)&w1s[co*32 + lg*8];
            sh1v[nt] = wsr[WS_SH1 + co];
        }
        for (int mi = 0; mi < 8; mi++) {
            int mt = w*8 + mi;
            int t = mt*16 + ln15;
            short e[8];
#pragma unroll
            for (int j = 0; j < 8; j++) e[j] = (short)xbf[t + lg*8 + j];
            bf16x8 af = {e[0],e[1],e[2],e[3],e[4],e[5],e[6],e[7]};
#pragma unroll
            for (int nt = 0; nt < 4; nt++) {
                f32x4 cacc = __builtin_amdgcn_mfma_f32_16x16x32_bf16(af, b1f[nt],
                                (f32x4){0.f,0.f,0.f,0.f}, 0, 0, 0);
                float g0 = gelu_tab(cacc[0] + sh1v[nt], gtab);
                float g1 = gelu_tab(cacc[1] + sh1v[nt], gtab);
                float g2 = gelu_tab(cacc[2] + sh1v[nt], gtab);
                float g3 = gelu_tab(cacc[3] + sh1v[nt], gtab);
                int tpA = mt*8 + lg*2;
                if (tpA < 250) {
                    int co = nt*16 + ln15;
                    // packed RNE f32->bf16 pair (v_cvt_pk_bf16_f32 where available)
                    union { __hip_bfloat162 b; unsigned u; } pk;
                    pk.b = __float22bfloat162_rn(make_float2(fmaxf(g0, g1), fmaxf(g2, g3)));
                    int r = tpA + 2;
                    int cp = (co >> 3) ^ (r & 7);
                    h1s[r*64 + cp*8 + (co & 7)] = (unsigned short)(pk.u & 0xffffu);
                    int r2 = r + 1;
                    int cp2 = (co >> 3) ^ (r2 & 7);
                    h1s[r2*64 + cp2*8 + (co & 7)] = (unsigned short)(pk.u >> 16);
                }
            }
        }
    }
    __syncthreads();

    // ---- phase 2: conv2 as 5 shifted GEMMs ----
    const unsigned short* wt = (const unsigned short*)(wsr + WS_W2T);
    f32x4 acc[4][4];
#pragma unroll
    for (int mi = 0; mi < 4; mi++)
#pragma unroll
        for (int nt = 0; nt < 4; nt++) acc[mi][nt] = (f32x4){0.f, 0.f, 0.f, 0.f};

    const unsigned short* wbase = wt + ln15*64 + lg*8;
#pragma unroll
    for (int kk = 0; kk < 5; kk++) {
#pragma unroll
        for (int s = 0; s < 2; s++) {
            bf16x8 bfv[4];
#pragma unroll
            for (int nt = 0; nt < 4; nt++)
                bfv[nt] = *(const bf16x8*)(wbase + kk*4096 + nt*1024 + s*32);
#pragma unroll
            for (int mi = 0; mi < 4; mi++) {
                int r = (w*4 + mi)*16 + ln15 + kk;
                int cp = (s*4 + lg) ^ (r & 7);
                bf16x8 af = *(const bf16x8*)&h1s[r*64 + cp*8];
#pragma unroll
                for (int nt = 0; nt < 4; nt++)
                    acc[mi][nt] = __builtin_amdgcn_mfma_f32_16x16x32_bf16(af, bfv[nt], acc[mi][nt], 0, 0, 0);
            }
        }
    }

    // ---- epilogue: BN + GELU + mean over t ----
#pragma unroll
    for (int nt = 0; nt < 4; nt++) {
        int co2 = nt*16 + ln15;
        float sc = wsr[WS_S2 + co2], sh = wsr[WS_SH2 + co2];
        float p = 0.f;
#pragma unroll
        for (int mi = 0; mi < 4; mi++) {
            int tbase = (w*4 + mi)*16 + lg*4;
#pragma unroll
            for (int i = 0; i < 4; i++) {
                if (tbase + i < 250)
                    p += gelu_tab(fmaf(acc[mi][nt][i], sc, sh), gtab);
            }
        }
        p += __shfl_down(p, 32, 64);
        p += __shfl_down(p, 16, 64);
        if (lane < 16) part[w*64 + co2] = p;
    }
    __syncthreads();
    if (tid < 64) {
        mean_l[tid] = (part[tid] + part[64+tid] + part[128+tid] + part[192+tid]) * (1.0f/250.0f);
    }
    __syncthreads();

    if (tid < DD) {
        int d = tid;
        float a = proj_b[d] + elec[c*DD + d];
#pragma unroll 8
        for (int o = 0; o < 64; o++) a = fmaf(mean_l[o], proj_w[d*64 + o], a);
        tok[(size_t)n * DD + d] = a;
    }
}

// ---------------- qkv GEMM: tok[f32] @ qkv_w^T + b -> bf16 qkvb (q,k) / vtb (v^T) ----
__global__ __launch_bounds__(256) void qkv_gemm(const float* __restrict__ Aptr,
        const unsigned short* __restrict__ Bbf,   // layer's qkv weights [e][k]
        const float* __restrict__ bias,           // layer's qkv bias [384]
        unsigned short* __restrict__ qkvb,        // [7808][256]
        unsigned short* __restrict__ vtb) {       // [b*128+dh][128]
    const int tid = threadIdx.x;
    const int m0 = blockIdx.x * 32;
    const int y  = blockIdx.y;                    // 0:q 1:k 2:v
    const int n0 = y * 128;
    __shared__ __align__(16) unsigned short As[32*128];

    const float* A = Aptr + (size_t)m0 * 128;
    for (int i = tid; i < 1024; i += 256) {
        int m = i >> 5; int kq = (i & 31)*4;
        float4 v = *(const float4*)(A + m*128 + kq);
        int cp = (kq >> 3) ^ (m & 15);
        short4 s4 = make_short4((short)f2bf(v.x), (short)f2bf(v.y),
                                (short)f2bf(v.z), (short)f2bf(v.w));
        *(short4*)&As[m*128 + cp*8 + (kq & 7)] = s4;
    }
    __syncthreads();

    const int lane = tid & 63, w = tid >> 6;
    const int ln15 = lane & 15, lg = lane >> 4;
    f32x4 acc[2][2];
#pragma unroll
    for (int mi = 0; mi < 2; mi++)
#pragma unroll
        for (int ni = 0; ni < 2; ni++) acc[mi][ni] = (f32x4){0.f, 0.f, 0.f, 0.f};

    const unsigned short* Bb = Bbf + (size_t)n0 * 128;
#pragma unroll
    for (int kt = 0; kt < 4; kt++) {
        bf16x8 af[2], bfv[2];
#pragma unroll
        for (int mi = 0; mi < 2; mi++) {
            int m = mi*16 + ln15;
            int cp = (kt*4 + lg) ^ (m & 15);
            af[mi] = *(const bf16x8*)&As[m*128 + cp*8];
        }
#pragma unroll
        for (int ni = 0; ni < 2; ni++) {
            int nn = (w*2 + ni)*16 + ln15;
            bfv[ni] = *(const bf16x8*)&Bb[(size_t)nn*128 + kt*32 + lg*8];
        }
#pragma unroll
        for (int mi = 0; mi < 2; mi++)
#pragma unroll
            for (int ni = 0; ni < 2; ni++)
                acc[mi][ni] = __builtin_amdgcn_mfma_f32_16x16x32_bf16(af[mi], bfv[ni], acc[mi][ni], 0, 0, 0);
    }

#pragma unroll
    for (int mi = 0; mi < 2; mi++)
#pragma unroll
        for (int ni = 0; ni < 2; ni++) {
            int nloc = (w*2 + ni)*16 + ln15;
            float bb = bias[n0 + nloc];
#pragma unroll
            for (int i = 0; i < 4; i++) {
                int ml = mi*16 + lg*4 + i;
                int nrow = m0 + ml;
                unsigned short us = f2bf(acc[mi][ni][i] + bb);
                if (y < 2) {
                    qkvb[(size_t)nrow*256 + n0 + nloc] = us;
                } else {
                    int bq = nrow / 122;
                    int j  = nrow - bq*122;
                    vtb[((size_t)(bq*128 + nloc))*128 + j] = us;
                }
            }
        }
}

// ---------------- fused attention + out-proj + LN1 + FF + LN2 (512 thr, head/wave) ----
// block = (b, quarter): rows m0l..m0l+31 of batch b; wave w handles head w
__global__ __launch_bounds__(512) void attn_tail(
        const unsigned short* __restrict__ qkvb,
        const unsigned short* __restrict__ vtb,
        const unsigned short* __restrict__ outW, const float* __restrict__ outb,
        float* __restrict__ tok,
        const float* __restrict__ ln1g, const float* __restrict__ ln1b,
        const unsigned short* __restrict__ B1, const float* __restrict__ b1,
        const unsigned short* __restrict__ B2, const float* __restrict__ b2,
        const float* __restrict__ ln2g, const float* __restrict__ ln2b) {
    __shared__ float Cs[32*129];                               // 16.5 KB
    __shared__ __align__(16) unsigned short Pregion[8*16*128]; // 32 KB (P/wave; later ln1buf+Hs)
    __shared__ __align__(16) unsigned short ctxs[32*128];      // 8 KB

    const int tid = threadIdx.x;
    const int blk = blockIdx.x;
    const int b = blk >> 2, mq = blk & 3;
    const int m0l = mq * 32;
    const int lane = tid & 63, w = tid >> 6;       // w = 0..7 = head
    const int ln15 = lane & 15, lg = lane >> 4;

    const unsigned short* qb = qkvb + (size_t)b * 122 * 256;
    unsigned short* Pw = Pregion + w * 2048;       // 16 rows x 128 cols bf16

    // ================= attention: head h = w, two 16-row chunks =================
    {
        const int h = w;
#pragma unroll
        for (int mt = 0; mt < 2; mt++) {
            // Q A-frag (octets k>=16 zeroed)
            int mrow = m0l + mt*16 + ln15;
            int gr = (mrow < 122) ? mrow : 121;
            bf16x8 af = {0,0,0,0,0,0,0,0};
            if (lg < 2) af = *(const bf16x8*)(qb + gr*256 + h*16 + lg*8);
            // S = Q K^T
            f32x4 S[8];
#pragma unroll
            for (int nt = 0; nt < 8; nt++) {
                int j = nt*16 + ln15;
                int gj = (j < 122) ? j : 121;
                bf16x8 bv = {0,0,0,0,0,0,0,0};
                if (lg < 2) bv = *(const bf16x8*)(qb + gj*256 + 128 + h*16 + lg*8);
                S[nt] = __builtin_amdgcn_mfma_f32_16x16x32_bf16(af, bv,
                            (f32x4){0.f,0.f,0.f,0.f}, 0, 0, 0);
            }
            // softmax (row = lg*4+i; reduce over ln15 within 16-lane group)
            float sm[4];
#pragma unroll
            for (int i = 0; i < 4; i++) {
                float m_ = -1e30f;
#pragma unroll
                for (int nt = 0; nt < 8; nt++) {
                    float v = S[nt][i] * 0.25f;
                    if (nt == 7 && ln15 >= 10) v = -1e30f;
                    S[nt][i] = v;
                    m_ = fmaxf(m_, v);
                }
                m_ = fmaxf(m_, __shfl_xor(m_, 1, 64));
                m_ = fmaxf(m_, __shfl_xor(m_, 2, 64));
                m_ = fmaxf(m_, __shfl_xor(m_, 4, 64));
                m_ = fmaxf(m_, __shfl_xor(m_, 8, 64));
                float s_ = 0.f;
#pragma unroll
                for (int nt = 0; nt < 8; nt++) {
                    float e = __expf(S[nt][i] - m_);
                    S[nt][i] = e;
                    s_ += e;
                }
                s_ += __shfl_xor(s_, 1, 64);
                s_ += __shfl_xor(s_, 2, 64);
                s_ += __shfl_xor(s_, 4, 64);
                s_ += __shfl_xor(s_, 8, 64);
                sm[i] = s_;
            }
            // P (unnormalized) -> Pw (16 rows, A-layout)
#pragma unroll
            for (int nt = 0; nt < 8; nt++)
#pragma unroll
                for (int i = 0; i < 4; i++) {
                    int rp = lg*4 + i;
                    int j = nt*16 + ln15;
                    int cp = (j >> 3) ^ rp;
                    Pw[rp*128 + cp*8 + (j & 7)] = f2bf(S[nt][i]);
                }
            // PV (K=128 over j)
            f32x4 cacc = (f32x4){0.f,0.f,0.f,0.f};
#pragma unroll
            for (int kt = 0; kt < 4; kt++) {
                bf16x8 bv = *(const bf16x8*)(vtb + ((size_t)(b*128 + h*16 + ln15))*128 + kt*32 + lg*8);
                int m = ln15;
                int cp = (kt*4 + lg) ^ m;
                bf16x8 ap = *(const bf16x8*)&Pw[m*128 + cp*8];
                cacc = __builtin_amdgcn_mfma_f32_16x16x32_bf16(ap, bv, cacc, 0, 0, 0);
            }
            // normalize + write ctx (bf16, A-layout)
#pragma unroll
            for (int i = 0; i < 4; i++) {
                float inv = __builtin_amdgcn_rcpf(sm[i]);
                int rp = mt*16 + lg*4 + i;
                int ccol = h*16 + ln15;
                int cp = (ccol >> 3) ^ (rp & 15);
                ctxs[rp*128 + cp*8 + (ccol & 7)] = f2bf(cacc[i] * inv);
            }
        }
    }
    __syncthreads();

    // ================= out-proj + residual: wave w owns cols w*16..w*16+15 =================
    {
        f32x4 acc[2];
#pragma unroll
        for (int mi = 0; mi < 2; mi++) acc[mi] = (f32x4){0.f,0.f,0.f,0.f};
        int nn = w*16 + ln15;
#pragma unroll
        for (int kt = 0; kt < 4; kt++) {
            bf16x8 bv = *(const bf16x8*)&outW[(size_t)nn*128 + kt*32 + lg*8];
#pragma unroll
            for (int mi = 0; mi < 2; mi++) {
                int m = mi*16 + ln15;
                int cp = (kt*4 + lg) ^ (m & 15);
                bf16x8 afm = *(const bf16x8*)&ctxs[m*128 + cp*8];
                acc[mi] = __builtin_amdgcn_mfma_f32_16x16x32_bf16(afm, bv, acc[mi], 0, 0, 0);
            }
        }
        float bb = outb[nn];
#pragma unroll
        for (int mi = 0; mi < 2; mi++)
#pragma unroll
            for (int i = 0; i < 4; i++) {
                int ml = mi*16 + lg*4 + i;
                int mrow = m0l + ml;
                int grow = b*122 + ((mrow < 122) ? mrow : 121);
                Cs[ml*129 + nn] = acc[mi][i] + bb + tok[(size_t)grow*128 + nn];
            }
    }
    __syncthreads();

    // ================= LN1 -> Cs(f32) + ln1buf(bf16) =================
    unsigned short* ln1buf = Pregion;          // 8 KB
    unsigned short* Hs = Pregion + 4096;       // 16 KB
    {
        int r = tid >> 4, sub = tid & 15;      // 32 rows x 16 lanes x 8 cols
        float s1 = 0.f, s2 = 0.f;
#pragma unroll
        for (int j = 0; j < 8; j++) {
            float vv = Cs[r*129 + sub*8 + j];
            s1 += vv; s2 += vv*vv;
        }
        s1 += __shfl_xor(s1, 1, 64); s2 += __shfl_xor(s2, 1, 64);
        s1 += __shfl_xor(s1, 2, 64); s2 += __shfl_xor(s2, 2, 64);
        s1 += __shfl_xor(s1, 4, 64); s2 += __shfl_xor(s2, 4, 64);
        s1 += __shfl_xor(s1, 8, 64); s2 += __shfl_xor(s2, 8, 64);
        float mu = s1 * (1.0f/128.0f);
        float var = s2 * (1.0f/128.0f) - mu*mu;
        float rstd = rsqrtf(var + EPS);
#pragma unroll
        for (int j = 0; j < 8; j++) {
            int nloc = sub*8 + j;
            float vv = (Cs[r*129 + nloc] - mu) * rstd * ln1g[nloc] + ln1b[nloc];
            Cs[r*129 + nloc] = vv;
            int cp = (nloc >> 3) ^ (r & 15);
            ln1buf[r*128 + cp*8 + (nloc & 7)] = f2bf(vv);
        }
    }
    __syncthreads();

    // ================= ff1 (gelu) -> Hs: wave w owns cols w*32..w*32+31 =================
    {
        f32x4 acc1[2][2];
#pragma unroll
        for (int mi = 0; mi < 2; mi++)
#pragma unroll
            for (int ni = 0; ni < 2; ni++) acc1[mi][ni] = (f32x4){0.f,0.f,0.f,0.f};
#pragma unroll
        for (int kt = 0; kt < 4; kt++) {
            bf16x8 afm[2];
#pragma unroll
            for (int mi = 0; mi < 2; mi++) {
                int m = mi*16 + ln15;
                int cp = (kt*4 + lg) ^ (m & 15);
                afm[mi] = *(const bf16x8*)&ln1buf[m*128 + cp*8];
            }
#pragma unroll
            for (int ni = 0; ni < 2; ni++) {
                int nn = (w*2 + ni)*16 + ln15;
                bf16x8 bv = *(const bf16x8*)&B1[(size_t)nn*128 + kt*32 + lg*8];
#pragma unroll
                for (int mi = 0; mi < 2; mi++)
                    acc1[mi][ni] = __builtin_amdgcn_mfma_f32_16x16x32_bf16(afm[mi], bv, acc1[mi][ni], 0, 0, 0);
            }
        }
#pragma unroll
        for (int ni = 0; ni < 2; ni++) {
            int nn = (w*2 + ni)*16 + ln15;
            float bb = b1[nn];
#pragma unroll
            for (int mi = 0; mi < 2; mi++)
#pragma unroll
                for (int i = 0; i < 4; i++) {
                    int m = mi*16 + lg*4 + i;
                    float v = gelu_fast(acc1[mi][ni][i] + bb);
                    int cp = (nn >> 3) ^ (m & 15);
                    Hs[m*256 + cp*8 + (nn & 7)] = f2bf(v);
                }
        }
    }
    __syncthreads();

    // ================= ff2 + residual: wave w owns cols w*16..w*16+15 =================
    {
        f32x4 acc2[2];
#pragma unroll
        for (int mi = 0; mi < 2; mi++) acc2[mi] = (f32x4){0.f,0.f,0.f,0.f};
        int nn = w*16 + ln15;
#pragma unroll
        for (int kt = 0; kt < 8; kt++) {
            bf16x8 bv = *(const bf16x8*)&B2[(size_t)nn*256 + kt*32 + lg*8];
#pragma unroll
            for (int mi = 0; mi < 2; mi++) {
                int m = mi*16 + ln15;
                int cp = (kt*4 + lg) ^ (m & 15);
                bf16x8 afm = *(const bf16x8*)&Hs[m*256 + cp*8];
                acc2[mi] = __builtin_amdgcn_mfma_f32_16x16x32_bf16(afm, bv, acc2[mi], 0, 0, 0);
            }
        }
        float bb = b2[nn];
#pragma unroll
        for (int mi = 0; mi < 2; mi++)
#pragma unroll
            for (int i = 0; i < 4; i++) {
                int ml = mi*16 + lg*4 + i;
                Cs[ml*129 + nn] = acc2[mi][i] + bb + Cs[ml*129 + nn];
            }
    }
    __syncthreads();

    // ================= LN2 -> tok =================
    {
        int r = tid >> 4, sub = tid & 15;
        float s1 = 0.f, s2 = 0.f;
#pragma unroll
        for (int j = 0; j < 8; j++) {
            float vv = Cs[r*129 + sub*8 + j];
            s1 += vv; s2 += vv*vv;
        }
        s1 += __shfl_xor(s1, 1, 64); s2 += __shfl_xor(s2, 1, 64);
        s1 += __shfl_xor(s1, 2, 64); s2 += __shfl_xor(s2, 2, 64);
        s1 += __shfl_xor(s1, 4, 64); s2 += __shfl_xor(s2, 4, 64);
        s1 += __shfl_xor(s1, 8, 64); s2 += __shfl_xor(s2, 8, 64);
        float mu = s1 * (1.0f/128.0f);
        float var = s2 * (1.0f/128.0f) - mu*mu;
        float rstd = rsqrtf(var + EPS);
        if (m0l + r < 122) {
#pragma unroll
            for (int j = 0; j < 8; j++) {
                int nloc = sub*8 + j;
                float vv = (Cs[r*129 + nloc] - mu) * rstd * ln2g[nloc] + ln2b[nloc];
                tok[((size_t)(b*122 + m0l + r))*128 + nloc] = vv;
            }
        }
    }
}

// ---------------- final: mean over C + subject head ----------------
__global__ __launch_bounds__(128) void final_kernel(const float* __restrict__ tok,
        const int* __restrict__ sid,
        const float* __restrict__ hw, const float* __restrict__ hb,
        float* __restrict__ outp) {
    __shared__ float pool[DD];
    int b = blockIdx.x, tid = threadIdx.x;
    float s = 0.f;
    for (int c2 = 0; c2 < CC; c2++) s += tok[((size_t)b*CC + c2)*DD + tid];
    pool[tid] = s * (1.0f/(float)CC);
    __syncthreads();
    if (tid < 4) {
        int sb = sid[b];
        const float* w = hw + ((size_t)sb*4 + tid)*DD;
        float a = hb[sb*4 + tid];
#pragma unroll 8
        for (int d = 0; d < DD; d++) a = fmaf(pool[d], w[d], a);
        outp[b*4 + tid] = a;
    }
}

extern "C" void kernel_launch(void* const* d_in, const int* in_sizes, int n_in,
                              void* d_out, int out_size, void* d_ws, size_t ws_size,
                              hipStream_t stream) {
    const float* x       = (const float*)d_in[0];
    const int*   sid     = (const int*)  d_in[1];
    const float* conv1_w = (const float*)d_in[2];
    const float* conv1_b = (const float*)d_in[3];
    const float* bn1_g   = (const float*)d_in[4];
    const float* bn1_b   = (const float*)d_in[5];
    const float* bn1_m   = (const float*)d_in[6];
    const float* bn1_v   = (const float*)d_in[7];
    const float* conv2_w = (const float*)d_in[8];
    const float* conv2_b = (const float*)d_in[9];
    const float* bn2_g   = (const float*)d_in[10];
    const float* bn2_b   = (const float*)d_in[11];
    const float* bn2_m   = (const float*)d_in[12];
    const float* bn2_v   = (const float*)d_in[13];
    const float* proj_w  = (const float*)d_in[14];
    const float* proj_b  = (const float*)d_in[15];
    const float* elec    = (const float*)d_in[16];
    const float* qkv_w   = (const float*)d_in[17];
    const float* qkv_b   = (const float*)d_in[18];
    const float* out_w   = (const float*)d_in[19];
    const float* out_b   = (const float*)d_in[20];
    const float* ln1_g   = (const float*)d_in[21];
    const float* ln1_b   = (const float*)d_in[22];
    const float* ff1_w   = (const float*)d_in[23];
    const float* ff1_b   = (const float*)d_in[24];
    const float* ff2_w   = (const float*)d_in[25];
    const float* ff2_b   = (const float*)d_in[26];
    const float* ln2_g   = (const float*)d_in[27];
    const float* ln2_b   = (const float*)d_in[28];
    const float* heads_w = (const float*)d_in[29];
    const float* heads_b = (const float*)d_in[30];
    float* ws = (float*)d_ws;
    const unsigned short* wbf = (const unsigned short*)(ws + WS_WBF);
    unsigned short* qkvb = (unsigned short*)(ws + WS_QKVB);
    unsigned short* vtb  = (unsigned short*)(ws + WS_VTB);

    prep_kernel<<<(285312 + 255)/256, 256, 0, stream>>>(
        conv1_w, conv1_b, bn1_g, bn1_b, bn1_m, bn1_v,
        conv2_w, conv2_b, bn2_g, bn2_b, bn2_m, bn2_v,
        qkv_w, out_w, ff1_w, ff2_w, ws);

    conv_kernel<<<SEQ, 256, 0, stream>>>(x, proj_w, proj_b, elec, ws, ws + WS_TOK);

    for (int l = 0; l < NLAYER; l++) {
        qkv_gemm<<<dim3(244,3), 256, 0, stream>>>(
            ws + WS_TOK, wbf + WB_QKV + l*49152, qkv_b + l*384, qkvb, vtb);
        attn_tail<<<BB*4, 512, 0, stream>>>(
            qkvb, vtb,
            wbf + WB_OUT + l*16384, out_b + l*128,
            ws + WS_TOK, ln1_g + l*128, ln1_b + l*128,
            wbf + WB_FF1 + l*32768, ff1_b + l*256,
            wbf + WB_FF2 + l*32768, ff2_b + l*128,
            ln2_g + l*128, ln2_b + l*128);
    }

    final_kernel<<<BB, 128, 0, stream>>>(ws + WS_TOK, sid, heads_w, heads_b, (float*)d_out);
}